// Round 13
// baseline (488.425 us; speedup 1.0000x reference)
//
#include <hip/hip_runtime.h>
#include <hip/hip_bf16.h>

#define H 256
#define NEG_SLOPE 0.01f
#define TILE_M 64

typedef __attribute__((ext_vector_type(4))) float f32x4;
typedef __attribute__((ext_vector_type(8))) short bf16x8;
typedef __attribute__((ext_vector_type(4))) short s16x4;

__device__ __forceinline__ short f2bf(float f) {
  __hip_bfloat16 b = __float2bfloat16(f);
  return *reinterpret_cast<short*>(&b);
}
__device__ __forceinline__ float bf2f(short s) {
  unsigned u = ((unsigned)(unsigned short)s) << 16;
  return __uint_as_float(u);
}

// ---------------- CSR build ----------------

__global__ __launch_bounds__(256) void hist_kernel(
    const int* __restrict__ parent, int* __restrict__ counts, int E) {
  int e = blockIdx.x * blockDim.x + threadIdx.x;
  if (e < E) atomicAdd(counts + parent[e], 1);
}

// Fused: blocks [0,nbCvt) convert h->hb (bf16); blocks [nbCvt,..) histogram.
__global__ __launch_bounds__(256) void prep_kernel(
    const float* __restrict__ h, short* __restrict__ hb, long total8,
    const int* __restrict__ parent, int* __restrict__ counts, int E,
    int nbCvt) {
  int b = blockIdx.x;
  if (b < nbCvt) {
    long i = (long)b * 256 + threadIdx.x;
    if (i >= total8) return;
    const f32x4* src = (const f32x4*)(h + i * 8);
    f32x4 v0 = src[0], v1 = src[1];
    bf16x8 o;
    o[0] = f2bf(v0.x); o[1] = f2bf(v0.y); o[2] = f2bf(v0.z); o[3] = f2bf(v0.w);
    o[4] = f2bf(v1.x); o[5] = f2bf(v1.y); o[6] = f2bf(v1.z); o[7] = f2bf(v1.w);
    *reinterpret_cast<bf16x8*>(hb + i * 8) = o;
  } else {
    int e = (b - nbCvt) * 256 + threadIdx.x;
    if (e < E) atomicAdd(counts + parent[e], 1);
  }
}

__global__ __launch_bounds__(256) void scan1_kernel(
    const int* __restrict__ counts, int* __restrict__ excl,
    int* __restrict__ blockSums, int n) {
  __shared__ int lds[256];
  int tid = threadIdx.x;
  int base = blockIdx.x * 1024 + tid * 4;
  int4 v = {0, 0, 0, 0};
  if (base + 3 < n) v = *reinterpret_cast<const int4*>(counts + base);
  int s = v.x + v.y + v.z + v.w;
  lds[tid] = s;
  __syncthreads();
  for (int off = 1; off < 256; off <<= 1) {
    int t = (tid >= off) ? lds[tid - off] : 0;
    __syncthreads();
    lds[tid] += t;
    __syncthreads();
  }
  int toff = lds[tid] - s;
  if (base + 3 < n) {
    int4 o;
    o.x = toff;
    o.y = toff + v.x;
    o.z = o.y + v.y;
    o.w = o.z + v.z;
    *reinterpret_cast<int4*>(excl + base) = o;
  }
  if (tid == 255) blockSums[blockIdx.x] = lds[255];
}

__global__ __launch_bounds__(256) void scan2_kernel(int* __restrict__ blockSums,
                                                    int nb) {
  __shared__ int lds[256];
  int tid = threadIdx.x;
  int s = (tid < nb) ? blockSums[tid] : 0;
  lds[tid] = s;
  __syncthreads();
  for (int off = 1; off < 256; off <<= 1) {
    int t = (tid >= off) ? lds[tid - off] : 0;
    __syncthreads();
    lds[tid] += t;
    __syncthreads();
  }
  if (tid < nb) blockSums[tid] = lds[tid] - s;
}

__global__ __launch_bounds__(256) void scan3_kernel(
    const int* __restrict__ excl, const int* __restrict__ blockSums,
    int* __restrict__ offsets, int* __restrict__ cursor, int n) {
  int i = blockIdx.x * blockDim.x + threadIdx.x;
  if (i < n) {
    int v = excl[i] + blockSums[i >> 10];
    offsets[i] = v;
    cursor[i] = v;
  }
}

__global__ __launch_bounds__(256) void scatter_kernel(
    const int* __restrict__ parent, const int* __restrict__ child,
    int* __restrict__ cursor, int* __restrict__ childlist, int E) {
  int e = blockIdx.x * blockDim.x + threadIdx.x;
  if (e < E) {
    int pos = atomicAdd(cursor + parent[e], 1);
    childlist[pos] = child[e];
  }
}

// Linear bf16 copies + fragment-packed copies.
__global__ __launch_bounds__(256) void cvt_kernel(
    const float* __restrict__ W1, const float* __restrict__ W2,
    short* __restrict__ w1b, short* __restrict__ w2b,
    short* __restrict__ w1p, short* __restrict__ w2p) {
  int i = blockIdx.x * blockDim.x + threadIdx.x;
  if (i < H * H) {
    short v1 = f2bf(W1[i]);
    short v2 = f2bf(W2[i]);
    w1b[i] = v1;
    w2b[i] = v2;
    int col = i >> 8, k = i & 255;
    int ks = k >> 5, lhi = (k >> 3) & 3, e = k & 7;
    int cb = col >> 4, lrr = col & 15;
    int pos = ((ks * 16 + cb) * 64 + lhi * 16 + lrr) * 8 + e;
    w1p[pos] = v1;
    w2p[pos] = v2;
  }
}

// ---------------- gather-mean from bf16 h: one wave per parent -------------
__global__ __launch_bounds__(256) void gather_mean_kernel(
    const short* __restrict__ hb, const int* __restrict__ childlist,
    const int* __restrict__ offsets, const int* __restrict__ counts,
    short* __restrict__ meansb, int n) {
  int w = (blockIdx.x * blockDim.x + threadIdx.x) >> 6;
  if (w >= n) return;
  int lane = threadIdx.x & 63;
  int deg = counts[w];
  int off = offsets[w];
  int degc = deg < 64 ? deg : 64;
  int cidx = 0;
  if (lane < degc) cidx = childlist[off + lane];  // one coalesced index load
  f32x4 acc = {0.f, 0.f, 0.f, 0.f};
  int i = 0;
  for (; i + 4 <= degc; i += 4) {
    int c0 = __shfl(cidx, i);
    int c1 = __shfl(cidx, i + 1);
    int c2 = __shfl(cidx, i + 2);
    int c3 = __shfl(cidx, i + 3);
    s16x4 v0 = ((const s16x4*)(hb + (size_t)c0 * H))[lane];
    s16x4 v1 = ((const s16x4*)(hb + (size_t)c1 * H))[lane];
    s16x4 v2 = ((const s16x4*)(hb + (size_t)c2 * H))[lane];
    s16x4 v3 = ((const s16x4*)(hb + (size_t)c3 * H))[lane];
    acc.x += bf2f(v0.x) + bf2f(v1.x) + bf2f(v2.x) + bf2f(v3.x);
    acc.y += bf2f(v0.y) + bf2f(v1.y) + bf2f(v2.y) + bf2f(v3.y);
    acc.z += bf2f(v0.z) + bf2f(v1.z) + bf2f(v2.z) + bf2f(v3.z);
    acc.w += bf2f(v0.w) + bf2f(v1.w) + bf2f(v2.w) + bf2f(v3.w);
  }
  for (; i < degc; ++i) {
    int c = __shfl(cidx, i);
    s16x4 v = ((const s16x4*)(hb + (size_t)c * H))[lane];
    acc.x += bf2f(v.x);
    acc.y += bf2f(v.y);
    acc.z += bf2f(v.z);
    acc.w += bf2f(v.w);
  }
  for (; i < deg; ++i) {  // deg > 64 cold path
    int c = childlist[off + i];
    s16x4 v = ((const s16x4*)(hb + (size_t)c * H))[lane];
    acc.x += bf2f(v.x);
    acc.y += bf2f(v.y);
    acc.z += bf2f(v.z);
    acc.w += bf2f(v.w);
  }
  float inv = 1.0f / (float)(deg > 0 ? deg : 1);
  acc *= inv;
  s16x4 bv;
  bv.x = f2bf(acc.x);
  bv.y = f2bf(acc.y);
  bv.z = f2bf(acc.z);
  bv.w = f2bf(acc.w);
  *reinterpret_cast<s16x4*>(meansb + (size_t)w * H + lane * 4) = bv;
}

// Fallback: gather from f32 h (when ws has no room for hb).
__global__ __launch_bounds__(256) void gather_mean_f32_kernel(
    const float* __restrict__ h, const int* __restrict__ childlist,
    const int* __restrict__ offsets, const int* __restrict__ counts,
    short* __restrict__ meansb, int n) {
  int w = (blockIdx.x * blockDim.x + threadIdx.x) >> 6;
  if (w >= n) return;
  int lane = threadIdx.x & 63;
  int deg = counts[w];
  int off = offsets[w];
  int degc = deg < 64 ? deg : 64;
  int cidx = 0;
  if (lane < degc) cidx = childlist[off + lane];
  f32x4 acc = {0.f, 0.f, 0.f, 0.f};
  int i = 0;
  for (; i + 4 <= degc; i += 4) {
    int c0 = __shfl(cidx, i);
    int c1 = __shfl(cidx, i + 1);
    int c2 = __shfl(cidx, i + 2);
    int c3 = __shfl(cidx, i + 3);
    f32x4 v0 = ((const f32x4*)(h + (size_t)c0 * H))[lane];
    f32x4 v1 = ((const f32x4*)(h + (size_t)c1 * H))[lane];
    f32x4 v2 = ((const f32x4*)(h + (size_t)c2 * H))[lane];
    f32x4 v3 = ((const f32x4*)(h + (size_t)c3 * H))[lane];
    acc += v0 + v1 + v2 + v3;
  }
  for (; i < degc; ++i) {
    int c = __shfl(cidx, i);
    acc += ((const f32x4*)(h + (size_t)c * H))[lane];
  }
  for (; i < deg; ++i) {
    int c = childlist[off + i];
    acc += ((const f32x4*)(h + (size_t)c * H))[lane];
  }
  float inv = 1.0f / (float)(deg > 0 ? deg : 1);
  acc *= inv;
  s16x4 bv;
  bv.x = f2bf(acc.x);
  bv.y = f2bf(acc.y);
  bv.z = f2bf(acc.z);
  bv.w = f2bf(acc.w);
  *reinterpret_cast<s16x4*>(meansb + (size_t)w * H + lane * 4) = bv;
}

// ---------------- MLP v7: (512,6) occupancy bump ----------------
// VGPR need is 64 (R12 counters); (512,6) caps at ~84 so no spill expected,
// giving 3 blocks/CU (24 waves) vs 2 at (512,4). R11 showed (512,8) cap=64
// forces allocator to 32+spill — (512,6) is the untested middle point.
__global__ __launch_bounds__(512, 6) void mlp2_kernel(
    const float* __restrict__ h, const short* __restrict__ hres,
    const short* __restrict__ meansb, const int* __restrict__ counts,
    const short* __restrict__ w1p, const short* __restrict__ w2p,
    const float* __restrict__ b1, const float* __restrict__ b2,
    float* __restrict__ out, int n) {
  __shared__ short lds[TILE_M * H];  // 32 KB: means tile -> z tile -> delta

  const int tid = threadIdx.x;
  const int row0 = blockIdx.x * TILE_M;
  const int lane = tid & 63;
  const int wv = tid >> 6;
  const int wm = wv >> 2;      // 0..1
  const int wn = wv & 3;       // 0..3
  const int lr = lane & 15;
  const int lhi = lane >> 4;

  // ---- Stage means -> LDS (coalesced 8KB bursts, XOR-swizzled) ----
#pragma unroll
  for (int v = 0; v < 4; ++v) {
    int lin = v * 8192 + tid * 16;          // byte index in 32KB tile
    int row = lin >> 9;                     // 0..63
    int grow = row0 + row;
    if (grow >= n) grow = n - 1;
    bf16x8 mv = *reinterpret_cast<const bf16x8*>(
        meansb + (size_t)grow * H + ((lin & 511) >> 1));
    int byte = lin ^ ((row & 7) << 4);
    *reinterpret_cast<bf16x8*>(reinterpret_cast<char*>(lds) + byte) = mv;
  }
  __syncthreads();

  const f32x4 zero4 = {0.f, 0.f, 0.f, 0.f};
  f32x4 acc[2][4];
#pragma unroll
  for (int m = 0; m < 2; ++m)
#pragma unroll
    for (int j = 0; j < 4; ++j) acc[m][j] = zero4;

  // ---- Layer 1: z = mean @ W1^T ----
#pragma unroll
  for (int ks = 0; ks < 8; ++ks) {
    bf16x8 a[2], b[4];
#pragma unroll
    for (int m = 0; m < 2; ++m) {
      int ar = wm * 32 + m * 16 + lr;
      int abyte = (ar * 512 + ks * 64 + lhi * 16) ^ ((ar & 7) << 4);
      a[m] = *reinterpret_cast<const bf16x8*>(
          reinterpret_cast<const char*>(lds) + abyte);
    }
#pragma unroll
    for (int j = 0; j < 4; ++j) {
      int cb = wn * 4 + j;
      b[j] = *reinterpret_cast<const bf16x8*>(
          w1p + ((ks * 16 + cb) * 64 + lane) * 8);
    }
#pragma unroll
    for (int m = 0; m < 2; ++m)
#pragma unroll
      for (int j = 0; j < 4; ++j)
        acc[m][j] = __builtin_amdgcn_mfma_f32_16x16x32_bf16(a[m], b[j],
                                                            acc[m][j], 0, 0, 0);
  }
  __syncthreads();  // all means reads done; tile will hold z

  // z (activated, bf16) into LDS stripe.
#pragma unroll
  for (int m = 0; m < 2; ++m)
#pragma unroll
    for (int j = 0; j < 4; ++j) {
      int col = wn * 64 + j * 16 + lr;
      float bias = b1[col];
#pragma unroll
      for (int r = 0; r < 4; ++r) {
        float z = acc[m][j][r] + bias;
        z = z >= 0.f ? z : NEG_SLOPE * z;
        int zr = wm * 32 + m * 16 + lhi * 4 + r;
        int byte = (zr * 512 + col * 2) ^ ((zr & 7) << 4);
        *reinterpret_cast<short*>(reinterpret_cast<char*>(lds) + byte) = f2bf(z);
      }
    }
  __syncthreads();

  // ---- Layer 2: delta = z @ W2^T ----
#pragma unroll
  for (int m = 0; m < 2; ++m)
#pragma unroll
    for (int j = 0; j < 4; ++j) acc[m][j] = zero4;

#pragma unroll
  for (int ks = 0; ks < 8; ++ks) {
    bf16x8 a[2], b[4];
#pragma unroll
    for (int m = 0; m < 2; ++m) {
      int ar = wm * 32 + m * 16 + lr;
      int abyte = (ar * 512 + ks * 64 + lhi * 16) ^ ((ar & 7) << 4);
      a[m] = *reinterpret_cast<const bf16x8*>(
          reinterpret_cast<const char*>(lds) + abyte);
    }
#pragma unroll
    for (int j = 0; j < 4; ++j) {
      int cb = wn * 4 + j;
      b[j] = *reinterpret_cast<const bf16x8*>(
          w2p + ((ks * 16 + cb) * 64 + lane) * 8);
    }
#pragma unroll
    for (int m = 0; m < 2; ++m)
#pragma unroll
      for (int j = 0; j < 4; ++j)
        acc[m][j] = __builtin_amdgcn_mfma_f32_16x16x32_bf16(a[m], b[j],
                                                            acc[m][j], 0, 0, 0);
  }
  __syncthreads();  // all z reads done; tile will hold delta

  // delta (+b2, bf16) into LDS stripe.
#pragma unroll
  for (int m = 0; m < 2; ++m)
#pragma unroll
    for (int j = 0; j < 4; ++j) {
      int col = wn * 64 + j * 16 + lr;
      float bias = b2[col];
#pragma unroll
      for (int r = 0; r < 4; ++r) {
        float d = acc[m][j][r] + bias;
        int zr = wm * 32 + m * 16 + lhi * 4 + r;
        int byte = (zr * 512 + col * 2) ^ ((zr & 7) << 4);
        *reinterpret_cast<short*>(reinterpret_cast<char*>(lds) + byte) = f2bf(d);
      }
    }
  __syncthreads();

  // Vectorized epilogue: thread t -> row t>>3, 32 cols (4 x bf16x8).
  // Residual from bf16 hb when available (L3-hit) else f32 h.
  {
    int row = tid >> 3;
    int sub = tid & 7;
    int grow = row0 + row;
    if (grow < n) {
      float mask = counts[grow] > 0 ? 1.0f : 0.0f;
      float* orow = out + (size_t)grow * H;
      if (hres) {
        const short* hrow = hres + (size_t)grow * H;
#pragma unroll
        for (int u = 0; u < 4; ++u) {
          int col = sub * 8 + u * 64;
          int byte = (row * 512 + col * 2) ^ ((row & 7) << 4);
          bf16x8 dv = *reinterpret_cast<const bf16x8*>(
              reinterpret_cast<const char*>(lds) + byte);
          bf16x8 hv = *reinterpret_cast<const bf16x8*>(hrow + col);
          f32x4 o0, o1;
          o0.x = bf2f(hv[0]) + bf2f(dv[0]) * mask;
          o0.y = bf2f(hv[1]) + bf2f(dv[1]) * mask;
          o0.z = bf2f(hv[2]) + bf2f(dv[2]) * mask;
          o0.w = bf2f(hv[3]) + bf2f(dv[3]) * mask;
          o1.x = bf2f(hv[4]) + bf2f(dv[4]) * mask;
          o1.y = bf2f(hv[5]) + bf2f(dv[5]) * mask;
          o1.z = bf2f(hv[6]) + bf2f(dv[6]) * mask;
          o1.w = bf2f(hv[7]) + bf2f(dv[7]) * mask;
          *reinterpret_cast<f32x4*>(orow + col) = o0;
          *reinterpret_cast<f32x4*>(orow + col + 4) = o1;
        }
      } else {
        const float* hrow = h + (size_t)grow * H;
#pragma unroll
        for (int u = 0; u < 4; ++u) {
          int col = sub * 8 + u * 64;
          int byte = (row * 512 + col * 2) ^ ((row & 7) << 4);
          bf16x8 dv = *reinterpret_cast<const bf16x8*>(
              reinterpret_cast<const char*>(lds) + byte);
          f32x4 h0 = *reinterpret_cast<const f32x4*>(hrow + col);
          f32x4 h1 = *reinterpret_cast<const f32x4*>(hrow + col + 4);
          f32x4 o0, o1;
          o0.x = h0.x + bf2f(dv[0]) * mask;
          o0.y = h0.y + bf2f(dv[1]) * mask;
          o0.z = h0.z + bf2f(dv[2]) * mask;
          o0.w = h0.w + bf2f(dv[3]) * mask;
          o1.x = h1.x + bf2f(dv[4]) * mask;
          o1.y = h1.y + bf2f(dv[5]) * mask;
          o1.z = h1.z + bf2f(dv[6]) * mask;
          o1.w = h1.w + bf2f(dv[7]) * mask;
          *reinterpret_cast<f32x4*>(orow + col) = o0;
          *reinterpret_cast<f32x4*>(orow + col + 4) = o1;
        }
      }
    }
  }
}

// ---------------- mid fallback: fused gather+MLP (linear weights) ---------
__global__ __launch_bounds__(256) void fused_kernel(
    const float* __restrict__ h, const int* __restrict__ childlist,
    const int* __restrict__ offsets, const int* __restrict__ counts,
    const short* __restrict__ w1b, const short* __restrict__ w2b,
    const float* __restrict__ b1, const float* __restrict__ b2,
    float* __restrict__ out, int n) {
  __shared__ short lds[TILE_M * H];

  const int tid = threadIdx.x;
  const int row0 = blockIdx.x * TILE_M;
  const int lane = tid & 63;
  const int wv = tid >> 6;
  const int wrow = wv * 16;
  const int lr = lane & 15;
  const int lhi = lane >> 4;

  int rid = row0 + wrow + lr;
  if (rid >= n) rid = n - 1;
  const int myc = counts[rid];
  const int myo = offsets[rid];

  for (int rr = 0; rr < 16; ++rr) {
    int deg = __shfl(myc, rr);
    int off = __shfl(myo, rr);
    int degc = deg < 64 ? deg : 64;
    int cidx = 0;
    if (lane < degc) cidx = childlist[off + lane];
    f32x4 acc = {0.f, 0.f, 0.f, 0.f};
    int i = 0;
    for (; i + 4 <= degc; i += 4) {
      int c0 = __shfl(cidx, i);
      int c1 = __shfl(cidx, i + 1);
      int c2 = __shfl(cidx, i + 2);
      int c3 = __shfl(cidx, i + 3);
      f32x4 v0 = ((const f32x4*)(h + (size_t)c0 * H))[lane];
      f32x4 v1 = ((const f32x4*)(h + (size_t)c1 * H))[lane];
      f32x4 v2 = ((const f32x4*)(h + (size_t)c2 * H))[lane];
      f32x4 v3 = ((const f32x4*)(h + (size_t)c3 * H))[lane];
      acc += v0 + v1 + v2 + v3;
    }
    for (; i < degc; ++i) {
      int c = __shfl(cidx, i);
      acc += ((const f32x4*)(h + (size_t)c * H))[lane];
    }
    for (; i < deg; ++i) {
      int c = childlist[off + i];
      acc += ((const f32x4*)(h + (size_t)c * H))[lane];
    }
    float inv = 1.0f / (float)(deg > 0 ? deg : 1);
    acc *= inv;
    s16x4 bv;
    bv.x = f2bf(acc.x);
    bv.y = f2bf(acc.y);
    bv.z = f2bf(acc.z);
    bv.w = f2bf(acc.w);
    int r = wrow + rr;
    int byte = (r * 512 + lane * 8) ^ ((r & 7) << 4);
    *reinterpret_cast<s16x4*>(reinterpret_cast<char*>(lds) + byte) = bv;
  }
  __syncthreads();

  const f32x4 zero4 = {0.f, 0.f, 0.f, 0.f};
  f32x4 acc[4][4];
#pragma unroll
  for (int m = 0; m < 4; ++m)
#pragma unroll
    for (int j = 0; j < 4; ++j) acc[m][j] = zero4;

#pragma unroll
  for (int ks = 0; ks < 8; ++ks) {
    bf16x8 a[4], b[4];
#pragma unroll
    for (int m = 0; m < 4; ++m) {
      int ar = m * 16 + lr;
      int abyte = (ar * 512 + ks * 64 + lhi * 16) ^ ((ar & 7) << 4);
      a[m] = *reinterpret_cast<const bf16x8*>(
          reinterpret_cast<const char*>(lds) + abyte);
    }
#pragma unroll
    for (int j = 0; j < 4; ++j) {
      int col = wv * 64 + j * 16 + lr;
      b[j] = *reinterpret_cast<const bf16x8*>(w1b + col * H + ks * 32 + lhi * 8);
    }
#pragma unroll
    for (int m = 0; m < 4; ++m)
#pragma unroll
      for (int j = 0; j < 4; ++j)
        acc[m][j] = __builtin_amdgcn_mfma_f32_16x16x32_bf16(a[m], b[j],
                                                            acc[m][j], 0, 0, 0);
  }
  __syncthreads();

#pragma unroll
  for (int m = 0; m < 4; ++m)
#pragma unroll
    for (int j = 0; j < 4; ++j) {
      int col = wv * 64 + j * 16 + lr;
      float bias = b1[col];
#pragma unroll
      for (int r = 0; r < 4; ++r) {
        float z = acc[m][j][r] + bias;
        z = z >= 0.f ? z : NEG_SLOPE * z;
        int zr = m * 16 + lhi * 4 + r;
        int byte = (zr * 512 + col * 2) ^ ((zr & 7) << 4);
        *reinterpret_cast<short*>(reinterpret_cast<char*>(lds) + byte) = f2bf(z);
      }
    }
  __syncthreads();

#pragma unroll
  for (int m = 0; m < 4; ++m)
#pragma unroll
    for (int j = 0; j < 4; ++j) acc[m][j] = zero4;

#pragma unroll
  for (int ks = 0; ks < 8; ++ks) {
    bf16x8 a[4], b[4];
#pragma unroll
    for (int m = 0; m < 4; ++m) {
      int ar = m * 16 + lr;
      int abyte = (ar * 512 + ks * 64 + lhi * 16) ^ ((ar & 7) << 4);
      a[m] = *reinterpret_cast<const bf16x8*>(
          reinterpret_cast<const char*>(lds) + abyte);
    }
#pragma unroll
    for (int j = 0; j < 4; ++j) {
      int col = wv * 64 + j * 16 + lr;
      b[j] = *reinterpret_cast<const bf16x8*>(w2b + col * H + ks * 32 + lhi * 8);
    }
#pragma unroll
    for (int m = 0; m < 4; ++m)
#pragma unroll
      for (int j = 0; j < 4; ++j)
        acc[m][j] = __builtin_amdgcn_mfma_f32_16x16x32_bf16(a[m], b[j],
                                                            acc[m][j], 0, 0, 0);
  }

#pragma unroll
  for (int m = 0; m < 4; ++m) {
#pragma unroll
    for (int r = 0; r < 4; ++r) {
      int grow = row0 + m * 16 + lhi * 4 + r;
      if (grow < n) {
        float mask = counts[grow] > 0 ? 1.0f : 0.0f;
        const float* hrow = h + (size_t)grow * H;
        float* orow = out + (size_t)grow * H;
#pragma unroll
        for (int j = 0; j < 4; ++j) {
          int col = wv * 64 + j * 16 + lr;
          orow[col] = hrow[col] + (acc[m][j][r] + b2[col]) * mask;
        }
      }
    }
  }
}

// ---------------- last-resort fallback: atomic agg ----------------
__global__ __launch_bounds__(256) void agg_kernel(
    const float* __restrict__ h, const int* __restrict__ parent,
    const int* __restrict__ child, float* __restrict__ sums,
    int* __restrict__ counts, int E) {
  int gid = blockIdx.x * blockDim.x + threadIdx.x;
  int e = gid >> 6;
  if (e >= E) return;
  int lane = threadIdx.x & 63;
  int p = parent[e];
  int c = child[e];
  f32x4 v = ((const f32x4*)(h + (size_t)c * H))[lane];
  float* dst = sums + (size_t)p * H + lane * 4;
  unsafeAtomicAdd(dst + 0, v.x);
  unsafeAtomicAdd(dst + 1, v.y);
  unsafeAtomicAdd(dst + 2, v.z);
  unsafeAtomicAdd(dst + 3, v.w);
  if (lane == 0) atomicAdd(counts + p, 1);
}

__global__ __launch_bounds__(256) void mean_div_bf16_kernel(
    const float* __restrict__ sums, const int* __restrict__ counts,
    short* __restrict__ meansb, int n) {
  int w = (blockIdx.x * blockDim.x + threadIdx.x) >> 6;
  if (w >= n) return;
  int lane = threadIdx.x & 63;
  float inv = 1.0f / fmaxf((float)counts[w], 1.0f);
  f32x4 v = ((const f32x4*)(sums + (size_t)w * H))[lane];
  v *= inv;
  s16x4 bv;
  bv.x = f2bf(v.x);
  bv.y = f2bf(v.y);
  bv.z = f2bf(v.z);
  bv.w = f2bf(v.w);
  *reinterpret_cast<s16x4*>(meansb + (size_t)w * H + lane * 4) = bv;
}

extern "C" void kernel_launch(void* const* d_in, const int* in_sizes, int n_in,
                              void* d_out, int out_size, void* d_ws, size_t ws_size,
                              hipStream_t stream) {
  const float* h  = (const float*)d_in[0];
  const int* edges = (const int*)d_in[1];
  const float* W1 = (const float*)d_in[2];
  const float* b1 = (const float*)d_in[3];
  const float* W2 = (const float*)d_in[4];
  const float* b2 = (const float*)d_in[5];
  float* out = (float*)d_out;

  const int n = in_sizes[0] / H;   // 200000
  const int E = in_sizes[1] / 2;   // 1000000
  const int* parent = edges;
  const int* child = edges + E;

  char* ws = (char*)d_ws;
  int* counts    = (int*)(ws);                // n ints (800 KB)
  short* w1b     = (short*)(ws + 0x100000);   // 128 KB linear
  short* w2b     = (short*)(ws + 0x120000);   // 128 KB linear
  short* w1p     = (short*)(ws + 0x140000);   // 128 KB packed
  short* w2p     = (short*)(ws + 0x160000);   // 128 KB packed
  int* excl      = (int*)(ws + 0x180000);     // n ints
  int* cursor    = (int*)(ws + 0x280000);     // n ints
  int* blockSums = (int*)(ws + 0x380000);     // 256 ints
  int* offsets   = (int*)(ws + 0x384000);     // n ints
  int* childlist = (int*)(ws + 0x484000);     // E ints (4 MB @ E=1M)
  short* meansb  = (short*)(ws + 0x884000);   // n*H bf16 (102.4 MB)
  size_t meansz  = (size_t)n * H * 2;
  short* hb      = (short*)(ws + 0x884000 + meansz);  // n*H bf16 (102.4 MB)

  size_t need_csr  = 0x484000 + (size_t)E * 4;
  size_t need_full = 0x884000 + meansz;
  size_t need_hb   = need_full + meansz;
  int nblk64 = (n + TILE_M - 1) / TILE_M;

  cvt_kernel<<<(H * H + 255) / 256, 256, 0, stream>>>(W1, W2, w1b, w2b, w1p, w2p);

  if (ws_size >= need_full && E <= (0x400000 / 4) && n <= 256 * 1024) {
    hipMemsetAsync(counts, 0, (size_t)n * sizeof(int), stream);
    if (ws_size >= need_hb) {
      long total8 = (long)n * H / 8;
      int nbCvt = (int)((total8 + 255) / 256);
      int nbHist = (E + 255) / 256;
      prep_kernel<<<nbCvt + nbHist, 256, 0, stream>>>(h, hb, total8, parent,
                                                      counts, E, nbCvt);
    } else {
      hist_kernel<<<(E + 255) / 256, 256, 0, stream>>>(parent, counts, E);
    }
    int nb = (n + 1023) >> 10;
    scan1_kernel<<<nb, 256, 0, stream>>>(counts, excl, blockSums, n);
    scan2_kernel<<<1, 256, 0, stream>>>(blockSums, nb);
    scan3_kernel<<<(n + 255) / 256, 256, 0, stream>>>(excl, blockSums, offsets,
                                                      cursor, n);
    scatter_kernel<<<(E + 255) / 256, 256, 0, stream>>>(parent, child, cursor,
                                                        childlist, E);
    if (ws_size >= need_hb) {
      gather_mean_kernel<<<((size_t)n * 64 + 255) / 256, 256, 0, stream>>>(
          hb, childlist, offsets, counts, meansb, n);
      mlp2_kernel<<<nblk64, 512, 0, stream>>>(h, hb, meansb, counts, w1p, w2p,
                                              b1, b2, out, n);
    } else {
      gather_mean_f32_kernel<<<((size_t)n * 64 + 255) / 256, 256, 0, stream>>>(
          h, childlist, offsets, counts, meansb, n);
      mlp2_kernel<<<nblk64, 512, 0, stream>>>(h, nullptr, meansb, counts, w1p,
                                              w2p, b1, b2, out, n);
    }
  } else if (ws_size >= need_csr && n <= 256 * 1024) {
    hipMemsetAsync(counts, 0, (size_t)n * sizeof(int), stream);
    hist_kernel<<<(E + 255) / 256, 256, 0, stream>>>(parent, counts, E);
    int nb = (n + 1023) >> 10;
    scan1_kernel<<<nb, 256, 0, stream>>>(counts, excl, blockSums, n);
    scan2_kernel<<<1, 256, 0, stream>>>(blockSums, nb);
    scan3_kernel<<<(n + 255) / 256, 256, 0, stream>>>(excl, blockSums, offsets,
                                                      cursor, n);
    scatter_kernel<<<(E + 255) / 256, 256, 0, stream>>>(parent, child, cursor,
                                                        childlist, E);
    fused_kernel<<<nblk64, 256, 0, stream>>>(h, childlist, offsets, counts, w1b,
                                             w2b, b1, b2, out, n);
  } else {
    hipMemsetAsync(out, 0, (size_t)n * H * sizeof(float), stream);
    hipMemsetAsync(counts, 0, (size_t)n * sizeof(int), stream);
    agg_kernel<<<(E + 3) / 4, 256, 0, stream>>>(h, parent, child, out, counts, E);
    mean_div_bf16_kernel<<<((size_t)n * 64 + 255) / 256, 256, 0, stream>>>(
        out, counts, (short*)(ws + 0x180000), n);
    mlp2_kernel<<<nblk64, 512, 0, stream>>>(h, nullptr,
                                            (short*)(ws + 0x180000), counts,
                                            w1p, w2p, b1, b2, out, n);
  }
}

// Round 14
// 377.642 us; speedup vs baseline: 1.2934x; 1.2934x over previous
//
#include <hip/hip_runtime.h>
#include <hip/hip_bf16.h>

#define H 256
#define NEG_SLOPE 0.01f
#define TILE_M 64
#define TILE_M2 32

typedef __attribute__((ext_vector_type(4))) float f32x4;
typedef __attribute__((ext_vector_type(8))) short bf16x8;
typedef __attribute__((ext_vector_type(4))) short s16x4;

__device__ __forceinline__ short f2bf(float f) {
  __hip_bfloat16 b = __float2bfloat16(f);
  return *reinterpret_cast<short*>(&b);
}
__device__ __forceinline__ float bf2f(short s) {
  unsigned u = ((unsigned)(unsigned short)s) << 16;
  return __uint_as_float(u);
}

// ---------------- CSR build ----------------

__global__ __launch_bounds__(256) void hist_kernel(
    const int* __restrict__ parent, int* __restrict__ counts, int E) {
  int e = blockIdx.x * blockDim.x + threadIdx.x;
  if (e < E) atomicAdd(counts + parent[e], 1);
}

// Fused: blocks [0,nbCvt) convert h->hb (bf16); blocks [nbCvt,..) histogram.
__global__ __launch_bounds__(256) void prep_kernel(
    const float* __restrict__ h, short* __restrict__ hb, long total8,
    const int* __restrict__ parent, int* __restrict__ counts, int E,
    int nbCvt) {
  int b = blockIdx.x;
  if (b < nbCvt) {
    long i = (long)b * 256 + threadIdx.x;
    if (i >= total8) return;
    const f32x4* src = (const f32x4*)(h + i * 8);
    f32x4 v0 = src[0], v1 = src[1];
    bf16x8 o;
    o[0] = f2bf(v0.x); o[1] = f2bf(v0.y); o[2] = f2bf(v0.z); o[3] = f2bf(v0.w);
    o[4] = f2bf(v1.x); o[5] = f2bf(v1.y); o[6] = f2bf(v1.z); o[7] = f2bf(v1.w);
    *reinterpret_cast<bf16x8*>(hb + i * 8) = o;
  } else {
    int e = (b - nbCvt) * 256 + threadIdx.x;
    if (e < E) atomicAdd(counts + parent[e], 1);
  }
}

__global__ __launch_bounds__(256) void scan1_kernel(
    const int* __restrict__ counts, int* __restrict__ excl,
    int* __restrict__ blockSums, int n) {
  __shared__ int lds[256];
  int tid = threadIdx.x;
  int base = blockIdx.x * 1024 + tid * 4;
  int4 v = {0, 0, 0, 0};
  if (base + 3 < n) v = *reinterpret_cast<const int4*>(counts + base);
  int s = v.x + v.y + v.z + v.w;
  lds[tid] = s;
  __syncthreads();
  for (int off = 1; off < 256; off <<= 1) {
    int t = (tid >= off) ? lds[tid - off] : 0;
    __syncthreads();
    lds[tid] += t;
    __syncthreads();
  }
  int toff = lds[tid] - s;
  if (base + 3 < n) {
    int4 o;
    o.x = toff;
    o.y = toff + v.x;
    o.z = o.y + v.y;
    o.w = o.z + v.z;
    *reinterpret_cast<int4*>(excl + base) = o;
  }
  if (tid == 255) blockSums[blockIdx.x] = lds[255];
}

__global__ __launch_bounds__(256) void scan2_kernel(int* __restrict__ blockSums,
                                                    int nb) {
  __shared__ int lds[256];
  int tid = threadIdx.x;
  int s = (tid < nb) ? blockSums[tid] : 0;
  lds[tid] = s;
  __syncthreads();
  for (int off = 1; off < 256; off <<= 1) {
    int t = (tid >= off) ? lds[tid - off] : 0;
    __syncthreads();
    lds[tid] += t;
    __syncthreads();
  }
  if (tid < nb) blockSums[tid] = lds[tid] - s;
}

__global__ __launch_bounds__(256) void scan3_kernel(
    const int* __restrict__ excl, const int* __restrict__ blockSums,
    int* __restrict__ offsets, int* __restrict__ cursor, int n) {
  int i = blockIdx.x * blockDim.x + threadIdx.x;
  if (i < n) {
    int v = excl[i] + blockSums[i >> 10];
    offsets[i] = v;
    cursor[i] = v;
  }
}

__global__ __launch_bounds__(256) void scatter_kernel(
    const int* __restrict__ parent, const int* __restrict__ child,
    int* __restrict__ cursor, int* __restrict__ childlist, int E) {
  int e = blockIdx.x * blockDim.x + threadIdx.x;
  if (e < E) {
    int pos = atomicAdd(cursor + parent[e], 1);
    childlist[pos] = child[e];
  }
}

// Linear bf16 copies + fragment-packed copies.
__global__ __launch_bounds__(256) void cvt_kernel(
    const float* __restrict__ W1, const float* __restrict__ W2,
    short* __restrict__ w1b, short* __restrict__ w2b,
    short* __restrict__ w1p, short* __restrict__ w2p) {
  int i = blockIdx.x * blockDim.x + threadIdx.x;
  if (i < H * H) {
    short v1 = f2bf(W1[i]);
    short v2 = f2bf(W2[i]);
    w1b[i] = v1;
    w2b[i] = v2;
    int col = i >> 8, k = i & 255;
    int ks = k >> 5, lhi = (k >> 3) & 3, e = k & 7;
    int cb = col >> 4, lrr = col & 15;
    int pos = ((ks * 16 + cb) * 64 + lhi * 16 + lrr) * 8 + e;
    w1p[pos] = v1;
    w2p[pos] = v2;
  }
}

// ---------------- gather-mean from bf16 h: one wave per parent -------------
__global__ __launch_bounds__(256) void gather_mean_kernel(
    const short* __restrict__ hb, const int* __restrict__ childlist,
    const int* __restrict__ offsets, const int* __restrict__ counts,
    short* __restrict__ meansb, int n) {
  int w = (blockIdx.x * blockDim.x + threadIdx.x) >> 6;
  if (w >= n) return;
  int lane = threadIdx.x & 63;
  int deg = counts[w];
  int off = offsets[w];
  int degc = deg < 64 ? deg : 64;
  int cidx = 0;
  if (lane < degc) cidx = childlist[off + lane];  // one coalesced index load
  f32x4 acc = {0.f, 0.f, 0.f, 0.f};
  int i = 0;
  for (; i + 4 <= degc; i += 4) {
    int c0 = __shfl(cidx, i);
    int c1 = __shfl(cidx, i + 1);
    int c2 = __shfl(cidx, i + 2);
    int c3 = __shfl(cidx, i + 3);
    s16x4 v0 = ((const s16x4*)(hb + (size_t)c0 * H))[lane];
    s16x4 v1 = ((const s16x4*)(hb + (size_t)c1 * H))[lane];
    s16x4 v2 = ((const s16x4*)(hb + (size_t)c2 * H))[lane];
    s16x4 v3 = ((const s16x4*)(hb + (size_t)c3 * H))[lane];
    acc.x += bf2f(v0.x) + bf2f(v1.x) + bf2f(v2.x) + bf2f(v3.x);
    acc.y += bf2f(v0.y) + bf2f(v1.y) + bf2f(v2.y) + bf2f(v3.y);
    acc.z += bf2f(v0.z) + bf2f(v1.z) + bf2f(v2.z) + bf2f(v3.z);
    acc.w += bf2f(v0.w) + bf2f(v1.w) + bf2f(v2.w) + bf2f(v3.w);
  }
  for (; i < degc; ++i) {
    int c = __shfl(cidx, i);
    s16x4 v = ((const s16x4*)(hb + (size_t)c * H))[lane];
    acc.x += bf2f(v.x);
    acc.y += bf2f(v.y);
    acc.z += bf2f(v.z);
    acc.w += bf2f(v.w);
  }
  for (; i < deg; ++i) {  // deg > 64 cold path
    int c = childlist[off + i];
    s16x4 v = ((const s16x4*)(hb + (size_t)c * H))[lane];
    acc.x += bf2f(v.x);
    acc.y += bf2f(v.y);
    acc.z += bf2f(v.z);
    acc.w += bf2f(v.w);
  }
  float inv = 1.0f / (float)(deg > 0 ? deg : 1);
  acc *= inv;
  s16x4 bv;
  bv.x = f2bf(acc.x);
  bv.y = f2bf(acc.y);
  bv.z = f2bf(acc.z);
  bv.w = f2bf(acc.w);
  *reinterpret_cast<s16x4*>(meansb + (size_t)w * H + lane * 4) = bv;
}

// Fallback: gather from f32 h (when ws has no room for hb).
__global__ __launch_bounds__(256) void gather_mean_f32_kernel(
    const float* __restrict__ h, const int* __restrict__ childlist,
    const int* __restrict__ offsets, const int* __restrict__ counts,
    short* __restrict__ meansb, int n) {
  int w = (blockIdx.x * blockDim.x + threadIdx.x) >> 6;
  if (w >= n) return;
  int lane = threadIdx.x & 63;
  int deg = counts[w];
  int off = offsets[w];
  int degc = deg < 64 ? deg : 64;
  int cidx = 0;
  if (lane < degc) cidx = childlist[off + lane];
  f32x4 acc = {0.f, 0.f, 0.f, 0.f};
  int i = 0;
  for (; i + 4 <= degc; i += 4) {
    int c0 = __shfl(cidx, i);
    int c1 = __shfl(cidx, i + 1);
    int c2 = __shfl(cidx, i + 2);
    int c3 = __shfl(cidx, i + 3);
    f32x4 v0 = ((const f32x4*)(h + (size_t)c0 * H))[lane];
    f32x4 v1 = ((const f32x4*)(h + (size_t)c1 * H))[lane];
    f32x4 v2 = ((const f32x4*)(h + (size_t)c2 * H))[lane];
    f32x4 v3 = ((const f32x4*)(h + (size_t)c3 * H))[lane];
    acc += v0 + v1 + v2 + v3;
  }
  for (; i < degc; ++i) {
    int c = __shfl(cidx, i);
    acc += ((const f32x4*)(h + (size_t)c * H))[lane];
  }
  for (; i < deg; ++i) {
    int c = childlist[off + i];
    acc += ((const f32x4*)(h + (size_t)c * H))[lane];
  }
  float inv = 1.0f / (float)(deg > 0 ? deg : 1);
  acc *= inv;
  s16x4 bv;
  bv.x = f2bf(acc.x);
  bv.y = f2bf(acc.y);
  bv.z = f2bf(acc.z);
  bv.w = f2bf(acc.w);
  *reinterpret_cast<s16x4*>(meansb + (size_t)w * H + lane * 4) = bv;
}

// ---------------- MLP v8: 256-thread blocks, TILE_M2=32 ----------------
// R13 law: any min-waves>4 at 512 threads spills (VGPR cap collapse).
// Instead: smaller blocks at (256,4) — VGPR cap 128 (no spill for our ~64),
// 4+ blocks/CU resident, finer-grain phase overlap, smaller tail.
// Wave wn (0..3): all 32 rows x cols wn*64..+64, acc[2][4]. LDS 16 KB.
__global__ __launch_bounds__(256, 4) void mlp2_kernel(
    const float* __restrict__ h, const short* __restrict__ hres,
    const short* __restrict__ meansb, const int* __restrict__ counts,
    const short* __restrict__ w1p, const short* __restrict__ w2p,
    const float* __restrict__ b1, const float* __restrict__ b2,
    float* __restrict__ out, int n) {
  __shared__ short lds[TILE_M2 * H];  // 16 KB: means tile -> z tile -> delta

  const int tid = threadIdx.x;
  const int row0 = blockIdx.x * TILE_M2;
  const int lane = tid & 63;
  const int wn = tid >> 6;     // 0..3 (col stripe)
  const int lr = lane & 15;
  const int lhi = lane >> 4;

  // ---- Stage means -> LDS (coalesced 4KB bursts, XOR-swizzled) ----
#pragma unroll
  for (int v = 0; v < 4; ++v) {
    int lin = v * 4096 + tid * 16;          // byte index in 16KB tile
    int row = lin >> 9;                     // 0..31
    int grow = row0 + row;
    if (grow >= n) grow = n - 1;
    bf16x8 mv = *reinterpret_cast<const bf16x8*>(
        meansb + (size_t)grow * H + ((lin & 511) >> 1));
    int byte = lin ^ ((row & 7) << 4);
    *reinterpret_cast<bf16x8*>(reinterpret_cast<char*>(lds) + byte) = mv;
  }
  __syncthreads();

  const f32x4 zero4 = {0.f, 0.f, 0.f, 0.f};
  f32x4 acc[2][4];
#pragma unroll
  for (int m = 0; m < 2; ++m)
#pragma unroll
    for (int j = 0; j < 4; ++j) acc[m][j] = zero4;

  // ---- Layer 1: z = mean @ W1^T ----
#pragma unroll
  for (int ks = 0; ks < 8; ++ks) {
    bf16x8 a[2], b[4];
#pragma unroll
    for (int m = 0; m < 2; ++m) {
      int ar = m * 16 + lr;                 // 0..31
      int abyte = (ar * 512 + ks * 64 + lhi * 16) ^ ((ar & 7) << 4);
      a[m] = *reinterpret_cast<const bf16x8*>(
          reinterpret_cast<const char*>(lds) + abyte);
    }
#pragma unroll
    for (int j = 0; j < 4; ++j) {
      int cb = wn * 4 + j;
      b[j] = *reinterpret_cast<const bf16x8*>(
          w1p + ((ks * 16 + cb) * 64 + lane) * 8);
    }
#pragma unroll
    for (int m = 0; m < 2; ++m)
#pragma unroll
      for (int j = 0; j < 4; ++j)
        acc[m][j] = __builtin_amdgcn_mfma_f32_16x16x32_bf16(a[m], b[j],
                                                            acc[m][j], 0, 0, 0);
  }
  __syncthreads();  // all means reads done; tile will hold z

  // z (activated, bf16) into LDS stripe.
#pragma unroll
  for (int m = 0; m < 2; ++m)
#pragma unroll
    for (int j = 0; j < 4; ++j) {
      int col = wn * 64 + j * 16 + lr;
      float bias = b1[col];
#pragma unroll
      for (int r = 0; r < 4; ++r) {
        float z = acc[m][j][r] + bias;
        z = z >= 0.f ? z : NEG_SLOPE * z;
        int zr = m * 16 + lhi * 4 + r;      // 0..31
        int byte = (zr * 512 + col * 2) ^ ((zr & 7) << 4);
        *reinterpret_cast<short*>(reinterpret_cast<char*>(lds) + byte) = f2bf(z);
      }
    }
  __syncthreads();

  // ---- Layer 2: delta = z @ W2^T ----
#pragma unroll
  for (int m = 0; m < 2; ++m)
#pragma unroll
    for (int j = 0; j < 4; ++j) acc[m][j] = zero4;

#pragma unroll
  for (int ks = 0; ks < 8; ++ks) {
    bf16x8 a[2], b[4];
#pragma unroll
    for (int m = 0; m < 2; ++m) {
      int ar = m * 16 + lr;
      int abyte = (ar * 512 + ks * 64 + lhi * 16) ^ ((ar & 7) << 4);
      a[m] = *reinterpret_cast<const bf16x8*>(
          reinterpret_cast<const char*>(lds) + abyte);
    }
#pragma unroll
    for (int j = 0; j < 4; ++j) {
      int cb = wn * 4 + j;
      b[j] = *reinterpret_cast<const bf16x8*>(
          w2p + ((ks * 16 + cb) * 64 + lane) * 8);
    }
#pragma unroll
    for (int m = 0; m < 2; ++m)
#pragma unroll
      for (int j = 0; j < 4; ++j)
        acc[m][j] = __builtin_amdgcn_mfma_f32_16x16x32_bf16(a[m], b[j],
                                                            acc[m][j], 0, 0, 0);
  }
  __syncthreads();  // all z reads done; tile will hold delta

  // delta (+b2, bf16) into LDS stripe.
#pragma unroll
  for (int m = 0; m < 2; ++m)
#pragma unroll
    for (int j = 0; j < 4; ++j) {
      int col = wn * 64 + j * 16 + lr;
      float bias = b2[col];
#pragma unroll
      for (int r = 0; r < 4; ++r) {
        float d = acc[m][j][r] + bias;
        int zr = m * 16 + lhi * 4 + r;
        int byte = (zr * 512 + col * 2) ^ ((zr & 7) << 4);
        *reinterpret_cast<short*>(reinterpret_cast<char*>(lds) + byte) = f2bf(d);
      }
    }
  __syncthreads();

  // Vectorized epilogue: thread t -> row t>>3, 32 cols (4 x bf16x8).
  {
    int row = tid >> 3;                     // 0..31
    int sub = tid & 7;
    int grow = row0 + row;
    if (grow < n) {
      float mask = counts[grow] > 0 ? 1.0f : 0.0f;
      float* orow = out + (size_t)grow * H;
      if (hres) {
        const short* hrow = hres + (size_t)grow * H;
#pragma unroll
        for (int u = 0; u < 4; ++u) {
          int col = sub * 8 + u * 64;
          int byte = (row * 512 + col * 2) ^ ((row & 7) << 4);
          bf16x8 dv = *reinterpret_cast<const bf16x8*>(
              reinterpret_cast<const char*>(lds) + byte);
          bf16x8 hv = *reinterpret_cast<const bf16x8*>(hrow + col);
          f32x4 o0, o1;
          o0.x = bf2f(hv[0]) + bf2f(dv[0]) * mask;
          o0.y = bf2f(hv[1]) + bf2f(dv[1]) * mask;
          o0.z = bf2f(hv[2]) + bf2f(dv[2]) * mask;
          o0.w = bf2f(hv[3]) + bf2f(dv[3]) * mask;
          o1.x = bf2f(hv[4]) + bf2f(dv[4]) * mask;
          o1.y = bf2f(hv[5]) + bf2f(dv[5]) * mask;
          o1.z = bf2f(hv[6]) + bf2f(dv[6]) * mask;
          o1.w = bf2f(hv[7]) + bf2f(dv[7]) * mask;
          *reinterpret_cast<f32x4*>(orow + col) = o0;
          *reinterpret_cast<f32x4*>(orow + col + 4) = o1;
        }
      } else {
        const float* hrow = h + (size_t)grow * H;
#pragma unroll
        for (int u = 0; u < 4; ++u) {
          int col = sub * 8 + u * 64;
          int byte = (row * 512 + col * 2) ^ ((row & 7) << 4);
          bf16x8 dv = *reinterpret_cast<const bf16x8*>(
              reinterpret_cast<const char*>(lds) + byte);
          f32x4 h0 = *reinterpret_cast<const f32x4*>(hrow + col);
          f32x4 h1 = *reinterpret_cast<const f32x4*>(hrow + col + 4);
          f32x4 o0, o1;
          o0.x = h0.x + bf2f(dv[0]) * mask;
          o0.y = h0.y + bf2f(dv[1]) * mask;
          o0.z = h0.z + bf2f(dv[2]) * mask;
          o0.w = h0.w + bf2f(dv[3]) * mask;
          o1.x = h1.x + bf2f(dv[4]) * mask;
          o1.y = h1.y + bf2f(dv[5]) * mask;
          o1.z = h1.z + bf2f(dv[6]) * mask;
          o1.w = h1.w + bf2f(dv[7]) * mask;
          *reinterpret_cast<f32x4*>(orow + col) = o0;
          *reinterpret_cast<f32x4*>(orow + col + 4) = o1;
        }
      }
    }
  }
}

// ---------------- mid fallback: fused gather+MLP (linear weights) ---------
__global__ __launch_bounds__(256) void fused_kernel(
    const float* __restrict__ h, const int* __restrict__ childlist,
    const int* __restrict__ offsets, const int* __restrict__ counts,
    const short* __restrict__ w1b, const short* __restrict__ w2b,
    const float* __restrict__ b1, const float* __restrict__ b2,
    float* __restrict__ out, int n) {
  __shared__ short lds[TILE_M * H];

  const int tid = threadIdx.x;
  const int row0 = blockIdx.x * TILE_M;
  const int lane = tid & 63;
  const int wv = tid >> 6;
  const int wrow = wv * 16;
  const int lr = lane & 15;
  const int lhi = lane >> 4;

  int rid = row0 + wrow + lr;
  if (rid >= n) rid = n - 1;
  const int myc = counts[rid];
  const int myo = offsets[rid];

  for (int rr = 0; rr < 16; ++rr) {
    int deg = __shfl(myc, rr);
    int off = __shfl(myo, rr);
    int degc = deg < 64 ? deg : 64;
    int cidx = 0;
    if (lane < degc) cidx = childlist[off + lane];
    f32x4 acc = {0.f, 0.f, 0.f, 0.f};
    int i = 0;
    for (; i + 4 <= degc; i += 4) {
      int c0 = __shfl(cidx, i);
      int c1 = __shfl(cidx, i + 1);
      int c2 = __shfl(cidx, i + 2);
      int c3 = __shfl(cidx, i + 3);
      f32x4 v0 = ((const f32x4*)(h + (size_t)c0 * H))[lane];
      f32x4 v1 = ((const f32x4*)(h + (size_t)c1 * H))[lane];
      f32x4 v2 = ((const f32x4*)(h + (size_t)c2 * H))[lane];
      f32x4 v3 = ((const f32x4*)(h + (size_t)c3 * H))[lane];
      acc += v0 + v1 + v2 + v3;
    }
    for (; i < degc; ++i) {
      int c = __shfl(cidx, i);
      acc += ((const f32x4*)(h + (size_t)c * H))[lane];
    }
    for (; i < deg; ++i) {
      int c = childlist[off + i];
      acc += ((const f32x4*)(h + (size_t)c * H))[lane];
    }
    float inv = 1.0f / (float)(deg > 0 ? deg : 1);
    acc *= inv;
    s16x4 bv;
    bv.x = f2bf(acc.x);
    bv.y = f2bf(acc.y);
    bv.z = f2bf(acc.z);
    bv.w = f2bf(acc.w);
    int r = wrow + rr;
    int byte = (r * 512 + lane * 8) ^ ((r & 7) << 4);
    *reinterpret_cast<s16x4*>(reinterpret_cast<char*>(lds) + byte) = bv;
  }
  __syncthreads();

  const f32x4 zero4 = {0.f, 0.f, 0.f, 0.f};
  f32x4 acc[4][4];
#pragma unroll
  for (int m = 0; m < 4; ++m)
#pragma unroll
    for (int j = 0; j < 4; ++j) acc[m][j] = zero4;

#pragma unroll
  for (int ks = 0; ks < 8; ++ks) {
    bf16x8 a[4], b[4];
#pragma unroll
    for (int m = 0; m < 4; ++m) {
      int ar = m * 16 + lr;
      int abyte = (ar * 512 + ks * 64 + lhi * 16) ^ ((ar & 7) << 4);
      a[m] = *reinterpret_cast<const bf16x8*>(
          reinterpret_cast<const char*>(lds) + abyte);
    }
#pragma unroll
    for (int j = 0; j < 4; ++j) {
      int col = wv * 64 + j * 16 + lr;
      b[j] = *reinterpret_cast<const bf16x8*>(w1b + col * H + ks * 32 + lhi * 8);
    }
#pragma unroll
    for (int m = 0; m < 4; ++m)
#pragma unroll
      for (int j = 0; j < 4; ++j)
        acc[m][j] = __builtin_amdgcn_mfma_f32_16x16x32_bf16(a[m], b[j],
                                                            acc[m][j], 0, 0, 0);
  }
  __syncthreads();

#pragma unroll
  for (int m = 0; m < 4; ++m)
#pragma unroll
    for (int j = 0; j < 4; ++j) {
      int col = wv * 64 + j * 16 + lr;
      float bias = b1[col];
#pragma unroll
      for (int r = 0; r < 4; ++r) {
        float z = acc[m][j][r] + bias;
        z = z >= 0.f ? z : NEG_SLOPE * z;
        int zr = m * 16 + lhi * 4 + r;
        int byte = (zr * 512 + col * 2) ^ ((zr & 7) << 4);
        *reinterpret_cast<short*>(reinterpret_cast<char*>(lds) + byte) = f2bf(z);
      }
    }
  __syncthreads();

#pragma unroll
  for (int m = 0; m < 4; ++m)
#pragma unroll
    for (int j = 0; j < 4; ++j) acc[m][j] = zero4;

#pragma unroll
  for (int ks = 0; ks < 8; ++ks) {
    bf16x8 a[4], b[4];
#pragma unroll
    for (int m = 0; m < 4; ++m) {
      int ar = m * 16 + lr;
      int abyte = (ar * 512 + ks * 64 + lhi * 16) ^ ((ar & 7) << 4);
      a[m] = *reinterpret_cast<const bf16x8*>(
          reinterpret_cast<const char*>(lds) + abyte);
    }
#pragma unroll
    for (int j = 0; j < 4; ++j) {
      int col = wv * 64 + j * 16 + lr;
      b[j] = *reinterpret_cast<const bf16x8*>(w2b + col * H + ks * 32 + lhi * 8);
    }
#pragma unroll
    for (int m = 0; m < 4; ++m)
#pragma unroll
      for (int j = 0; j < 4; ++j)
        acc[m][j] = __builtin_amdgcn_mfma_f32_16x16x32_bf16(a[m], b[j],
                                                            acc[m][j], 0, 0, 0);
  }

#pragma unroll
  for (int m = 0; m < 4; ++m) {
#pragma unroll
    for (int r = 0; r < 4; ++r) {
      int grow = row0 + m * 16 + lhi * 4 + r;
      if (grow < n) {
        float mask = counts[grow] > 0 ? 1.0f : 0.0f;
        const float* hrow = h + (size_t)grow * H;
        float* orow = out + (size_t)grow * H;
#pragma unroll
        for (int j = 0; j < 4; ++j) {
          int col = wv * 64 + j * 16 + lr;
          orow[col] = hrow[col] + (acc[m][j][r] + b2[col]) * mask;
        }
      }
    }
  }
}

// ---------------- last-resort fallback: atomic agg ----------------
__global__ __launch_bounds__(256) void agg_kernel(
    const float* __restrict__ h, const int* __restrict__ parent,
    const int* __restrict__ child, float* __restrict__ sums,
    int* __restrict__ counts, int E) {
  int gid = blockIdx.x * blockDim.x + threadIdx.x;
  int e = gid >> 6;
  if (e >= E) return;
  int lane = threadIdx.x & 63;
  int p = parent[e];
  int c = child[e];
  f32x4 v = ((const f32x4*)(h + (size_t)c * H))[lane];
  float* dst = sums + (size_t)p * H + lane * 4;
  unsafeAtomicAdd(dst + 0, v.x);
  unsafeAtomicAdd(dst + 1, v.y);
  unsafeAtomicAdd(dst + 2, v.z);
  unsafeAtomicAdd(dst + 3, v.w);
  if (lane == 0) atomicAdd(counts + p, 1);
}

__global__ __launch_bounds__(256) void mean_div_bf16_kernel(
    const float* __restrict__ sums, const int* __restrict__ counts,
    short* __restrict__ meansb, int n) {
  int w = (blockIdx.x * blockDim.x + threadIdx.x) >> 6;
  if (w >= n) return;
  int lane = threadIdx.x & 63;
  float inv = 1.0f / fmaxf((float)counts[w], 1.0f);
  f32x4 v = ((const f32x4*)(sums + (size_t)w * H))[lane];
  v *= inv;
  s16x4 bv;
  bv.x = f2bf(v.x);
  bv.y = f2bf(v.y);
  bv.z = f2bf(v.z);
  bv.w = f2bf(v.w);
  *reinterpret_cast<s16x4*>(meansb + (size_t)w * H + lane * 4) = bv;
}

extern "C" void kernel_launch(void* const* d_in, const int* in_sizes, int n_in,
                              void* d_out, int out_size, void* d_ws, size_t ws_size,
                              hipStream_t stream) {
  const float* h  = (const float*)d_in[0];
  const int* edges = (const int*)d_in[1];
  const float* W1 = (const float*)d_in[2];
  const float* b1 = (const float*)d_in[3];
  const float* W2 = (const float*)d_in[4];
  const float* b2 = (const float*)d_in[5];
  float* out = (float*)d_out;

  const int n = in_sizes[0] / H;   // 200000
  const int E = in_sizes[1] / 2;   // 1000000
  const int* parent = edges;
  const int* child = edges + E;

  char* ws = (char*)d_ws;
  int* counts    = (int*)(ws);                // n ints (800 KB)
  short* w1b     = (short*)(ws + 0x100000);   // 128 KB linear
  short* w2b     = (short*)(ws + 0x120000);   // 128 KB linear
  short* w1p     = (short*)(ws + 0x140000);   // 128 KB packed
  short* w2p     = (short*)(ws + 0x160000);   // 128 KB packed
  int* excl      = (int*)(ws + 0x180000);     // n ints
  int* cursor    = (int*)(ws + 0x280000);     // n ints
  int* blockSums = (int*)(ws + 0x380000);     // 256 ints
  int* offsets   = (int*)(ws + 0x384000);     // n ints
  int* childlist = (int*)(ws + 0x484000);     // E ints (4 MB @ E=1M)
  short* meansb  = (short*)(ws + 0x884000);   // n*H bf16 (102.4 MB)
  size_t meansz  = (size_t)n * H * 2;
  short* hb      = (short*)(ws + 0x884000 + meansz);  // n*H bf16 (102.4 MB)

  size_t need_csr  = 0x484000 + (size_t)E * 4;
  size_t need_full = 0x884000 + meansz;
  size_t need_hb   = need_full + meansz;
  int nblk64 = (n + TILE_M - 1) / TILE_M;
  int nblk32 = (n + TILE_M2 - 1) / TILE_M2;

  cvt_kernel<<<(H * H + 255) / 256, 256, 0, stream>>>(W1, W2, w1b, w2b, w1p, w2p);

  if (ws_size >= need_full && E <= (0x400000 / 4) && n <= 256 * 1024) {
    hipMemsetAsync(counts, 0, (size_t)n * sizeof(int), stream);
    if (ws_size >= need_hb) {
      long total8 = (long)n * H / 8;
      int nbCvt = (int)((total8 + 255) / 256);
      int nbHist = (E + 255) / 256;
      prep_kernel<<<nbCvt + nbHist, 256, 0, stream>>>(h, hb, total8, parent,
                                                      counts, E, nbCvt);
    } else {
      hist_kernel<<<(E + 255) / 256, 256, 0, stream>>>(parent, counts, E);
    }
    int nb = (n + 1023) >> 10;
    scan1_kernel<<<nb, 256, 0, stream>>>(counts, excl, blockSums, n);
    scan2_kernel<<<1, 256, 0, stream>>>(blockSums, nb);
    scan3_kernel<<<(n + 255) / 256, 256, 0, stream>>>(excl, blockSums, offsets,
                                                      cursor, n);
    scatter_kernel<<<(E + 255) / 256, 256, 0, stream>>>(parent, child, cursor,
                                                        childlist, E);
    if (ws_size >= need_hb) {
      gather_mean_kernel<<<((size_t)n * 64 + 255) / 256, 256, 0, stream>>>(
          hb, childlist, offsets, counts, meansb, n);
      mlp2_kernel<<<nblk32, 256, 0, stream>>>(h, hb, meansb, counts, w1p, w2p,
                                              b1, b2, out, n);
    } else {
      gather_mean_f32_kernel<<<((size_t)n * 64 + 255) / 256, 256, 0, stream>>>(
          h, childlist, offsets, counts, meansb, n);
      mlp2_kernel<<<nblk32, 256, 0, stream>>>(h, nullptr, meansb, counts, w1p,
                                              w2p, b1, b2, out, n);
    }
  } else if (ws_size >= need_csr && n <= 256 * 1024) {
    hipMemsetAsync(counts, 0, (size_t)n * sizeof(int), stream);
    hist_kernel<<<(E + 255) / 256, 256, 0, stream>>>(parent, counts, E);
    int nb = (n + 1023) >> 10;
    scan1_kernel<<<nb, 256, 0, stream>>>(counts, excl, blockSums, n);
    scan2_kernel<<<1, 256, 0, stream>>>(blockSums, nb);
    scan3_kernel<<<(n + 255) / 256, 256, 0, stream>>>(excl, blockSums, offsets,
                                                      cursor, n);
    scatter_kernel<<<(E + 255) / 256, 256, 0, stream>>>(parent, child, cursor,
                                                        childlist, E);
    fused_kernel<<<nblk64, 256, 0, stream>>>(h, childlist, offsets, counts, w1b,
                                             w2b, b1, b2, out, n);
  } else {
    hipMemsetAsync(out, 0, (size_t)n * H * sizeof(float), stream);
    hipMemsetAsync(counts, 0, (size_t)n * sizeof(int), stream);
    agg_kernel<<<(E + 3) / 4, 256, 0, stream>>>(h, parent, child, out, counts, E);
    mean_div_bf16_kernel<<<((size_t)n * 64 + 255) / 256, 256, 0, stream>>>(
        out, counts, (short*)(ws + 0x180000), n);
    mlp2_kernel<<<nblk32, 256, 0, stream>>>(h, nullptr,
                                            (short*)(ws + 0x180000), counts,
                                            w1p, w2p, b1, b2, out, n);
  }
}

// Round 15
// 333.547 us; speedup vs baseline: 1.4643x; 1.1322x over previous
//
#include <hip/hip_runtime.h>
#include <hip/hip_bf16.h>

#define H 256
#define NEG_SLOPE 0.01f
#define TILE_M 64
#define TILE_M2 32

typedef __attribute__((ext_vector_type(4))) float f32x4;
typedef __attribute__((ext_vector_type(8))) short bf16x8;
typedef __attribute__((ext_vector_type(4))) short s16x4;

__device__ __forceinline__ short f2bf(float f) {
  __hip_bfloat16 b = __float2bfloat16(f);
  return *reinterpret_cast<short*>(&b);
}
__device__ __forceinline__ float bf2f(short s) {
  unsigned u = ((unsigned)(unsigned short)s) << 16;
  return __uint_as_float(u);
}

// ---------------- CSR build ----------------

__global__ __launch_bounds__(256) void hist_kernel(
    const int* __restrict__ parent, int* __restrict__ counts, int E) {
  int e = blockIdx.x * blockDim.x + threadIdx.x;
  if (e < E) atomicAdd(counts + parent[e], 1);
}

// Fused: blocks [0,nbCvt) convert h->hb (bf16); blocks [nbCvt,..) histogram.
__global__ __launch_bounds__(256) void prep_kernel(
    const float* __restrict__ h, short* __restrict__ hb, long total8,
    const int* __restrict__ parent, int* __restrict__ counts, int E,
    int nbCvt) {
  int b = blockIdx.x;
  if (b < nbCvt) {
    long i = (long)b * 256 + threadIdx.x;
    if (i >= total8) return;
    const f32x4* src = (const f32x4*)(h + i * 8);
    f32x4 v0 = src[0], v1 = src[1];
    bf16x8 o;
    o[0] = f2bf(v0.x); o[1] = f2bf(v0.y); o[2] = f2bf(v0.z); o[3] = f2bf(v0.w);
    o[4] = f2bf(v1.x); o[5] = f2bf(v1.y); o[6] = f2bf(v1.z); o[7] = f2bf(v1.w);
    *reinterpret_cast<bf16x8*>(hb + i * 8) = o;
  } else {
    int e = (b - nbCvt) * 256 + threadIdx.x;
    if (e < E) atomicAdd(counts + parent[e], 1);
  }
}

__global__ __launch_bounds__(256) void scan1_kernel(
    const int* __restrict__ counts, int* __restrict__ excl,
    int* __restrict__ blockSums, int n) {
  __shared__ int lds[256];
  int tid = threadIdx.x;
  int base = blockIdx.x * 1024 + tid * 4;
  int4 v = {0, 0, 0, 0};
  if (base + 3 < n) v = *reinterpret_cast<const int4*>(counts + base);
  int s = v.x + v.y + v.z + v.w;
  lds[tid] = s;
  __syncthreads();
  for (int off = 1; off < 256; off <<= 1) {
    int t = (tid >= off) ? lds[tid - off] : 0;
    __syncthreads();
    lds[tid] += t;
    __syncthreads();
  }
  int toff = lds[tid] - s;
  if (base + 3 < n) {
    int4 o;
    o.x = toff;
    o.y = toff + v.x;
    o.z = o.y + v.y;
    o.w = o.z + v.z;
    *reinterpret_cast<int4*>(excl + base) = o;
  }
  if (tid == 255) blockSums[blockIdx.x] = lds[255];
}

__global__ __launch_bounds__(256) void scan2_kernel(int* __restrict__ blockSums,
                                                    int nb) {
  __shared__ int lds[256];
  int tid = threadIdx.x;
  int s = (tid < nb) ? blockSums[tid] : 0;
  lds[tid] = s;
  __syncthreads();
  for (int off = 1; off < 256; off <<= 1) {
    int t = (tid >= off) ? lds[tid - off] : 0;
    __syncthreads();
    lds[tid] += t;
    __syncthreads();
  }
  if (tid < nb) blockSums[tid] = lds[tid] - s;
}

__global__ __launch_bounds__(256) void scan3_kernel(
    const int* __restrict__ excl, const int* __restrict__ blockSums,
    int* __restrict__ offsets, int* __restrict__ cursor, int n) {
  int i = blockIdx.x * blockDim.x + threadIdx.x;
  if (i < n) {
    int v = excl[i] + blockSums[i >> 10];
    offsets[i] = v;
    cursor[i] = v;
  }
}

__global__ __launch_bounds__(256) void scatter_kernel(
    const int* __restrict__ parent, const int* __restrict__ child,
    int* __restrict__ cursor, int* __restrict__ childlist, int E) {
  int e = blockIdx.x * blockDim.x + threadIdx.x;
  if (e < E) {
    int pos = atomicAdd(cursor + parent[e], 1);
    childlist[pos] = child[e];
  }
}

// Linear bf16 copies + fragment-packed copies.
__global__ __launch_bounds__(256) void cvt_kernel(
    const float* __restrict__ W1, const float* __restrict__ W2,
    short* __restrict__ w1b, short* __restrict__ w2b,
    short* __restrict__ w1p, short* __restrict__ w2p) {
  int i = blockIdx.x * blockDim.x + threadIdx.x;
  if (i < H * H) {
    short v1 = f2bf(W1[i]);
    short v2 = f2bf(W2[i]);
    w1b[i] = v1;
    w2b[i] = v2;
    int col = i >> 8, k = i & 255;
    int ks = k >> 5, lhi = (k >> 3) & 3, e = k & 7;
    int cb = col >> 4, lrr = col & 15;
    int pos = ((ks * 16 + cb) * 64 + lhi * 16 + lrr) * 8 + e;
    w1p[pos] = v1;
    w2p[pos] = v2;
  }
}

// ---------------- fully fused: gather-mean -> MLP -> residual --------------
// 256 threads / 4 waves, tile 32 rows. Phase A: wave wv gather-means rows
// [wv*8, wv*8+8) from bf16 hb into swizzled LDS. Then wave wv computes all
// 32 rows x cols wv*64..+64 (acc[2][4], packed B). Fusion removes the
// meansb write+read (~204MB) and a launch. R4's fusion failed at VGPR=144 /
// 1 block/CU; this shape needs ~60-80 VGPR at (256,4) -> 4+ blocks/CU, so
// one block's gather overlaps other blocks' MFMA.
__global__ __launch_bounds__(256, 4) void gm_mlp_kernel(
    const short* __restrict__ hb, const int* __restrict__ childlist,
    const int* __restrict__ offsets, const int* __restrict__ counts,
    const short* __restrict__ w1p, const short* __restrict__ w2p,
    const float* __restrict__ b1, const float* __restrict__ b2,
    float* __restrict__ out, int n) {
  __shared__ short lds[TILE_M2 * H];  // 16 KB: means -> z -> delta
  __shared__ float cmask[TILE_M2];

  const int tid = threadIdx.x;
  const int row0 = blockIdx.x * TILE_M2;
  const int lane = tid & 63;
  const int wv = tid >> 6;     // wave = col stripe wn, and gather row group
  const int lr = lane & 15;
  const int lhi = lane >> 4;

  // ---- Phase A: gather-mean rows [wv*8, wv*8+8) ----
  {
    int rid = row0 + wv * 8 + (lane & 7);
    if (rid >= n) rid = n - 1;
    int myc = counts[rid];
    int myo = offsets[rid];

    for (int rr = 0; rr < 8; ++rr) {
      int deg = __shfl(myc, rr);
      int off = __shfl(myo, rr);
      int degc = deg < 64 ? deg : 64;
      int cidx = 0;
      if (lane < degc) cidx = childlist[off + lane];  // one coalesced load
      f32x4 acc = {0.f, 0.f, 0.f, 0.f};
      int i = 0;
      for (; i + 4 <= degc; i += 4) {
        int c0 = __shfl(cidx, i);
        int c1 = __shfl(cidx, i + 1);
        int c2 = __shfl(cidx, i + 2);
        int c3 = __shfl(cidx, i + 3);
        s16x4 v0 = ((const s16x4*)(hb + (size_t)c0 * H))[lane];
        s16x4 v1 = ((const s16x4*)(hb + (size_t)c1 * H))[lane];
        s16x4 v2 = ((const s16x4*)(hb + (size_t)c2 * H))[lane];
        s16x4 v3 = ((const s16x4*)(hb + (size_t)c3 * H))[lane];
        acc.x += bf2f(v0.x) + bf2f(v1.x) + bf2f(v2.x) + bf2f(v3.x);
        acc.y += bf2f(v0.y) + bf2f(v1.y) + bf2f(v2.y) + bf2f(v3.y);
        acc.z += bf2f(v0.z) + bf2f(v1.z) + bf2f(v2.z) + bf2f(v3.z);
        acc.w += bf2f(v0.w) + bf2f(v1.w) + bf2f(v2.w) + bf2f(v3.w);
      }
      for (; i < degc; ++i) {
        int c = __shfl(cidx, i);
        s16x4 v = ((const s16x4*)(hb + (size_t)c * H))[lane];
        acc.x += bf2f(v.x);
        acc.y += bf2f(v.y);
        acc.z += bf2f(v.z);
        acc.w += bf2f(v.w);
      }
      for (; i < deg; ++i) {  // deg > 64 cold path
        int c = childlist[off + i];
        s16x4 v = ((const s16x4*)(hb + (size_t)c * H))[lane];
        acc.x += bf2f(v.x);
        acc.y += bf2f(v.y);
        acc.z += bf2f(v.z);
        acc.w += bf2f(v.w);
      }
      float inv = 1.0f / (float)(deg > 0 ? deg : 1);
      acc *= inv;
      int r = wv * 8 + rr;
      if (lane == 0) cmask[r] = deg > 0 ? 1.0f : 0.0f;
      s16x4 bv;
      bv.x = f2bf(acc.x);
      bv.y = f2bf(acc.y);
      bv.z = f2bf(acc.z);
      bv.w = f2bf(acc.w);
      int byte = (r * 512 + lane * 8) ^ ((r & 7) << 4);
      *reinterpret_cast<s16x4*>(reinterpret_cast<char*>(lds) + byte) = bv;
    }
  }
  __syncthreads();

  const f32x4 zero4 = {0.f, 0.f, 0.f, 0.f};
  f32x4 acc[2][4];
#pragma unroll
  for (int m = 0; m < 2; ++m)
#pragma unroll
    for (int j = 0; j < 4; ++j) acc[m][j] = zero4;

  // ---- Layer 1: z = mean @ W1^T ----
#pragma unroll
  for (int ks = 0; ks < 8; ++ks) {
    bf16x8 a[2], b[4];
#pragma unroll
    for (int m = 0; m < 2; ++m) {
      int ar = m * 16 + lr;
      int abyte = (ar * 512 + ks * 64 + lhi * 16) ^ ((ar & 7) << 4);
      a[m] = *reinterpret_cast<const bf16x8*>(
          reinterpret_cast<const char*>(lds) + abyte);
    }
#pragma unroll
    for (int j = 0; j < 4; ++j) {
      int cb = wv * 4 + j;
      b[j] = *reinterpret_cast<const bf16x8*>(
          w1p + ((ks * 16 + cb) * 64 + lane) * 8);
    }
#pragma unroll
    for (int m = 0; m < 2; ++m)
#pragma unroll
      for (int j = 0; j < 4; ++j)
        acc[m][j] = __builtin_amdgcn_mfma_f32_16x16x32_bf16(a[m], b[j],
                                                            acc[m][j], 0, 0, 0);
  }
  __syncthreads();  // all means reads done; tile will hold z

  // z (activated, bf16) into LDS stripe.
#pragma unroll
  for (int m = 0; m < 2; ++m)
#pragma unroll
    for (int j = 0; j < 4; ++j) {
      int col = wv * 64 + j * 16 + lr;
      float bias = b1[col];
#pragma unroll
      for (int r = 0; r < 4; ++r) {
        float z = acc[m][j][r] + bias;
        z = z >= 0.f ? z : NEG_SLOPE * z;
        int zr = m * 16 + lhi * 4 + r;
        int byte = (zr * 512 + col * 2) ^ ((zr & 7) << 4);
        *reinterpret_cast<short*>(reinterpret_cast<char*>(lds) + byte) = f2bf(z);
      }
    }
  __syncthreads();

  // ---- Layer 2: delta = z @ W2^T ----
#pragma unroll
  for (int m = 0; m < 2; ++m)
#pragma unroll
    for (int j = 0; j < 4; ++j) acc[m][j] = zero4;

#pragma unroll
  for (int ks = 0; ks < 8; ++ks) {
    bf16x8 a[2], b[4];
#pragma unroll
    for (int m = 0; m < 2; ++m) {
      int ar = m * 16 + lr;
      int abyte = (ar * 512 + ks * 64 + lhi * 16) ^ ((ar & 7) << 4);
      a[m] = *reinterpret_cast<const bf16x8*>(
          reinterpret_cast<const char*>(lds) + abyte);
    }
#pragma unroll
    for (int j = 0; j < 4; ++j) {
      int cb = wv * 4 + j;
      b[j] = *reinterpret_cast<const bf16x8*>(
          w2p + ((ks * 16 + cb) * 64 + lane) * 8);
    }
#pragma unroll
    for (int m = 0; m < 2; ++m)
#pragma unroll
      for (int j = 0; j < 4; ++j)
        acc[m][j] = __builtin_amdgcn_mfma_f32_16x16x32_bf16(a[m], b[j],
                                                            acc[m][j], 0, 0, 0);
  }
  __syncthreads();  // all z reads done; tile will hold delta

  // delta (+b2, bf16) into LDS stripe.
#pragma unroll
  for (int m = 0; m < 2; ++m)
#pragma unroll
    for (int j = 0; j < 4; ++j) {
      int col = wv * 64 + j * 16 + lr;
      float bias = b2[col];
#pragma unroll
      for (int r = 0; r < 4; ++r) {
        float d = acc[m][j][r] + bias;
        int zr = m * 16 + lhi * 4 + r;
        int byte = (zr * 512 + col * 2) ^ ((zr & 7) << 4);
        *reinterpret_cast<short*>(reinterpret_cast<char*>(lds) + byte) = f2bf(d);
      }
    }
  __syncthreads();

  // Vectorized epilogue: thread t -> row t>>3, 32 cols; residual from hb.
  {
    int row = tid >> 3;
    int sub = tid & 7;
    int grow = row0 + row;
    if (grow < n) {
      float mask = cmask[row];
      float* orow = out + (size_t)grow * H;
      const short* hrow = hb + (size_t)grow * H;
#pragma unroll
      for (int u = 0; u < 4; ++u) {
        int col = sub * 8 + u * 64;
        int byte = (row * 512 + col * 2) ^ ((row & 7) << 4);
        bf16x8 dv = *reinterpret_cast<const bf16x8*>(
            reinterpret_cast<const char*>(lds) + byte);
        bf16x8 hv = *reinterpret_cast<const bf16x8*>(hrow + col);
        f32x4 o0, o1;
        o0.x = bf2f(hv[0]) + bf2f(dv[0]) * mask;
        o0.y = bf2f(hv[1]) + bf2f(dv[1]) * mask;
        o0.z = bf2f(hv[2]) + bf2f(dv[2]) * mask;
        o0.w = bf2f(hv[3]) + bf2f(dv[3]) * mask;
        o1.x = bf2f(hv[4]) + bf2f(dv[4]) * mask;
        o1.y = bf2f(hv[5]) + bf2f(dv[5]) * mask;
        o1.z = bf2f(hv[6]) + bf2f(dv[6]) * mask;
        o1.w = bf2f(hv[7]) + bf2f(dv[7]) * mask;
        *reinterpret_cast<f32x4*>(orow + col) = o0;
        *reinterpret_cast<f32x4*>(orow + col + 4) = o1;
      }
    }
  }
}

// ---------------- non-fused MLP (atomic-fallback path) ----------------
__global__ __launch_bounds__(256, 4) void mlp2_kernel(
    const float* __restrict__ h, const short* __restrict__ hres,
    const short* __restrict__ meansb, const int* __restrict__ counts,
    const short* __restrict__ w1p, const short* __restrict__ w2p,
    const float* __restrict__ b1, const float* __restrict__ b2,
    float* __restrict__ out, int n) {
  __shared__ short lds[TILE_M2 * H];

  const int tid = threadIdx.x;
  const int row0 = blockIdx.x * TILE_M2;
  const int lane = tid & 63;
  const int wn = tid >> 6;
  const int lr = lane & 15;
  const int lhi = lane >> 4;

#pragma unroll
  for (int v = 0; v < 4; ++v) {
    int lin = v * 4096 + tid * 16;
    int row = lin >> 9;
    int grow = row0 + row;
    if (grow >= n) grow = n - 1;
    bf16x8 mv = *reinterpret_cast<const bf16x8*>(
        meansb + (size_t)grow * H + ((lin & 511) >> 1));
    int byte = lin ^ ((row & 7) << 4);
    *reinterpret_cast<bf16x8*>(reinterpret_cast<char*>(lds) + byte) = mv;
  }
  __syncthreads();

  const f32x4 zero4 = {0.f, 0.f, 0.f, 0.f};
  f32x4 acc[2][4];
#pragma unroll
  for (int m = 0; m < 2; ++m)
#pragma unroll
    for (int j = 0; j < 4; ++j) acc[m][j] = zero4;

#pragma unroll
  for (int ks = 0; ks < 8; ++ks) {
    bf16x8 a[2], b[4];
#pragma unroll
    for (int m = 0; m < 2; ++m) {
      int ar = m * 16 + lr;
      int abyte = (ar * 512 + ks * 64 + lhi * 16) ^ ((ar & 7) << 4);
      a[m] = *reinterpret_cast<const bf16x8*>(
          reinterpret_cast<const char*>(lds) + abyte);
    }
#pragma unroll
    for (int j = 0; j < 4; ++j) {
      int cb = wn * 4 + j;
      b[j] = *reinterpret_cast<const bf16x8*>(
          w1p + ((ks * 16 + cb) * 64 + lane) * 8);
    }
#pragma unroll
    for (int m = 0; m < 2; ++m)
#pragma unroll
      for (int j = 0; j < 4; ++j)
        acc[m][j] = __builtin_amdgcn_mfma_f32_16x16x32_bf16(a[m], b[j],
                                                            acc[m][j], 0, 0, 0);
  }
  __syncthreads();

#pragma unroll
  for (int m = 0; m < 2; ++m)
#pragma unroll
    for (int j = 0; j < 4; ++j) {
      int col = wn * 64 + j * 16 + lr;
      float bias = b1[col];
#pragma unroll
      for (int r = 0; r < 4; ++r) {
        float z = acc[m][j][r] + bias;
        z = z >= 0.f ? z : NEG_SLOPE * z;
        int zr = m * 16 + lhi * 4 + r;
        int byte = (zr * 512 + col * 2) ^ ((zr & 7) << 4);
        *reinterpret_cast<short*>(reinterpret_cast<char*>(lds) + byte) = f2bf(z);
      }
    }
  __syncthreads();

#pragma unroll
  for (int m = 0; m < 2; ++m)
#pragma unroll
    for (int j = 0; j < 4; ++j) acc[m][j] = zero4;

#pragma unroll
  for (int ks = 0; ks < 8; ++ks) {
    bf16x8 a[2], b[4];
#pragma unroll
    for (int m = 0; m < 2; ++m) {
      int ar = m * 16 + lr;
      int abyte = (ar * 512 + ks * 64 + lhi * 16) ^ ((ar & 7) << 4);
      a[m] = *reinterpret_cast<const bf16x8*>(
          reinterpret_cast<const char*>(lds) + abyte);
    }
#pragma unroll
    for (int j = 0; j < 4; ++j) {
      int cb = wn * 4 + j;
      b[j] = *reinterpret_cast<const bf16x8*>(
          w2p + ((ks * 16 + cb) * 64 + lane) * 8);
    }
#pragma unroll
    for (int m = 0; m < 2; ++m)
#pragma unroll
      for (int j = 0; j < 4; ++j)
        acc[m][j] = __builtin_amdgcn_mfma_f32_16x16x32_bf16(a[m], b[j],
                                                            acc[m][j], 0, 0, 0);
  }
  __syncthreads();

#pragma unroll
  for (int m = 0; m < 2; ++m)
#pragma unroll
    for (int j = 0; j < 4; ++j) {
      int col = wn * 64 + j * 16 + lr;
      float bias = b2[col];
#pragma unroll
      for (int r = 0; r < 4; ++r) {
        float d = acc[m][j][r] + bias;
        int zr = m * 16 + lhi * 4 + r;
        int byte = (zr * 512 + col * 2) ^ ((zr & 7) << 4);
        *reinterpret_cast<short*>(reinterpret_cast<char*>(lds) + byte) = f2bf(d);
      }
    }
  __syncthreads();

  {
    int row = tid >> 3;
    int sub = tid & 7;
    int grow = row0 + row;
    if (grow < n) {
      float mask = counts[grow] > 0 ? 1.0f : 0.0f;
      float* orow = out + (size_t)grow * H;
      const float* hrow = h + (size_t)grow * H;
#pragma unroll
      for (int u = 0; u < 4; ++u) {
        int col = sub * 8 + u * 64;
        int byte = (row * 512 + col * 2) ^ ((row & 7) << 4);
        bf16x8 dv = *reinterpret_cast<const bf16x8*>(
            reinterpret_cast<const char*>(lds) + byte);
        f32x4 h0 = *reinterpret_cast<const f32x4*>(hrow + col);
        f32x4 h1 = *reinterpret_cast<const f32x4*>(hrow + col + 4);
        f32x4 o0, o1;
        o0.x = h0.x + bf2f(dv[0]) * mask;
        o0.y = h0.y + bf2f(dv[1]) * mask;
        o0.z = h0.z + bf2f(dv[2]) * mask;
        o0.w = h0.w + bf2f(dv[3]) * mask;
        o1.x = h1.x + bf2f(dv[4]) * mask;
        o1.y = h1.y + bf2f(dv[5]) * mask;
        o1.z = h1.z + bf2f(dv[6]) * mask;
        o1.w = h1.w + bf2f(dv[7]) * mask;
        *reinterpret_cast<f32x4*>(orow + col) = o0;
        *reinterpret_cast<f32x4*>(orow + col + 4) = o1;
      }
    }
  }
}

// ---------------- mid fallback: fused gather+MLP (linear weights, f32) -----
__global__ __launch_bounds__(256) void fused_kernel(
    const float* __restrict__ h, const int* __restrict__ childlist,
    const int* __restrict__ offsets, const int* __restrict__ counts,
    const short* __restrict__ w1b, const short* __restrict__ w2b,
    const float* __restrict__ b1, const float* __restrict__ b2,
    float* __restrict__ out, int n) {
  __shared__ short lds[TILE_M * H];

  const int tid = threadIdx.x;
  const int row0 = blockIdx.x * TILE_M;
  const int lane = tid & 63;
  const int wv = tid >> 6;
  const int wrow = wv * 16;
  const int lr = lane & 15;
  const int lhi = lane >> 4;

  int rid = row0 + wrow + lr;
  if (rid >= n) rid = n - 1;
  const int myc = counts[rid];
  const int myo = offsets[rid];

  for (int rr = 0; rr < 16; ++rr) {
    int deg = __shfl(myc, rr);
    int off = __shfl(myo, rr);
    int degc = deg < 64 ? deg : 64;
    int cidx = 0;
    if (lane < degc) cidx = childlist[off + lane];
    f32x4 acc = {0.f, 0.f, 0.f, 0.f};
    int i = 0;
    for (; i + 4 <= degc; i += 4) {
      int c0 = __shfl(cidx, i);
      int c1 = __shfl(cidx, i + 1);
      int c2 = __shfl(cidx, i + 2);
      int c3 = __shfl(cidx, i + 3);
      f32x4 v0 = ((const f32x4*)(h + (size_t)c0 * H))[lane];
      f32x4 v1 = ((const f32x4*)(h + (size_t)c1 * H))[lane];
      f32x4 v2 = ((const f32x4*)(h + (size_t)c2 * H))[lane];
      f32x4 v3 = ((const f32x4*)(h + (size_t)c3 * H))[lane];
      acc += v0 + v1 + v2 + v3;
    }
    for (; i < degc; ++i) {
      int c = __shfl(cidx, i);
      acc += ((const f32x4*)(h + (size_t)c * H))[lane];
    }
    for (; i < deg; ++i) {
      int c = childlist[off + i];
      acc += ((const f32x4*)(h + (size_t)c * H))[lane];
    }
    float inv = 1.0f / (float)(deg > 0 ? deg : 1);
    acc *= inv;
    s16x4 bv;
    bv.x = f2bf(acc.x);
    bv.y = f2bf(acc.y);
    bv.z = f2bf(acc.z);
    bv.w = f2bf(acc.w);
    int r = wrow + rr;
    int byte = (r * 512 + lane * 8) ^ ((r & 7) << 4);
    *reinterpret_cast<s16x4*>(reinterpret_cast<char*>(lds) + byte) = bv;
  }
  __syncthreads();

  const f32x4 zero4 = {0.f, 0.f, 0.f, 0.f};
  f32x4 acc[4][4];
#pragma unroll
  for (int m = 0; m < 4; ++m)
#pragma unroll
    for (int j = 0; j < 4; ++j) acc[m][j] = zero4;

#pragma unroll
  for (int ks = 0; ks < 8; ++ks) {
    bf16x8 a[4], b[4];
#pragma unroll
    for (int m = 0; m < 4; ++m) {
      int ar = m * 16 + lr;
      int abyte = (ar * 512 + ks * 64 + lhi * 16) ^ ((ar & 7) << 4);
      a[m] = *reinterpret_cast<const bf16x8*>(
          reinterpret_cast<const char*>(lds) + abyte);
    }
#pragma unroll
    for (int j = 0; j < 4; ++j) {
      int col = wv * 64 + j * 16 + lr;
      b[j] = *reinterpret_cast<const bf16x8*>(w1b + col * H + ks * 32 + lhi * 8);
    }
#pragma unroll
    for (int m = 0; m < 4; ++m)
#pragma unroll
      for (int j = 0; j < 4; ++j)
        acc[m][j] = __builtin_amdgcn_mfma_f32_16x16x32_bf16(a[m], b[j],
                                                            acc[m][j], 0, 0, 0);
  }
  __syncthreads();

#pragma unroll
  for (int m = 0; m < 4; ++m)
#pragma unroll
    for (int j = 0; j < 4; ++j) {
      int col = wv * 64 + j * 16 + lr;
      float bias = b1[col];
#pragma unroll
      for (int r = 0; r < 4; ++r) {
        float z = acc[m][j][r] + bias;
        z = z >= 0.f ? z : NEG_SLOPE * z;
        int zr = m * 16 + lhi * 4 + r;
        int byte = (zr * 512 + col * 2) ^ ((zr & 7) << 4);
        *reinterpret_cast<short*>(reinterpret_cast<char*>(lds) + byte) = f2bf(z);
      }
    }
  __syncthreads();

#pragma unroll
  for (int m = 0; m < 4; ++m)
#pragma unroll
    for (int j = 0; j < 4; ++j) acc[m][j] = zero4;

#pragma unroll
  for (int ks = 0; ks < 8; ++ks) {
    bf16x8 a[4], b[4];
#pragma unroll
    for (int m = 0; m < 4; ++m) {
      int ar = m * 16 + lr;
      int abyte = (ar * 512 + ks * 64 + lhi * 16) ^ ((ar & 7) << 4);
      a[m] = *reinterpret_cast<const bf16x8*>(
          reinterpret_cast<const char*>(lds) + abyte);
    }
#pragma unroll
    for (int j = 0; j < 4; ++j) {
      int col = wv * 64 + j * 16 + lr;
      b[j] = *reinterpret_cast<const bf16x8*>(w2b + col * H + ks * 32 + lhi * 8);
    }
#pragma unroll
    for (int m = 0; m < 4; ++m)
#pragma unroll
      for (int j = 0; j < 4; ++j)
        acc[m][j] = __builtin_amdgcn_mfma_f32_16x16x32_bf16(a[m], b[j],
                                                            acc[m][j], 0, 0, 0);
  }

#pragma unroll
  for (int m = 0; m < 4; ++m) {
#pragma unroll
    for (int r = 0; r < 4; ++r) {
      int grow = row0 + m * 16 + lhi * 4 + r;
      if (grow < n) {
        float mask = counts[grow] > 0 ? 1.0f : 0.0f;
        const float* hrow = h + (size_t)grow * H;
        float* orow = out + (size_t)grow * H;
#pragma unroll
        for (int j = 0; j < 4; ++j) {
          int col = wv * 64 + j * 16 + lr;
          orow[col] = hrow[col] + (acc[m][j][r] + b2[col]) * mask;
        }
      }
    }
  }
}

// ---------------- last-resort fallback: atomic agg ----------------
__global__ __launch_bounds__(256) void agg_kernel(
    const float* __restrict__ h, const int* __restrict__ parent,
    const int* __restrict__ child, float* __restrict__ sums,
    int* __restrict__ counts, int E) {
  int gid = blockIdx.x * blockDim.x + threadIdx.x;
  int e = gid >> 6;
  if (e >= E) return;
  int lane = threadIdx.x & 63;
  int p = parent[e];
  int c = child[e];
  f32x4 v = ((const f32x4*)(h + (size_t)c * H))[lane];
  float* dst = sums + (size_t)p * H + lane * 4;
  unsafeAtomicAdd(dst + 0, v.x);
  unsafeAtomicAdd(dst + 1, v.y);
  unsafeAtomicAdd(dst + 2, v.z);
  unsafeAtomicAdd(dst + 3, v.w);
  if (lane == 0) atomicAdd(counts + p, 1);
}

__global__ __launch_bounds__(256) void mean_div_bf16_kernel(
    const float* __restrict__ sums, const int* __restrict__ counts,
    short* __restrict__ meansb, int n) {
  int w = (blockIdx.x * blockDim.x + threadIdx.x) >> 6;
  if (w >= n) return;
  int lane = threadIdx.x & 63;
  float inv = 1.0f / fmaxf((float)counts[w], 1.0f);
  f32x4 v = ((const f32x4*)(sums + (size_t)w * H))[lane];
  v *= inv;
  s16x4 bv;
  bv.x = f2bf(v.x);
  bv.y = f2bf(v.y);
  bv.z = f2bf(v.z);
  bv.w = f2bf(v.w);
  *reinterpret_cast<s16x4*>(meansb + (size_t)w * H + lane * 4) = bv;
}

extern "C" void kernel_launch(void* const* d_in, const int* in_sizes, int n_in,
                              void* d_out, int out_size, void* d_ws, size_t ws_size,
                              hipStream_t stream) {
  const float* h  = (const float*)d_in[0];
  const int* edges = (const int*)d_in[1];
  const float* W1 = (const float*)d_in[2];
  const float* b1 = (const float*)d_in[3];
  const float* W2 = (const float*)d_in[4];
  const float* b2 = (const float*)d_in[5];
  float* out = (float*)d_out;

  const int n = in_sizes[0] / H;   // 200000
  const int E = in_sizes[1] / 2;   // 1000000
  const int* parent = edges;
  const int* child = edges + E;

  char* ws = (char*)d_ws;
  int* counts    = (int*)(ws);                // n ints (800 KB)
  short* w1b     = (short*)(ws + 0x100000);   // 128 KB linear
  short* w2b     = (short*)(ws + 0x120000);   // 128 KB linear
  short* w1p     = (short*)(ws + 0x140000);   // 128 KB packed
  short* w2p     = (short*)(ws + 0x160000);   // 128 KB packed
  int* excl      = (int*)(ws + 0x180000);     // n ints
  int* cursor    = (int*)(ws + 0x280000);     // n ints
  int* blockSums = (int*)(ws + 0x380000);     // 256 ints
  int* offsets   = (int*)(ws + 0x384000);     // n ints
  int* childlist = (int*)(ws + 0x484000);     // E ints (4 MB @ E=1M)
  short* hb      = (short*)(ws + 0x884000);   // n*H bf16 (102.4 MB)
  size_t meansz  = (size_t)n * H * 2;

  size_t need_csr   = 0x484000 + (size_t)E * 4;
  size_t need_fused = 0x884000 + meansz;      // CSR + hb
  int nblk64 = (n + TILE_M - 1) / TILE_M;
  int nblk32 = (n + TILE_M2 - 1) / TILE_M2;

  cvt_kernel<<<(H * H + 255) / 256, 256, 0, stream>>>(W1, W2, w1b, w2b, w1p, w2p);

  if (ws_size >= need_fused && E <= (0x400000 / 4) && n <= 256 * 1024) {
    hipMemsetAsync(counts, 0, (size_t)n * sizeof(int), stream);
    long total8 = (long)n * H / 8;
    int nbCvt = (int)((total8 + 255) / 256);
    int nbHist = (E + 255) / 256;
    prep_kernel<<<nbCvt + nbHist, 256, 0, stream>>>(h, hb, total8, parent,
                                                    counts, E, nbCvt);
    int nb = (n + 1023) >> 10;
    scan1_kernel<<<nb, 256, 0, stream>>>(counts, excl, blockSums, n);
    scan2_kernel<<<1, 256, 0, stream>>>(blockSums, nb);
    scan3_kernel<<<(n + 255) / 256, 256, 0, stream>>>(excl, blockSums, offsets,
                                                      cursor, n);
    scatter_kernel<<<(E + 255) / 256, 256, 0, stream>>>(parent, child, cursor,
                                                        childlist, E);
    gm_mlp_kernel<<<nblk32, 256, 0, stream>>>(hb, childlist, offsets, counts,
                                              w1p, w2p, b1, b2, out, n);
  } else if (ws_size >= need_csr && n <= 256 * 1024) {
    hipMemsetAsync(counts, 0, (size_t)n * sizeof(int), stream);
    hist_kernel<<<(E + 255) / 256, 256, 0, stream>>>(parent, counts, E);
    int nb = (n + 1023) >> 10;
    scan1_kernel<<<nb, 256, 0, stream>>>(counts, excl, blockSums, n);
    scan2_kernel<<<1, 256, 0, stream>>>(blockSums, nb);
    scan3_kernel<<<(n + 255) / 256, 256, 0, stream>>>(excl, blockSums, offsets,
                                                      cursor, n);
    scatter_kernel<<<(E + 255) / 256, 256, 0, stream>>>(parent, child, cursor,
                                                        childlist, E);
    fused_kernel<<<nblk64, 256, 0, stream>>>(h, childlist, offsets, counts, w1b,
                                             w2b, b1, b2, out, n);
  } else {
    hipMemsetAsync(out, 0, (size_t)n * H * sizeof(float), stream);
    hipMemsetAsync(counts, 0, (size_t)n * sizeof(int), stream);
    agg_kernel<<<(E + 3) / 4, 256, 0, stream>>>(h, parent, child, out, counts, E);
    mean_div_bf16_kernel<<<((size_t)n * 64 + 255) / 256, 256, 0, stream>>>(
        out, counts, (short*)(ws + 0x180000), n);
    mlp2_kernel<<<nblk32, 256, 0, stream>>>(h, nullptr,
                                            (short*)(ws + 0x180000), counts,
                                            w1p, w2p, b1, b2, out, n);
  }
}

// Round 16
// 326.832 us; speedup vs baseline: 1.4944x; 1.0205x over previous
//
#include <hip/hip_runtime.h>
#include <hip/hip_bf16.h>

#define H 256
#define NEG_SLOPE 0.01f
#define TILE_M 64
#define TILE_M2 32

typedef __attribute__((ext_vector_type(4))) float f32x4;
typedef __attribute__((ext_vector_type(8))) short bf16x8;
typedef __attribute__((ext_vector_type(4))) short s16x4;

__device__ __forceinline__ short f2bf(float f) {
  __hip_bfloat16 b = __float2bfloat16(f);
  return *reinterpret_cast<short*>(&b);
}
__device__ __forceinline__ float bf2f(short s) {
  unsigned u = ((unsigned)(unsigned short)s) << 16;
  return __uint_as_float(u);
}

// ---------------- CSR build ----------------

__global__ __launch_bounds__(256) void hist_kernel(
    const int* __restrict__ parent, int* __restrict__ counts, int E) {
  int e = blockIdx.x * blockDim.x + threadIdx.x;
  if (e < E) atomicAdd(counts + parent[e], 1);
}

// Fused: blocks [0,nbCvt) convert h->hb (bf16); blocks [nbCvt,..) histogram.
__global__ __launch_bounds__(256) void prep_kernel(
    const float* __restrict__ h, short* __restrict__ hb, long total8,
    const int* __restrict__ parent, int* __restrict__ counts, int E,
    int nbCvt) {
  int b = blockIdx.x;
  if (b < nbCvt) {
    long i = (long)b * 256 + threadIdx.x;
    if (i >= total8) return;
    const f32x4* src = (const f32x4*)(h + i * 8);
    f32x4 v0 = src[0], v1 = src[1];
    bf16x8 o;
    o[0] = f2bf(v0.x); o[1] = f2bf(v0.y); o[2] = f2bf(v0.z); o[3] = f2bf(v0.w);
    o[4] = f2bf(v1.x); o[5] = f2bf(v1.y); o[6] = f2bf(v1.z); o[7] = f2bf(v1.w);
    *reinterpret_cast<bf16x8*>(hb + i * 8) = o;
  } else {
    int e = (b - nbCvt) * 256 + threadIdx.x;
    if (e < E) atomicAdd(counts + parent[e], 1);
  }
}

__global__ __launch_bounds__(256) void scan1_kernel(
    const int* __restrict__ counts, int* __restrict__ excl,
    int* __restrict__ blockSums, int n) {
  __shared__ int lds[256];
  int tid = threadIdx.x;
  int base = blockIdx.x * 1024 + tid * 4;
  int4 v = {0, 0, 0, 0};
  if (base + 3 < n) v = *reinterpret_cast<const int4*>(counts + base);
  int s = v.x + v.y + v.z + v.w;
  lds[tid] = s;
  __syncthreads();
  for (int off = 1; off < 256; off <<= 1) {
    int t = (tid >= off) ? lds[tid - off] : 0;
    __syncthreads();
    lds[tid] += t;
    __syncthreads();
  }
  int toff = lds[tid] - s;
  if (base + 3 < n) {
    int4 o;
    o.x = toff;
    o.y = toff + v.x;
    o.z = o.y + v.y;
    o.w = o.z + v.z;
    *reinterpret_cast<int4*>(excl + base) = o;
  }
  if (tid == 255) blockSums[blockIdx.x] = lds[255];
}

__global__ __launch_bounds__(256) void scan2_kernel(int* __restrict__ blockSums,
                                                    int nb) {
  __shared__ int lds[256];
  int tid = threadIdx.x;
  int s = (tid < nb) ? blockSums[tid] : 0;
  lds[tid] = s;
  __syncthreads();
  for (int off = 1; off < 256; off <<= 1) {
    int t = (tid >= off) ? lds[tid - off] : 0;
    __syncthreads();
    lds[tid] += t;
    __syncthreads();
  }
  if (tid < nb) blockSums[tid] = lds[tid] - s;
}

__global__ __launch_bounds__(256) void scan3_kernel(
    const int* __restrict__ excl, const int* __restrict__ blockSums,
    int* __restrict__ offsets, int* __restrict__ cursor, int n) {
  int i = blockIdx.x * blockDim.x + threadIdx.x;
  if (i < n) {
    int v = excl[i] + blockSums[i >> 10];
    offsets[i] = v;
    cursor[i] = v;
  }
}

__global__ __launch_bounds__(256) void scatter_kernel(
    const int* __restrict__ parent, const int* __restrict__ child,
    int* __restrict__ cursor, int* __restrict__ childlist, int E) {
  int e = blockIdx.x * blockDim.x + threadIdx.x;
  if (e < E) {
    int pos = atomicAdd(cursor + parent[e], 1);
    childlist[pos] = child[e];
  }
}

// Linear bf16 copies + fragment-packed copies.
__global__ __launch_bounds__(256) void cvt_kernel(
    const float* __restrict__ W1, const float* __restrict__ W2,
    short* __restrict__ w1b, short* __restrict__ w2b,
    short* __restrict__ w1p, short* __restrict__ w2p) {
  int i = blockIdx.x * blockDim.x + threadIdx.x;
  if (i < H * H) {
    short v1 = f2bf(W1[i]);
    short v2 = f2bf(W2[i]);
    w1b[i] = v1;
    w2b[i] = v2;
    int col = i >> 8, k = i & 255;
    int ks = k >> 5, lhi = (k >> 3) & 3, e = k & 7;
    int cb = col >> 4, lrr = col & 15;
    int pos = ((ks * 16 + cb) * 64 + lhi * 16 + lrr) * 8 + e;
    w1p[pos] = v1;
    w2p[pos] = v2;
  }
}

// ---------------- fully fused: gather-mean -> MLP -> residual --------------
// 256 threads / 4 waves, tile 32 rows. Phase A: wave wv gather-means rows
// [wv*8, wv*8+8) from bf16 hb into swizzled LDS, with (a) 8-wide predicated
// gather (deg is wave-uniform -> scalar branches; up to 8 loads in flight)
// and (b) next-row index prefetch. Then wave wv computes all 32 rows x
// cols wv*64..+64 (acc[2][4], packed B).
__global__ __launch_bounds__(256, 4) void gm_mlp_kernel(
    const short* __restrict__ hb, const int* __restrict__ childlist,
    const int* __restrict__ offsets, const int* __restrict__ counts,
    const short* __restrict__ w1p, const short* __restrict__ w2p,
    const float* __restrict__ b1, const float* __restrict__ b2,
    float* __restrict__ out, int n) {
  __shared__ short lds[TILE_M2 * H];  // 16 KB: means -> z -> delta
  __shared__ float cmask[TILE_M2];

  const int tid = threadIdx.x;
  const int row0 = blockIdx.x * TILE_M2;
  const int lane = tid & 63;
  const int wv = tid >> 6;     // wave = col stripe, and gather row group
  const int lr = lane & 15;
  const int lhi = lane >> 4;

  // ---- Phase A: gather-mean rows [wv*8, wv*8+8) ----
  {
    int rid = row0 + wv * 8 + (lane & 7);
    if (rid >= n) rid = n - 1;
    int myc = counts[rid];
    int myo = offsets[rid];

    // Prefetch row 0's indices.
    int deg_n = __shfl(myc, 0);
    int off_n = __shfl(myo, 0);
    int dcn = deg_n < 64 ? deg_n : 64;
    int cidx_n = 0;
    if (lane < dcn) cidx_n = childlist[off_n + lane];

    for (int rr = 0; rr < 8; ++rr) {
      const int deg = deg_n;
      const int off = off_n;
      const int degc = dcn;
      const int cidx = cidx_n;
      if (rr + 1 < 8) {  // prefetch next row's indices under this row's work
        deg_n = __shfl(myc, rr + 1);
        off_n = __shfl(myo, rr + 1);
        dcn = deg_n < 64 ? deg_n : 64;
        cidx_n = 0;
        if (lane < dcn) cidx_n = childlist[off_n + lane];
      }

      f32x4 acc = {0.f, 0.f, 0.f, 0.f};
      const int k8 = degc < 8 ? degc : 8;
      s16x4 v[8];
      // Issue up to 8 independent loads (uniform branches — no divergence).
#pragma unroll
      for (int j = 0; j < 8; ++j)
        if (j < k8) {
          int c = __shfl(cidx, j);
          v[j] = ((const s16x4*)(hb + (size_t)c * H))[lane];
        }
#pragma unroll
      for (int j = 0; j < 8; ++j)
        if (j < k8) {
          acc.x += bf2f(v[j].x);
          acc.y += bf2f(v[j].y);
          acc.z += bf2f(v[j].z);
          acc.w += bf2f(v[j].w);
        }
      // deg > 8: continue in 4-wide chunks.
      int i = 8;
      for (; i + 4 <= degc; i += 4) {
        int c0 = __shfl(cidx, i);
        int c1 = __shfl(cidx, i + 1);
        int c2 = __shfl(cidx, i + 2);
        int c3 = __shfl(cidx, i + 3);
        s16x4 v0 = ((const s16x4*)(hb + (size_t)c0 * H))[lane];
        s16x4 v1 = ((const s16x4*)(hb + (size_t)c1 * H))[lane];
        s16x4 v2 = ((const s16x4*)(hb + (size_t)c2 * H))[lane];
        s16x4 v3 = ((const s16x4*)(hb + (size_t)c3 * H))[lane];
        acc.x += bf2f(v0.x) + bf2f(v1.x) + bf2f(v2.x) + bf2f(v3.x);
        acc.y += bf2f(v0.y) + bf2f(v1.y) + bf2f(v2.y) + bf2f(v3.y);
        acc.z += bf2f(v0.z) + bf2f(v1.z) + bf2f(v2.z) + bf2f(v3.z);
        acc.w += bf2f(v0.w) + bf2f(v1.w) + bf2f(v2.w) + bf2f(v3.w);
      }
      for (; i < degc; ++i) {
        int c = __shfl(cidx, i);
        s16x4 vv = ((const s16x4*)(hb + (size_t)c * H))[lane];
        acc.x += bf2f(vv.x);
        acc.y += bf2f(vv.y);
        acc.z += bf2f(vv.z);
        acc.w += bf2f(vv.w);
      }
      for (; i < deg; ++i) {  // deg > 64 cold path
        int c = childlist[off + i];
        s16x4 vv = ((const s16x4*)(hb + (size_t)c * H))[lane];
        acc.x += bf2f(vv.x);
        acc.y += bf2f(vv.y);
        acc.z += bf2f(vv.z);
        acc.w += bf2f(vv.w);
      }
      float inv = 1.0f / (float)(deg > 0 ? deg : 1);
      acc *= inv;
      int r = wv * 8 + rr;
      if (lane == 0) cmask[r] = deg > 0 ? 1.0f : 0.0f;
      s16x4 bv;
      bv.x = f2bf(acc.x);
      bv.y = f2bf(acc.y);
      bv.z = f2bf(acc.z);
      bv.w = f2bf(acc.w);
      int byte = (r * 512 + lane * 8) ^ ((r & 7) << 4);
      *reinterpret_cast<s16x4*>(reinterpret_cast<char*>(lds) + byte) = bv;
    }
  }
  __syncthreads();

  const f32x4 zero4 = {0.f, 0.f, 0.f, 0.f};
  f32x4 acc[2][4];
#pragma unroll
  for (int m = 0; m < 2; ++m)
#pragma unroll
    for (int j = 0; j < 4; ++j) acc[m][j] = zero4;

  // ---- Layer 1: z = mean @ W1^T ----
#pragma unroll
  for (int ks = 0; ks < 8; ++ks) {
    bf16x8 a[2], b[4];
#pragma unroll
    for (int m = 0; m < 2; ++m) {
      int ar = m * 16 + lr;
      int abyte = (ar * 512 + ks * 64 + lhi * 16) ^ ((ar & 7) << 4);
      a[m] = *reinterpret_cast<const bf16x8*>(
          reinterpret_cast<const char*>(lds) + abyte);
    }
#pragma unroll
    for (int j = 0; j < 4; ++j) {
      int cb = wv * 4 + j;
      b[j] = *reinterpret_cast<const bf16x8*>(
          w1p + ((ks * 16 + cb) * 64 + lane) * 8);
    }
#pragma unroll
    for (int m = 0; m < 2; ++m)
#pragma unroll
      for (int j = 0; j < 4; ++j)
        acc[m][j] = __builtin_amdgcn_mfma_f32_16x16x32_bf16(a[m], b[j],
                                                            acc[m][j], 0, 0, 0);
  }
  __syncthreads();  // all means reads done; tile will hold z

  // z (activated, bf16) into LDS stripe.
#pragma unroll
  for (int m = 0; m < 2; ++m)
#pragma unroll
    for (int j = 0; j < 4; ++j) {
      int col = wv * 64 + j * 16 + lr;
      float bias = b1[col];
#pragma unroll
      for (int r = 0; r < 4; ++r) {
        float z = acc[m][j][r] + bias;
        z = z >= 0.f ? z : NEG_SLOPE * z;
        int zr = m * 16 + lhi * 4 + r;
        int byte = (zr * 512 + col * 2) ^ ((zr & 7) << 4);
        *reinterpret_cast<short*>(reinterpret_cast<char*>(lds) + byte) = f2bf(z);
      }
    }
  __syncthreads();

  // ---- Layer 2: delta = z @ W2^T ----
#pragma unroll
  for (int m = 0; m < 2; ++m)
#pragma unroll
    for (int j = 0; j < 4; ++j) acc[m][j] = zero4;

#pragma unroll
  for (int ks = 0; ks < 8; ++ks) {
    bf16x8 a[2], b[4];
#pragma unroll
    for (int m = 0; m < 2; ++m) {
      int ar = m * 16 + lr;
      int abyte = (ar * 512 + ks * 64 + lhi * 16) ^ ((ar & 7) << 4);
      a[m] = *reinterpret_cast<const bf16x8*>(
          reinterpret_cast<const char*>(lds) + abyte);
    }
#pragma unroll
    for (int j = 0; j < 4; ++j) {
      int cb = wv * 4 + j;
      b[j] = *reinterpret_cast<const bf16x8*>(
          w2p + ((ks * 16 + cb) * 64 + lane) * 8);
    }
#pragma unroll
    for (int m = 0; m < 2; ++m)
#pragma unroll
      for (int j = 0; j < 4; ++j)
        acc[m][j] = __builtin_amdgcn_mfma_f32_16x16x32_bf16(a[m], b[j],
                                                            acc[m][j], 0, 0, 0);
  }
  __syncthreads();  // all z reads done; tile will hold delta

  // delta (+b2, bf16) into LDS stripe.
#pragma unroll
  for (int m = 0; m < 2; ++m)
#pragma unroll
    for (int j = 0; j < 4; ++j) {
      int col = wv * 64 + j * 16 + lr;
      float bias = b2[col];
#pragma unroll
      for (int r = 0; r < 4; ++r) {
        float d = acc[m][j][r] + bias;
        int zr = m * 16 + lhi * 4 + r;
        int byte = (zr * 512 + col * 2) ^ ((zr & 7) << 4);
        *reinterpret_cast<short*>(reinterpret_cast<char*>(lds) + byte) = f2bf(d);
      }
    }
  __syncthreads();

  // Vectorized epilogue: thread t -> row t>>3, 32 cols; residual from hb.
  {
    int row = tid >> 3;
    int sub = tid & 7;
    int grow = row0 + row;
    if (grow < n) {
      float mask = cmask[row];
      float* orow = out + (size_t)grow * H;
      const short* hrow = hb + (size_t)grow * H;
#pragma unroll
      for (int u = 0; u < 4; ++u) {
        int col = sub * 8 + u * 64;
        int byte = (row * 512 + col * 2) ^ ((row & 7) << 4);
        bf16x8 dv = *reinterpret_cast<const bf16x8*>(
            reinterpret_cast<const char*>(lds) + byte);
        bf16x8 hv = *reinterpret_cast<const bf16x8*>(hrow + col);
        f32x4 o0, o1;
        o0.x = bf2f(hv[0]) + bf2f(dv[0]) * mask;
        o0.y = bf2f(hv[1]) + bf2f(dv[1]) * mask;
        o0.z = bf2f(hv[2]) + bf2f(dv[2]) * mask;
        o0.w = bf2f(hv[3]) + bf2f(dv[3]) * mask;
        o1.x = bf2f(hv[4]) + bf2f(dv[4]) * mask;
        o1.y = bf2f(hv[5]) + bf2f(dv[5]) * mask;
        o1.z = bf2f(hv[6]) + bf2f(dv[6]) * mask;
        o1.w = bf2f(hv[7]) + bf2f(dv[7]) * mask;
        *reinterpret_cast<f32x4*>(orow + col) = o0;
        *reinterpret_cast<f32x4*>(orow + col + 4) = o1;
      }
    }
  }
}

// ---------------- non-fused MLP (atomic-fallback path) ----------------
__global__ __launch_bounds__(256, 4) void mlp2_kernel(
    const float* __restrict__ h, const short* __restrict__ hres,
    const short* __restrict__ meansb, const int* __restrict__ counts,
    const short* __restrict__ w1p, const short* __restrict__ w2p,
    const float* __restrict__ b1, const float* __restrict__ b2,
    float* __restrict__ out, int n) {
  __shared__ short lds[TILE_M2 * H];

  const int tid = threadIdx.x;
  const int row0 = blockIdx.x * TILE_M2;
  const int lane = tid & 63;
  const int wn = tid >> 6;
  const int lr = lane & 15;
  const int lhi = lane >> 4;

#pragma unroll
  for (int v = 0; v < 4; ++v) {
    int lin = v * 4096 + tid * 16;
    int row = lin >> 9;
    int grow = row0 + row;
    if (grow >= n) grow = n - 1;
    bf16x8 mv = *reinterpret_cast<const bf16x8*>(
        meansb + (size_t)grow * H + ((lin & 511) >> 1));
    int byte = lin ^ ((row & 7) << 4);
    *reinterpret_cast<bf16x8*>(reinterpret_cast<char*>(lds) + byte) = mv;
  }
  __syncthreads();

  const f32x4 zero4 = {0.f, 0.f, 0.f, 0.f};
  f32x4 acc[2][4];
#pragma unroll
  for (int m = 0; m < 2; ++m)
#pragma unroll
    for (int j = 0; j < 4; ++j) acc[m][j] = zero4;

#pragma unroll
  for (int ks = 0; ks < 8; ++ks) {
    bf16x8 a[2], b[4];
#pragma unroll
    for (int m = 0; m < 2; ++m) {
      int ar = m * 16 + lr;
      int abyte = (ar * 512 + ks * 64 + lhi * 16) ^ ((ar & 7) << 4);
      a[m] = *reinterpret_cast<const bf16x8*>(
          reinterpret_cast<const char*>(lds) + abyte);
    }
#pragma unroll
    for (int j = 0; j < 4; ++j) {
      int cb = wn * 4 + j;
      b[j] = *reinterpret_cast<const bf16x8*>(
          w1p + ((ks * 16 + cb) * 64 + lane) * 8);
    }
#pragma unroll
    for (int m = 0; m < 2; ++m)
#pragma unroll
      for (int j = 0; j < 4; ++j)
        acc[m][j] = __builtin_amdgcn_mfma_f32_16x16x32_bf16(a[m], b[j],
                                                            acc[m][j], 0, 0, 0);
  }
  __syncthreads();

#pragma unroll
  for (int m = 0; m < 2; ++m)
#pragma unroll
    for (int j = 0; j < 4; ++j) {
      int col = wn * 64 + j * 16 + lr;
      float bias = b1[col];
#pragma unroll
      for (int r = 0; r < 4; ++r) {
        float z = acc[m][j][r] + bias;
        z = z >= 0.f ? z : NEG_SLOPE * z;
        int zr = m * 16 + lhi * 4 + r;
        int byte = (zr * 512 + col * 2) ^ ((zr & 7) << 4);
        *reinterpret_cast<short*>(reinterpret_cast<char*>(lds) + byte) = f2bf(z);
      }
    }
  __syncthreads();

#pragma unroll
  for (int m = 0; m < 2; ++m)
#pragma unroll
    for (int j = 0; j < 4; ++j) acc[m][j] = zero4;

#pragma unroll
  for (int ks = 0; ks < 8; ++ks) {
    bf16x8 a[2], b[4];
#pragma unroll
    for (int m = 0; m < 2; ++m) {
      int ar = m * 16 + lr;
      int abyte = (ar * 512 + ks * 64 + lhi * 16) ^ ((ar & 7) << 4);
      a[m] = *reinterpret_cast<const bf16x8*>(
          reinterpret_cast<const char*>(lds) + abyte);
    }
#pragma unroll
    for (int j = 0; j < 4; ++j) {
      int cb = wn * 4 + j;
      b[j] = *reinterpret_cast<const bf16x8*>(
          w2p + ((ks * 16 + cb) * 64 + lane) * 8);
    }
#pragma unroll
    for (int m = 0; m < 2; ++m)
#pragma unroll
      for (int j = 0; j < 4; ++j)
        acc[m][j] = __builtin_amdgcn_mfma_f32_16x16x32_bf16(a[m], b[j],
                                                            acc[m][j], 0, 0, 0);
  }
  __syncthreads();

#pragma unroll
  for (int m = 0; m < 2; ++m)
#pragma unroll
    for (int j = 0; j < 4; ++j) {
      int col = wn * 64 + j * 16 + lr;
      float bias = b2[col];
#pragma unroll
      for (int r = 0; r < 4; ++r) {
        float d = acc[m][j][r] + bias;
        int zr = m * 16 + lhi * 4 + r;
        int byte = (zr * 512 + col * 2) ^ ((zr & 7) << 4);
        *reinterpret_cast<short*>(reinterpret_cast<char*>(lds) + byte) = f2bf(d);
      }
    }
  __syncthreads();

  {
    int row = tid >> 3;
    int sub = tid & 7;
    int grow = row0 + row;
    if (grow < n) {
      float mask = counts[grow] > 0 ? 1.0f : 0.0f;
      float* orow = out + (size_t)grow * H;
      const float* hrow = h + (size_t)grow * H;
#pragma unroll
      for (int u = 0; u < 4; ++u) {
        int col = sub * 8 + u * 64;
        int byte = (row * 512 + col * 2) ^ ((row & 7) << 4);
        bf16x8 dv = *reinterpret_cast<const bf16x8*>(
            reinterpret_cast<const char*>(lds) + byte);
        f32x4 h0 = *reinterpret_cast<const f32x4*>(hrow + col);
        f32x4 h1 = *reinterpret_cast<const f32x4*>(hrow + col + 4);
        f32x4 o0, o1;
        o0.x = h0.x + bf2f(dv[0]) * mask;
        o0.y = h0.y + bf2f(dv[1]) * mask;
        o0.z = h0.z + bf2f(dv[2]) * mask;
        o0.w = h0.w + bf2f(dv[3]) * mask;
        o1.x = h1.x + bf2f(dv[4]) * mask;
        o1.y = h1.y + bf2f(dv[5]) * mask;
        o1.z = h1.z + bf2f(dv[6]) * mask;
        o1.w = h1.w + bf2f(dv[7]) * mask;
        *reinterpret_cast<f32x4*>(orow + col) = o0;
        *reinterpret_cast<f32x4*>(orow + col + 4) = o1;
      }
    }
  }
}

// ---------------- mid fallback: fused gather+MLP (linear weights, f32) -----
__global__ __launch_bounds__(256) void fused_kernel(
    const float* __restrict__ h, const int* __restrict__ childlist,
    const int* __restrict__ offsets, const int* __restrict__ counts,
    const short* __restrict__ w1b, const short* __restrict__ w2b,
    const float* __restrict__ b1, const float* __restrict__ b2,
    float* __restrict__ out, int n) {
  __shared__ short lds[TILE_M * H];

  const int tid = threadIdx.x;
  const int row0 = blockIdx.x * TILE_M;
  const int lane = tid & 63;
  const int wv = tid >> 6;
  const int wrow = wv * 16;
  const int lr = lane & 15;
  const int lhi = lane >> 4;

  int rid = row0 + wrow + lr;
  if (rid >= n) rid = n - 1;
  const int myc = counts[rid];
  const int myo = offsets[rid];

  for (int rr = 0; rr < 16; ++rr) {
    int deg = __shfl(myc, rr);
    int off = __shfl(myo, rr);
    int degc = deg < 64 ? deg : 64;
    int cidx = 0;
    if (lane < degc) cidx = childlist[off + lane];
    f32x4 acc = {0.f, 0.f, 0.f, 0.f};
    int i = 0;
    for (; i + 4 <= degc; i += 4) {
      int c0 = __shfl(cidx, i);
      int c1 = __shfl(cidx, i + 1);
      int c2 = __shfl(cidx, i + 2);
      int c3 = __shfl(cidx, i + 3);
      f32x4 v0 = ((const f32x4*)(h + (size_t)c0 * H))[lane];
      f32x4 v1 = ((const f32x4*)(h + (size_t)c1 * H))[lane];
      f32x4 v2 = ((const f32x4*)(h + (size_t)c2 * H))[lane];
      f32x4 v3 = ((const f32x4*)(h + (size_t)c3 * H))[lane];
      acc += v0 + v1 + v2 + v3;
    }
    for (; i < degc; ++i) {
      int c = __shfl(cidx, i);
      acc += ((const f32x4*)(h + (size_t)c * H))[lane];
    }
    for (; i < deg; ++i) {
      int c = childlist[off + i];
      acc += ((const f32x4*)(h + (size_t)c * H))[lane];
    }
    float inv = 1.0f / (float)(deg > 0 ? deg : 1);
    acc *= inv;
    s16x4 bv;
    bv.x = f2bf(acc.x);
    bv.y = f2bf(acc.y);
    bv.z = f2bf(acc.z);
    bv.w = f2bf(acc.w);
    int r = wrow + rr;
    int byte = (r * 512 + lane * 8) ^ ((r & 7) << 4);
    *reinterpret_cast<s16x4*>(reinterpret_cast<char*>(lds) + byte) = bv;
  }
  __syncthreads();

  const f32x4 zero4 = {0.f, 0.f, 0.f, 0.f};
  f32x4 acc[4][4];
#pragma unroll
  for (int m = 0; m < 4; ++m)
#pragma unroll
    for (int j = 0; j < 4; ++j) acc[m][j] = zero4;

#pragma unroll
  for (int ks = 0; ks < 8; ++ks) {
    bf16x8 a[4], b[4];
#pragma unroll
    for (int m = 0; m < 4; ++m) {
      int ar = m * 16 + lr;
      int abyte = (ar * 512 + ks * 64 + lhi * 16) ^ ((ar & 7) << 4);
      a[m] = *reinterpret_cast<const bf16x8*>(
          reinterpret_cast<const char*>(lds) + abyte);
    }
#pragma unroll
    for (int j = 0; j < 4; ++j) {
      int col = wv * 64 + j * 16 + lr;
      b[j] = *reinterpret_cast<const bf16x8*>(w1b + col * H + ks * 32 + lhi * 8);
    }
#pragma unroll
    for (int m = 0; m < 4; ++m)
#pragma unroll
      for (int j = 0; j < 4; ++j)
        acc[m][j] = __builtin_amdgcn_mfma_f32_16x16x32_bf16(a[m], b[j],
                                                            acc[m][j], 0, 0, 0);
  }
  __syncthreads();

#pragma unroll
  for (int m = 0; m < 4; ++m)
#pragma unroll
    for (int j = 0; j < 4; ++j) {
      int col = wv * 64 + j * 16 + lr;
      float bias = b1[col];
#pragma unroll
      for (int r = 0; r < 4; ++r) {
        float z = acc[m][j][r] + bias;
        z = z >= 0.f ? z : NEG_SLOPE * z;
        int zr = m * 16 + lhi * 4 + r;
        int byte = (zr * 512 + col * 2) ^ ((zr & 7) << 4);
        *reinterpret_cast<short*>(reinterpret_cast<char*>(lds) + byte) = f2bf(z);
      }
    }
  __syncthreads();

#pragma unroll
  for (int m = 0; m < 4; ++m)
#pragma unroll
    for (int j = 0; j < 4; ++j) acc[m][j] = zero4;

#pragma unroll
  for (int ks = 0; ks < 8; ++ks) {
    bf16x8 a[4], b[4];
#pragma unroll
    for (int m = 0; m < 4; ++m) {
      int ar = m * 16 + lr;
      int abyte = (ar * 512 + ks * 64 + lhi * 16) ^ ((ar & 7) << 4);
      a[m] = *reinterpret_cast<const bf16x8*>(
          reinterpret_cast<const char*>(lds) + abyte);
    }
#pragma unroll
    for (int j = 0; j < 4; ++j) {
      int col = wv * 64 + j * 16 + lr;
      b[j] = *reinterpret_cast<const bf16x8*>(w2b + col * H + ks * 32 + lhi * 8);
    }
#pragma unroll
    for (int m = 0; m < 4; ++m)
#pragma unroll
      for (int j = 0; j < 4; ++j)
        acc[m][j] = __builtin_amdgcn_mfma_f32_16x16x32_bf16(a[m], b[j],
                                                            acc[m][j], 0, 0, 0);
  }

#pragma unroll
  for (int m = 0; m < 4; ++m) {
#pragma unroll
    for (int r = 0; r < 4; ++r) {
      int grow = row0 + m * 16 + lhi * 4 + r;
      if (grow < n) {
        float mask = counts[grow] > 0 ? 1.0f : 0.0f;
        const float* hrow = h + (size_t)grow * H;
        float* orow = out + (size_t)grow * H;
#pragma unroll
        for (int j = 0; j < 4; ++j) {
          int col = wv * 64 + j * 16 + lr;
          orow[col] = hrow[col] + (acc[m][j][r] + b2[col]) * mask;
        }
      }
    }
  }
}

// ---------------- last-resort fallback: atomic agg ----------------
__global__ __launch_bounds__(256) void agg_kernel(
    const float* __restrict__ h, const int* __restrict__ parent,
    const int* __restrict__ child, float* __restrict__ sums,
    int* __restrict__ counts, int E) {
  int gid = blockIdx.x * blockDim.x + threadIdx.x;
  int e = gid >> 6;
  if (e >= E) return;
  int lane = threadIdx.x & 63;
  int p = parent[e];
  int c = child[e];
  f32x4 v = ((const f32x4*)(h + (size_t)c * H))[lane];
  float* dst = sums + (size_t)p * H + lane * 4;
  unsafeAtomicAdd(dst + 0, v.x);
  unsafeAtomicAdd(dst + 1, v.y);
  unsafeAtomicAdd(dst + 2, v.z);
  unsafeAtomicAdd(dst + 3, v.w);
  if (lane == 0) atomicAdd(counts + p, 1);
}

__global__ __launch_bounds__(256) void mean_div_bf16_kernel(
    const float* __restrict__ sums, const int* __restrict__ counts,
    short* __restrict__ meansb, int n) {
  int w = (blockIdx.x * blockDim.x + threadIdx.x) >> 6;
  if (w >= n) return;
  int lane = threadIdx.x & 63;
  float inv = 1.0f / fmaxf((float)counts[w], 1.0f);
  f32x4 v = ((const f32x4*)(sums + (size_t)w * H))[lane];
  v *= inv;
  s16x4 bv;
  bv.x = f2bf(v.x);
  bv.y = f2bf(v.y);
  bv.z = f2bf(v.z);
  bv.w = f2bf(v.w);
  *reinterpret_cast<s16x4*>(meansb + (size_t)w * H + lane * 4) = bv;
}

extern "C" void kernel_launch(void* const* d_in, const int* in_sizes, int n_in,
                              void* d_out, int out_size, void* d_ws, size_t ws_size,
                              hipStream_t stream) {
  const float* h  = (const float*)d_in[0];
  const int* edges = (const int*)d_in[1];
  const float* W1 = (const float*)d_in[2];
  const float* b1 = (const float*)d_in[3];
  const float* W2 = (const float*)d_in[4];
  const float* b2 = (const float*)d_in[5];
  float* out = (float*)d_out;

  const int n = in_sizes[0] / H;   // 200000
  const int E = in_sizes[1] / 2;   // 1000000
  const int* parent = edges;
  const int* child = edges + E;

  char* ws = (char*)d_ws;
  int* counts    = (int*)(ws);                // n ints (800 KB)
  short* w1b     = (short*)(ws + 0x100000);   // 128 KB linear
  short* w2b     = (short*)(ws + 0x120000);   // 128 KB linear
  short* w1p     = (short*)(ws + 0x140000);   // 128 KB packed
  short* w2p     = (short*)(ws + 0x160000);   // 128 KB packed
  int* excl      = (int*)(ws + 0x180000);     // n ints
  int* cursor    = (int*)(ws + 0x280000);     // n ints
  int* blockSums = (int*)(ws + 0x380000);     // 256 ints
  int* offsets   = (int*)(ws + 0x384000);     // n ints
  int* childlist = (int*)(ws + 0x484000);     // E ints (4 MB @ E=1M)
  short* hb      = (short*)(ws + 0x884000);   // n*H bf16 (102.4 MB)
  size_t meansz  = (size_t)n * H * 2;

  size_t need_csr   = 0x484000 + (size_t)E * 4;
  size_t need_fused = 0x884000 + meansz;      // CSR + hb
  int nblk64 = (n + TILE_M - 1) / TILE_M;
  int nblk32 = (n + TILE_M2 - 1) / TILE_M2;

  cvt_kernel<<<(H * H + 255) / 256, 256, 0, stream>>>(W1, W2, w1b, w2b, w1p, w2p);

  if (ws_size >= need_fused && E <= (0x400000 / 4) && n <= 256 * 1024) {
    hipMemsetAsync(counts, 0, (size_t)n * sizeof(int), stream);
    long total8 = (long)n * H / 8;
    int nbCvt = (int)((total8 + 255) / 256);
    int nbHist = (E + 255) / 256;
    prep_kernel<<<nbCvt + nbHist, 256, 0, stream>>>(h, hb, total8, parent,
                                                    counts, E, nbCvt);
    int nb = (n + 1023) >> 10;
    scan1_kernel<<<nb, 256, 0, stream>>>(counts, excl, blockSums, n);
    scan2_kernel<<<1, 256, 0, stream>>>(blockSums, nb);
    scan3_kernel<<<(n + 255) / 256, 256, 0, stream>>>(excl, blockSums, offsets,
                                                      cursor, n);
    scatter_kernel<<<(E + 255) / 256, 256, 0, stream>>>(parent, child, cursor,
                                                        childlist, E);
    gm_mlp_kernel<<<nblk32, 256, 0, stream>>>(hb, childlist, offsets, counts,
                                              w1p, w2p, b1, b2, out, n);
  } else if (ws_size >= need_csr && n <= 256 * 1024) {
    hipMemsetAsync(counts, 0, (size_t)n * sizeof(int), stream);
    hist_kernel<<<(E + 255) / 256, 256, 0, stream>>>(parent, counts, E);
    int nb = (n + 1023) >> 10;
    scan1_kernel<<<nb, 256, 0, stream>>>(counts, excl, blockSums, n);
    scan2_kernel<<<1, 256, 0, stream>>>(blockSums, nb);
    scan3_kernel<<<(n + 255) / 256, 256, 0, stream>>>(excl, blockSums, offsets,
                                                      cursor, n);
    scatter_kernel<<<(E + 255) / 256, 256, 0, stream>>>(parent, child, cursor,
                                                        childlist, E);
    fused_kernel<<<nblk64, 256, 0, stream>>>(h, childlist, offsets, counts, w1b,
                                             w2b, b1, b2, out, n);
  } else {
    hipMemsetAsync(out, 0, (size_t)n * H * sizeof(float), stream);
    hipMemsetAsync(counts, 0, (size_t)n * sizeof(int), stream);
    agg_kernel<<<(E + 3) / 4, 256, 0, stream>>>(h, parent, child, out, counts, E);
    mean_div_bf16_kernel<<<((size_t)n * 64 + 255) / 256, 256, 0, stream>>>(
        out, counts, (short*)(ws + 0x180000), n);
    mlp2_kernel<<<nblk32, 256, 0, stream>>>(h, nullptr,
                                            (short*)(ws + 0x180000), counts,
                                            w1p, w2p, b1, b2, out, n);
  }
}

// Round 17
// 323.870 us; speedup vs baseline: 1.5081x; 1.0091x over previous
//
#include <hip/hip_runtime.h>
#include <hip/hip_bf16.h>

#define H 256
#define NEG_SLOPE 0.01f
#define TILE_M 64
#define TILE_M2 32

typedef __attribute__((ext_vector_type(4))) float f32x4;
typedef __attribute__((ext_vector_type(8))) short bf16x8;
typedef __attribute__((ext_vector_type(4))) short s16x4;

__device__ __forceinline__ short f2bf(float f) {
  __hip_bfloat16 b = __float2bfloat16(f);
  return *reinterpret_cast<short*>(&b);
}
__device__ __forceinline__ float bf2f(short s) {
  unsigned u = ((unsigned)(unsigned short)s) << 16;
  return __uint_as_float(u);
}

// ---------------- CSR build ----------------

__global__ __launch_bounds__(256) void hist_kernel(
    const int* __restrict__ parent, int* __restrict__ counts, int E) {
  int e = blockIdx.x * blockDim.x + threadIdx.x;
  if (e < E) atomicAdd(counts + parent[e], 1);
}

// Fused: blocks [0,nbCvt) convert h->hb (bf16, NT h loads); rest histogram.
__global__ __launch_bounds__(256) void prep_kernel(
    const float* __restrict__ h, short* __restrict__ hb, long total8,
    const int* __restrict__ parent, int* __restrict__ counts, int E,
    int nbCvt) {
  int b = blockIdx.x;
  if (b < nbCvt) {
    long i = (long)b * 256 + threadIdx.x;
    if (i >= total8) return;
    const f32x4* src = (const f32x4*)(h + i * 8);
    f32x4 v0 = __builtin_nontemporal_load(src);
    f32x4 v1 = __builtin_nontemporal_load(src + 1);
    bf16x8 o;
    o[0] = f2bf(v0.x); o[1] = f2bf(v0.y); o[2] = f2bf(v0.z); o[3] = f2bf(v0.w);
    o[4] = f2bf(v1.x); o[5] = f2bf(v1.y); o[6] = f2bf(v1.z); o[7] = f2bf(v1.w);
    *reinterpret_cast<bf16x8*>(hb + i * 8) = o;
  } else {
    int e = (b - nbCvt) * 256 + threadIdx.x;
    if (e < E) atomicAdd(counts + parent[e], 1);
  }
}

__global__ __launch_bounds__(256) void scan1_kernel(
    const int* __restrict__ counts, int* __restrict__ excl,
    int* __restrict__ blockSums, int n) {
  __shared__ int lds[256];
  int tid = threadIdx.x;
  int base = blockIdx.x * 1024 + tid * 4;
  int4 v = {0, 0, 0, 0};
  if (base + 3 < n) v = *reinterpret_cast<const int4*>(counts + base);
  int s = v.x + v.y + v.z + v.w;
  lds[tid] = s;
  __syncthreads();
  for (int off = 1; off < 256; off <<= 1) {
    int t = (tid >= off) ? lds[tid - off] : 0;
    __syncthreads();
    lds[tid] += t;
    __syncthreads();
  }
  int toff = lds[tid] - s;
  if (base + 3 < n) {
    int4 o;
    o.x = toff;
    o.y = toff + v.x;
    o.z = o.y + v.y;
    o.w = o.z + v.z;
    *reinterpret_cast<int4*>(excl + base) = o;
  }
  if (tid == 255) blockSums[blockIdx.x] = lds[255];
}

__global__ __launch_bounds__(256) void scan2_kernel(int* __restrict__ blockSums,
                                                    int nb) {
  __shared__ int lds[256];
  int tid = threadIdx.x;
  int s = (tid < nb) ? blockSums[tid] : 0;
  lds[tid] = s;
  __syncthreads();
  for (int off = 1; off < 256; off <<= 1) {
    int t = (tid >= off) ? lds[tid - off] : 0;
    __syncthreads();
    lds[tid] += t;
    __syncthreads();
  }
  if (tid < nb) blockSums[tid] = lds[tid] - s;
}

__global__ __launch_bounds__(256) void scan3_kernel(
    const int* __restrict__ excl, const int* __restrict__ blockSums,
    int* __restrict__ offsets, int* __restrict__ cursor, int n) {
  int i = blockIdx.x * blockDim.x + threadIdx.x;
  if (i < n) {
    int v = excl[i] + blockSums[i >> 10];
    offsets[i] = v;
    cursor[i] = v;
  }
}

__global__ __launch_bounds__(256) void scatter_kernel(
    const int* __restrict__ parent, const int* __restrict__ child,
    int* __restrict__ cursor, int* __restrict__ childlist, int E) {
  int e = blockIdx.x * blockDim.x + threadIdx.x;
  if (e < E) {
    int pos = atomicAdd(cursor + parent[e], 1);
    childlist[pos] = child[e];
  }
}

// Linear bf16 copies + fragment-packed copies.
__global__ __launch_bounds__(256) void cvt_kernel(
    const float* __restrict__ W1, const float* __restrict__ W2,
    short* __restrict__ w1b, short* __restrict__ w2b,
    short* __restrict__ w1p, short* __restrict__ w2p) {
  int i = blockIdx.x * blockDim.x + threadIdx.x;
  if (i < H * H) {
    short v1 = f2bf(W1[i]);
    short v2 = f2bf(W2[i]);
    w1b[i] = v1;
    w2b[i] = v2;
    int col = i >> 8, k = i & 255;
    int ks = k >> 5, lhi = (k >> 3) & 3, e = k & 7;
    int cb = col >> 4, lrr = col & 15;
    int pos = ((ks * 16 + cb) * 64 + lhi * 16 + lrr) * 8 + e;
    w1p[pos] = v1;
    w2p[pos] = v2;
  }
}

// ---------------- fully fused: gather-mean -> MLP -> residual --------------
// 256 threads / 4 waves, tile 32 rows. Phase A: 8-wide predicated gather +
// next-row index prefetch. Epilogue: NON-TEMPORAL out stores so the 205MB
// write stream doesn't evict hb from L3 (R16: FETCH was 304MB vs ~106
// compulsory — out-stream L3 pollution).
__global__ __launch_bounds__(256, 4) void gm_mlp_kernel(
    const short* __restrict__ hb, const int* __restrict__ childlist,
    const int* __restrict__ offsets, const int* __restrict__ counts,
    const short* __restrict__ w1p, const short* __restrict__ w2p,
    const float* __restrict__ b1, const float* __restrict__ b2,
    float* __restrict__ out, int n) {
  __shared__ short lds[TILE_M2 * H];  // 16 KB: means -> z -> delta
  __shared__ float cmask[TILE_M2];

  const int tid = threadIdx.x;
  const int row0 = blockIdx.x * TILE_M2;
  const int lane = tid & 63;
  const int wv = tid >> 6;     // wave = col stripe, and gather row group
  const int lr = lane & 15;
  const int lhi = lane >> 4;

  // ---- Phase A: gather-mean rows [wv*8, wv*8+8) ----
  {
    int rid = row0 + wv * 8 + (lane & 7);
    if (rid >= n) rid = n - 1;
    int myc = counts[rid];
    int myo = offsets[rid];

    int deg_n = __shfl(myc, 0);
    int off_n = __shfl(myo, 0);
    int dcn = deg_n < 64 ? deg_n : 64;
    int cidx_n = 0;
    if (lane < dcn) cidx_n = childlist[off_n + lane];

    for (int rr = 0; rr < 8; ++rr) {
      const int deg = deg_n;
      const int off = off_n;
      const int degc = dcn;
      const int cidx = cidx_n;
      if (rr + 1 < 8) {
        deg_n = __shfl(myc, rr + 1);
        off_n = __shfl(myo, rr + 1);
        dcn = deg_n < 64 ? deg_n : 64;
        cidx_n = 0;
        if (lane < dcn) cidx_n = childlist[off_n + lane];
      }

      f32x4 acc = {0.f, 0.f, 0.f, 0.f};
      const int k8 = degc < 8 ? degc : 8;
      s16x4 v[8];
#pragma unroll
      for (int j = 0; j < 8; ++j)
        if (j < k8) {
          int c = __shfl(cidx, j);
          v[j] = ((const s16x4*)(hb + (size_t)c * H))[lane];
        }
#pragma unroll
      for (int j = 0; j < 8; ++j)
        if (j < k8) {
          acc.x += bf2f(v[j].x);
          acc.y += bf2f(v[j].y);
          acc.z += bf2f(v[j].z);
          acc.w += bf2f(v[j].w);
        }
      int i = 8;
      for (; i + 4 <= degc; i += 4) {
        int c0 = __shfl(cidx, i);
        int c1 = __shfl(cidx, i + 1);
        int c2 = __shfl(cidx, i + 2);
        int c3 = __shfl(cidx, i + 3);
        s16x4 v0 = ((const s16x4*)(hb + (size_t)c0 * H))[lane];
        s16x4 v1 = ((const s16x4*)(hb + (size_t)c1 * H))[lane];
        s16x4 v2 = ((const s16x4*)(hb + (size_t)c2 * H))[lane];
        s16x4 v3 = ((const s16x4*)(hb + (size_t)c3 * H))[lane];
        acc.x += bf2f(v0.x) + bf2f(v1.x) + bf2f(v2.x) + bf2f(v3.x);
        acc.y += bf2f(v0.y) + bf2f(v1.y) + bf2f(v2.y) + bf2f(v3.y);
        acc.z += bf2f(v0.z) + bf2f(v1.z) + bf2f(v2.z) + bf2f(v3.z);
        acc.w += bf2f(v0.w) + bf2f(v1.w) + bf2f(v2.w) + bf2f(v3.w);
      }
      for (; i < degc; ++i) {
        int c = __shfl(cidx, i);
        s16x4 vv = ((const s16x4*)(hb + (size_t)c * H))[lane];
        acc.x += bf2f(vv.x);
        acc.y += bf2f(vv.y);
        acc.z += bf2f(vv.z);
        acc.w += bf2f(vv.w);
      }
      for (; i < deg; ++i) {
        int c = childlist[off + i];
        s16x4 vv = ((const s16x4*)(hb + (size_t)c * H))[lane];
        acc.x += bf2f(vv.x);
        acc.y += bf2f(vv.y);
        acc.z += bf2f(vv.z);
        acc.w += bf2f(vv.w);
      }
      float inv = 1.0f / (float)(deg > 0 ? deg : 1);
      acc *= inv;
      int r = wv * 8 + rr;
      if (lane == 0) cmask[r] = deg > 0 ? 1.0f : 0.0f;
      s16x4 bv;
      bv.x = f2bf(acc.x);
      bv.y = f2bf(acc.y);
      bv.z = f2bf(acc.z);
      bv.w = f2bf(acc.w);
      int byte = (r * 512 + lane * 8) ^ ((r & 7) << 4);
      *reinterpret_cast<s16x4*>(reinterpret_cast<char*>(lds) + byte) = bv;
    }
  }
  __syncthreads();

  const f32x4 zero4 = {0.f, 0.f, 0.f, 0.f};
  f32x4 acc[2][4];
#pragma unroll
  for (int m = 0; m < 2; ++m)
#pragma unroll
    for (int j = 0; j < 4; ++j) acc[m][j] = zero4;

  // ---- Layer 1: z = mean @ W1^T ----
#pragma unroll
  for (int ks = 0; ks < 8; ++ks) {
    bf16x8 a[2], b[4];
#pragma unroll
    for (int m = 0; m < 2; ++m) {
      int ar = m * 16 + lr;
      int abyte = (ar * 512 + ks * 64 + lhi * 16) ^ ((ar & 7) << 4);
      a[m] = *reinterpret_cast<const bf16x8*>(
          reinterpret_cast<const char*>(lds) + abyte);
    }
#pragma unroll
    for (int j = 0; j < 4; ++j) {
      int cb = wv * 4 + j;
      b[j] = *reinterpret_cast<const bf16x8*>(
          w1p + ((ks * 16 + cb) * 64 + lane) * 8);
    }
#pragma unroll
    for (int m = 0; m < 2; ++m)
#pragma unroll
      for (int j = 0; j < 4; ++j)
        acc[m][j] = __builtin_amdgcn_mfma_f32_16x16x32_bf16(a[m], b[j],
                                                            acc[m][j], 0, 0, 0);
  }
  __syncthreads();  // all means reads done; tile will hold z

  // z (activated, bf16) into LDS stripe.
#pragma unroll
  for (int m = 0; m < 2; ++m)
#pragma unroll
    for (int j = 0; j < 4; ++j) {
      int col = wv * 64 + j * 16 + lr;
      float bias = b1[col];
#pragma unroll
      for (int r = 0; r < 4; ++r) {
        float z = acc[m][j][r] + bias;
        z = z >= 0.f ? z : NEG_SLOPE * z;
        int zr = m * 16 + lhi * 4 + r;
        int byte = (zr * 512 + col * 2) ^ ((zr & 7) << 4);
        *reinterpret_cast<short*>(reinterpret_cast<char*>(lds) + byte) = f2bf(z);
      }
    }
  __syncthreads();

  // ---- Layer 2: delta = z @ W2^T ----
#pragma unroll
  for (int m = 0; m < 2; ++m)
#pragma unroll
    for (int j = 0; j < 4; ++j) acc[m][j] = zero4;

#pragma unroll
  for (int ks = 0; ks < 8; ++ks) {
    bf16x8 a[2], b[4];
#pragma unroll
    for (int m = 0; m < 2; ++m) {
      int ar = m * 16 + lr;
      int abyte = (ar * 512 + ks * 64 + lhi * 16) ^ ((ar & 7) << 4);
      a[m] = *reinterpret_cast<const bf16x8*>(
          reinterpret_cast<const char*>(lds) + abyte);
    }
#pragma unroll
    for (int j = 0; j < 4; ++j) {
      int cb = wv * 4 + j;
      b[j] = *reinterpret_cast<const bf16x8*>(
          w2p + ((ks * 16 + cb) * 64 + lane) * 8);
    }
#pragma unroll
    for (int m = 0; m < 2; ++m)
#pragma unroll
      for (int j = 0; j < 4; ++j)
        acc[m][j] = __builtin_amdgcn_mfma_f32_16x16x32_bf16(a[m], b[j],
                                                            acc[m][j], 0, 0, 0);
  }
  __syncthreads();  // all z reads done; tile will hold delta

  // delta (+b2, bf16) into LDS stripe.
#pragma unroll
  for (int m = 0; m < 2; ++m)
#pragma unroll
    for (int j = 0; j < 4; ++j) {
      int col = wv * 64 + j * 16 + lr;
      float bias = b2[col];
#pragma unroll
      for (int r = 0; r < 4; ++r) {
        float d = acc[m][j][r] + bias;
        int zr = m * 16 + lhi * 4 + r;
        int byte = (zr * 512 + col * 2) ^ ((zr & 7) << 4);
        *reinterpret_cast<short*>(reinterpret_cast<char*>(lds) + byte) = f2bf(d);
      }
    }
  __syncthreads();

  // Vectorized epilogue: NT stores for out (write-once stream).
  {
    int row = tid >> 3;
    int sub = tid & 7;
    int grow = row0 + row;
    if (grow < n) {
      float mask = cmask[row];
      float* orow = out + (size_t)grow * H;
      const short* hrow = hb + (size_t)grow * H;
#pragma unroll
      for (int u = 0; u < 4; ++u) {
        int col = sub * 8 + u * 64;
        int byte = (row * 512 + col * 2) ^ ((row & 7) << 4);
        bf16x8 dv = *reinterpret_cast<const bf16x8*>(
            reinterpret_cast<const char*>(lds) + byte);
        bf16x8 hv = *reinterpret_cast<const bf16x8*>(hrow + col);
        f32x4 o0, o1;
        o0.x = bf2f(hv[0]) + bf2f(dv[0]) * mask;
        o0.y = bf2f(hv[1]) + bf2f(dv[1]) * mask;
        o0.z = bf2f(hv[2]) + bf2f(dv[2]) * mask;
        o0.w = bf2f(hv[3]) + bf2f(dv[3]) * mask;
        o1.x = bf2f(hv[4]) + bf2f(dv[4]) * mask;
        o1.y = bf2f(hv[5]) + bf2f(dv[5]) * mask;
        o1.z = bf2f(hv[6]) + bf2f(dv[6]) * mask;
        o1.w = bf2f(hv[7]) + bf2f(dv[7]) * mask;
        __builtin_nontemporal_store(o0, reinterpret_cast<f32x4*>(orow + col));
        __builtin_nontemporal_store(o1,
                                    reinterpret_cast<f32x4*>(orow + col + 4));
      }
    }
  }
}

// ---------------- non-fused MLP (atomic-fallback path) ----------------
__global__ __launch_bounds__(256, 4) void mlp2_kernel(
    const float* __restrict__ h, const short* __restrict__ hres,
    const short* __restrict__ meansb, const int* __restrict__ counts,
    const short* __restrict__ w1p, const short* __restrict__ w2p,
    const float* __restrict__ b1, const float* __restrict__ b2,
    float* __restrict__ out, int n) {
  __shared__ short lds[TILE_M2 * H];

  const int tid = threadIdx.x;
  const int row0 = blockIdx.x * TILE_M2;
  const int lane = tid & 63;
  const int wn = tid >> 6;
  const int lr = lane & 15;
  const int lhi = lane >> 4;

#pragma unroll
  for (int v = 0; v < 4; ++v) {
    int lin = v * 4096 + tid * 16;
    int row = lin >> 9;
    int grow = row0 + row;
    if (grow >= n) grow = n - 1;
    bf16x8 mv = *reinterpret_cast<const bf16x8*>(
        meansb + (size_t)grow * H + ((lin & 511) >> 1));
    int byte = lin ^ ((row & 7) << 4);
    *reinterpret_cast<bf16x8*>(reinterpret_cast<char*>(lds) + byte) = mv;
  }
  __syncthreads();

  const f32x4 zero4 = {0.f, 0.f, 0.f, 0.f};
  f32x4 acc[2][4];
#pragma unroll
  for (int m = 0; m < 2; ++m)
#pragma unroll
    for (int j = 0; j < 4; ++j) acc[m][j] = zero4;

#pragma unroll
  for (int ks = 0; ks < 8; ++ks) {
    bf16x8 a[2], b[4];
#pragma unroll
    for (int m = 0; m < 2; ++m) {
      int ar = m * 16 + lr;
      int abyte = (ar * 512 + ks * 64 + lhi * 16) ^ ((ar & 7) << 4);
      a[m] = *reinterpret_cast<const bf16x8*>(
          reinterpret_cast<const char*>(lds) + abyte);
    }
#pragma unroll
    for (int j = 0; j < 4; ++j) {
      int cb = wn * 4 + j;
      b[j] = *reinterpret_cast<const bf16x8*>(
          w1p + ((ks * 16 + cb) * 64 + lane) * 8);
    }
#pragma unroll
    for (int m = 0; m < 2; ++m)
#pragma unroll
      for (int j = 0; j < 4; ++j)
        acc[m][j] = __builtin_amdgcn_mfma_f32_16x16x32_bf16(a[m], b[j],
                                                            acc[m][j], 0, 0, 0);
  }
  __syncthreads();

#pragma unroll
  for (int m = 0; m < 2; ++m)
#pragma unroll
    for (int j = 0; j < 4; ++j) {
      int col = wn * 64 + j * 16 + lr;
      float bias = b1[col];
#pragma unroll
      for (int r = 0; r < 4; ++r) {
        float z = acc[m][j][r] + bias;
        z = z >= 0.f ? z : NEG_SLOPE * z;
        int zr = m * 16 + lhi * 4 + r;
        int byte = (zr * 512 + col * 2) ^ ((zr & 7) << 4);
        *reinterpret_cast<short*>(reinterpret_cast<char*>(lds) + byte) = f2bf(z);
      }
    }
  __syncthreads();

#pragma unroll
  for (int m = 0; m < 2; ++m)
#pragma unroll
    for (int j = 0; j < 4; ++j) acc[m][j] = zero4;

#pragma unroll
  for (int ks = 0; ks < 8; ++ks) {
    bf16x8 a[2], b[4];
#pragma unroll
    for (int m = 0; m < 2; ++m) {
      int ar = m * 16 + lr;
      int abyte = (ar * 512 + ks * 64 + lhi * 16) ^ ((ar & 7) << 4);
      a[m] = *reinterpret_cast<const bf16x8*>(
          reinterpret_cast<const char*>(lds) + abyte);
    }
#pragma unroll
    for (int j = 0; j < 4; ++j) {
      int cb = wn * 4 + j;
      b[j] = *reinterpret_cast<const bf16x8*>(
          w2p + ((ks * 16 + cb) * 64 + lane) * 8);
    }
#pragma unroll
    for (int m = 0; m < 2; ++m)
#pragma unroll
      for (int j = 0; j < 4; ++j)
        acc[m][j] = __builtin_amdgcn_mfma_f32_16x16x32_bf16(a[m], b[j],
                                                            acc[m][j], 0, 0, 0);
  }
  __syncthreads();

#pragma unroll
  for (int m = 0; m < 2; ++m)
#pragma unroll
    for (int j = 0; j < 4; ++j) {
      int col = wn * 64 + j * 16 + lr;
      float bias = b2[col];
#pragma unroll
      for (int r = 0; r < 4; ++r) {
        float d = acc[m][j][r] + bias;
        int zr = m * 16 + lhi * 4 + r;
        int byte = (zr * 512 + col * 2) ^ ((zr & 7) << 4);
        *reinterpret_cast<short*>(reinterpret_cast<char*>(lds) + byte) = f2bf(d);
      }
    }
  __syncthreads();

  {
    int row = tid >> 3;
    int sub = tid & 7;
    int grow = row0 + row;
    if (grow < n) {
      float mask = counts[grow] > 0 ? 1.0f : 0.0f;
      float* orow = out + (size_t)grow * H;
      const float* hrow = h + (size_t)grow * H;
#pragma unroll
      for (int u = 0; u < 4; ++u) {
        int col = sub * 8 + u * 64;
        int byte = (row * 512 + col * 2) ^ ((row & 7) << 4);
        bf16x8 dv = *reinterpret_cast<const bf16x8*>(
            reinterpret_cast<const char*>(lds) + byte);
        f32x4 h0 = *reinterpret_cast<const f32x4*>(hrow + col);
        f32x4 h1 = *reinterpret_cast<const f32x4*>(hrow + col + 4);
        f32x4 o0, o1;
        o0.x = h0.x + bf2f(dv[0]) * mask;
        o0.y = h0.y + bf2f(dv[1]) * mask;
        o0.z = h0.z + bf2f(dv[2]) * mask;
        o0.w = h0.w + bf2f(dv[3]) * mask;
        o1.x = h1.x + bf2f(dv[4]) * mask;
        o1.y = h1.y + bf2f(dv[5]) * mask;
        o1.z = h1.z + bf2f(dv[6]) * mask;
        o1.w = h1.w + bf2f(dv[7]) * mask;
        *reinterpret_cast<f32x4*>(orow + col) = o0;
        *reinterpret_cast<f32x4*>(orow + col + 4) = o1;
      }
    }
  }
}

// ---------------- mid fallback: fused gather+MLP (linear weights, f32) -----
__global__ __launch_bounds__(256) void fused_kernel(
    const float* __restrict__ h, const int* __restrict__ childlist,
    const int* __restrict__ offsets, const int* __restrict__ counts,
    const short* __restrict__ w1b, const short* __restrict__ w2b,
    const float* __restrict__ b1, const float* __restrict__ b2,
    float* __restrict__ out, int n) {
  __shared__ short lds[TILE_M * H];

  const int tid = threadIdx.x;
  const int row0 = blockIdx.x * TILE_M;
  const int lane = tid & 63;
  const int wv = tid >> 6;
  const int wrow = wv * 16;
  const int lr = lane & 15;
  const int lhi = lane >> 4;

  int rid = row0 + wrow + lr;
  if (rid >= n) rid = n - 1;
  const int myc = counts[rid];
  const int myo = offsets[rid];

  for (int rr = 0; rr < 16; ++rr) {
    int deg = __shfl(myc, rr);
    int off = __shfl(myo, rr);
    int degc = deg < 64 ? deg : 64;
    int cidx = 0;
    if (lane < degc) cidx = childlist[off + lane];
    f32x4 acc = {0.f, 0.f, 0.f, 0.f};
    int i = 0;
    for (; i + 4 <= degc; i += 4) {
      int c0 = __shfl(cidx, i);
      int c1 = __shfl(cidx, i + 1);
      int c2 = __shfl(cidx, i + 2);
      int c3 = __shfl(cidx, i + 3);
      f32x4 v0 = ((const f32x4*)(h + (size_t)c0 * H))[lane];
      f32x4 v1 = ((const f32x4*)(h + (size_t)c1 * H))[lane];
      f32x4 v2 = ((const f32x4*)(h + (size_t)c2 * H))[lane];
      f32x4 v3 = ((const f32x4*)(h + (size_t)c3 * H))[lane];
      acc += v0 + v1 + v2 + v3;
    }
    for (; i < degc; ++i) {
      int c = __shfl(cidx, i);
      acc += ((const f32x4*)(h + (size_t)c * H))[lane];
    }
    for (; i < deg; ++i) {
      int c = childlist[off + i];
      acc += ((const f32x4*)(h + (size_t)c * H))[lane];
    }
    float inv = 1.0f / (float)(deg > 0 ? deg : 1);
    acc *= inv;
    s16x4 bv;
    bv.x = f2bf(acc.x);
    bv.y = f2bf(acc.y);
    bv.z = f2bf(acc.z);
    bv.w = f2bf(acc.w);
    int r = wrow + rr;
    int byte = (r * 512 + lane * 8) ^ ((r & 7) << 4);
    *reinterpret_cast<s16x4*>(reinterpret_cast<char*>(lds) + byte) = bv;
  }
  __syncthreads();

  const f32x4 zero4 = {0.f, 0.f, 0.f, 0.f};
  f32x4 acc[4][4];
#pragma unroll
  for (int m = 0; m < 4; ++m)
#pragma unroll
    for (int j = 0; j < 4; ++j) acc[m][j] = zero4;

#pragma unroll
  for (int ks = 0; ks < 8; ++ks) {
    bf16x8 a[4], b[4];
#pragma unroll
    for (int m = 0; m < 4; ++m) {
      int ar = m * 16 + lr;
      int abyte = (ar * 512 + ks * 64 + lhi * 16) ^ ((ar & 7) << 4);
      a[m] = *reinterpret_cast<const bf16x8*>(
          reinterpret_cast<const char*>(lds) + abyte);
    }
#pragma unroll
    for (int j = 0; j < 4; ++j) {
      int col = wv * 64 + j * 16 + lr;
      b[j] = *reinterpret_cast<const bf16x8*>(w1b + col * H + ks * 32 + lhi * 8);
    }
#pragma unroll
    for (int m = 0; m < 4; ++m)
#pragma unroll
      for (int j = 0; j < 4; ++j)
        acc[m][j] = __builtin_amdgcn_mfma_f32_16x16x32_bf16(a[m], b[j],
                                                            acc[m][j], 0, 0, 0);
  }
  __syncthreads();

#pragma unroll
  for (int m = 0; m < 4; ++m)
#pragma unroll
    for (int j = 0; j < 4; ++j) {
      int col = wv * 64 + j * 16 + lr;
      float bias = b1[col];
#pragma unroll
      for (int r = 0; r < 4; ++r) {
        float z = acc[m][j][r] + bias;
        z = z >= 0.f ? z : NEG_SLOPE * z;
        int zr = m * 16 + lhi * 4 + r;
        int byte = (zr * 512 + col * 2) ^ ((zr & 7) << 4);
        *reinterpret_cast<short*>(reinterpret_cast<char*>(lds) + byte) = f2bf(z);
      }
    }
  __syncthreads();

#pragma unroll
  for (int m = 0; m < 4; ++m)
#pragma unroll
    for (int j = 0; j < 4; ++j) acc[m][j] = zero4;

#pragma unroll
  for (int ks = 0; ks < 8; ++ks) {
    bf16x8 a[4], b[4];
#pragma unroll
    for (int m = 0; m < 4; ++m) {
      int ar = m * 16 + lr;
      int abyte = (ar * 512 + ks * 64 + lhi * 16) ^ ((ar & 7) << 4);
      a[m] = *reinterpret_cast<const bf16x8*>(
          reinterpret_cast<const char*>(lds) + abyte);
    }
#pragma unroll
    for (int j = 0; j < 4; ++j) {
      int col = wv * 64 + j * 16 + lr;
      b[j] = *reinterpret_cast<const bf16x8*>(w2b + col * H + ks * 32 + lhi * 8);
    }
#pragma unroll
    for (int m = 0; m < 4; ++m)
#pragma unroll
      for (int j = 0; j < 4; ++j)
        acc[m][j] = __builtin_amdgcn_mfma_f32_16x16x32_bf16(a[m], b[j],
                                                            acc[m][j], 0, 0, 0);
  }

#pragma unroll
  for (int m = 0; m < 4; ++m) {
#pragma unroll
    for (int r = 0; r < 4; ++r) {
      int grow = row0 + m * 16 + lhi * 4 + r;
      if (grow < n) {
        float mask = counts[grow] > 0 ? 1.0f : 0.0f;
        const float* hrow = h + (size_t)grow * H;
        float* orow = out + (size_t)grow * H;
#pragma unroll
        for (int j = 0; j < 4; ++j) {
          int col = wv * 64 + j * 16 + lr;
          orow[col] = hrow[col] + (acc[m][j][r] + b2[col]) * mask;
        }
      }
    }
  }
}

// ---------------- last-resort fallback: atomic agg ----------------
__global__ __launch_bounds__(256) void agg_kernel(
    const float* __restrict__ h, const int* __restrict__ parent,
    const int* __restrict__ child, float* __restrict__ sums,
    int* __restrict__ counts, int E) {
  int gid = blockIdx.x * blockDim.x + threadIdx.x;
  int e = gid >> 6;
  if (e >= E) return;
  int lane = threadIdx.x & 63;
  int p = parent[e];
  int c = child[e];
  f32x4 v = ((const f32x4*)(h + (size_t)c * H))[lane];
  float* dst = sums + (size_t)p * H + lane * 4;
  unsafeAtomicAdd(dst + 0, v.x);
  unsafeAtomicAdd(dst + 1, v.y);
  unsafeAtomicAdd(dst + 2, v.z);
  unsafeAtomicAdd(dst + 3, v.w);
  if (lane == 0) atomicAdd(counts + p, 1);
}

__global__ __launch_bounds__(256) void mean_div_bf16_kernel(
    const float* __restrict__ sums, const int* __restrict__ counts,
    short* __restrict__ meansb, int n) {
  int w = (blockIdx.x * blockDim.x + threadIdx.x) >> 6;
  if (w >= n) return;
  int lane = threadIdx.x & 63;
  float inv = 1.0f / fmaxf((float)counts[w], 1.0f);
  f32x4 v = ((const f32x4*)(sums + (size_t)w * H))[lane];
  v *= inv;
  s16x4 bv;
  bv.x = f2bf(v.x);
  bv.y = f2bf(v.y);
  bv.z = f2bf(v.z);
  bv.w = f2bf(v.w);
  *reinterpret_cast<s16x4*>(meansb + (size_t)w * H + lane * 4) = bv;
}

extern "C" void kernel_launch(void* const* d_in, const int* in_sizes, int n_in,
                              void* d_out, int out_size, void* d_ws, size_t ws_size,
                              hipStream_t stream) {
  const float* h  = (const float*)d_in[0];
  const int* edges = (const int*)d_in[1];
  const float* W1 = (const float*)d_in[2];
  const float* b1 = (const float*)d_in[3];
  const float* W2 = (const float*)d_in[4];
  const float* b2 = (const float*)d_in[5];
  float* out = (float*)d_out;

  const int n = in_sizes[0] / H;   // 200000
  const int E = in_sizes[1] / 2;   // 1000000
  const int* parent = edges;
  const int* child = edges + E;

  char* ws = (char*)d_ws;
  int* counts    = (int*)(ws);                // n ints (800 KB)
  short* w1b     = (short*)(ws + 0x100000);   // 128 KB linear
  short* w2b     = (short*)(ws + 0x120000);   // 128 KB linear
  short* w1p     = (short*)(ws + 0x140000);   // 128 KB packed
  short* w2p     = (short*)(ws + 0x160000);   // 128 KB packed
  int* excl      = (int*)(ws + 0x180000);     // n ints
  int* cursor    = (int*)(ws + 0x280000);     // n ints
  int* blockSums = (int*)(ws + 0x380000);     // 256 ints
  int* offsets   = (int*)(ws + 0x384000);     // n ints
  int* childlist = (int*)(ws + 0x484000);     // E ints (4 MB @ E=1M)
  short* hb      = (short*)(ws + 0x884000);   // n*H bf16 (102.4 MB)
  size_t meansz  = (size_t)n * H * 2;

  size_t need_csr   = 0x484000 + (size_t)E * 4;
  size_t need_fused = 0x884000 + meansz;      // CSR + hb
  int nblk64 = (n + TILE_M - 1) / TILE_M;
  int nblk32 = (n + TILE_M2 - 1) / TILE_M2;

  cvt_kernel<<<(H * H + 255) / 256, 256, 0, stream>>>(W1, W2, w1b, w2b, w1p, w2p);

  if (ws_size >= need_fused && E <= (0x400000 / 4) && n <= 256 * 1024) {
    hipMemsetAsync(counts, 0, (size_t)n * sizeof(int), stream);
    long total8 = (long)n * H / 8;
    int nbCvt = (int)((total8 + 255) / 256);
    int nbHist = (E + 255) / 256;
    prep_kernel<<<nbCvt + nbHist, 256, 0, stream>>>(h, hb, total8, parent,
                                                    counts, E, nbCvt);
    int nb = (n + 1023) >> 10;
    scan1_kernel<<<nb, 256, 0, stream>>>(counts, excl, blockSums, n);
    scan2_kernel<<<1, 256, 0, stream>>>(blockSums, nb);
    scan3_kernel<<<(n + 255) / 256, 256, 0, stream>>>(excl, blockSums, offsets,
                                                      cursor, n);
    scatter_kernel<<<(E + 255) / 256, 256, 0, stream>>>(parent, child, cursor,
                                                        childlist, E);
    gm_mlp_kernel<<<nblk32, 256, 0, stream>>>(hb, childlist, offsets, counts,
                                              w1p, w2p, b1, b2, out, n);
  } else if (ws_size >= need_csr && n <= 256 * 1024) {
    hipMemsetAsync(counts, 0, (size_t)n * sizeof(int), stream);
    hist_kernel<<<(E + 255) / 256, 256, 0, stream>>>(parent, counts, E);
    int nb = (n + 1023) >> 10;
    scan1_kernel<<<nb, 256, 0, stream>>>(counts, excl, blockSums, n);
    scan2_kernel<<<1, 256, 0, stream>>>(blockSums, nb);
    scan3_kernel<<<(n + 255) / 256, 256, 0, stream>>>(excl, blockSums, offsets,
                                                      cursor, n);
    scatter_kernel<<<(E + 255) / 256, 256, 0, stream>>>(parent, child, cursor,
                                                        childlist, E);
    fused_kernel<<<nblk64, 256, 0, stream>>>(h, childlist, offsets, counts, w1b,
                                             w2b, b1, b2, out, n);
  } else {
    hipMemsetAsync(out, 0, (size_t)n * H * sizeof(float), stream);
    hipMemsetAsync(counts, 0, (size_t)n * sizeof(int), stream);
    agg_kernel<<<(E + 3) / 4, 256, 0, stream>>>(h, parent, child, out, counts, E);
    mean_div_bf16_kernel<<<((size_t)n * 64 + 255) / 256, 256, 0, stream>>>(
        out, counts, (short*)(ws + 0x180000), n);
    mlp2_kernel<<<nblk32, 256, 0, stream>>>(h, nullptr,
                                            (short*)(ws + 0x180000), counts,
                                            w1p, w2p, b1, b2, out, n);
  }
}

// Round 18
// 322.871 us; speedup vs baseline: 1.5128x; 1.0031x over previous
//
#include <hip/hip_runtime.h>
#include <hip/hip_bf16.h>

#define H 256
#define NEG_SLOPE 0.01f
#define TILE_M 64
#define TILE_M2 32

typedef __attribute__((ext_vector_type(4))) float f32x4;
typedef __attribute__((ext_vector_type(8))) short bf16x8;
typedef __attribute__((ext_vector_type(4))) short s16x4;

__device__ __forceinline__ short f2bf(float f) {
  __hip_bfloat16 b = __float2bfloat16(f);
  return *reinterpret_cast<short*>(&b);
}
__device__ __forceinline__ float bf2f(short s) {
  unsigned u = ((unsigned)(unsigned short)s) << 16;
  return __uint_as_float(u);
}

// ---------------- CSR build ----------------

__global__ __launch_bounds__(256) void hist_kernel(
    const int* __restrict__ parent, int* __restrict__ counts, int E) {
  int e = blockIdx.x * blockDim.x + threadIdx.x;
  if (e < E) atomicAdd(counts + parent[e], 1);
}

// 3-way fused: [0,nbCvt): h->hb bf16; [nbCvt,nbCvt+nbHist): histogram;
// rest: weight conversion (linear + fragment-packed).
__global__ __launch_bounds__(256) void prep_kernel(
    const float* __restrict__ h, short* __restrict__ hb, long total8,
    const int* __restrict__ parent, int* __restrict__ counts, int E,
    const float* __restrict__ W1, const float* __restrict__ W2,
    short* __restrict__ w1b, short* __restrict__ w2b,
    short* __restrict__ w1p, short* __restrict__ w2p,
    int nbCvt, int nbHist) {
  int b = blockIdx.x;
  if (b < nbCvt) {
    long i = (long)b * 256 + threadIdx.x;
    if (i >= total8) return;
    const f32x4* src = (const f32x4*)(h + i * 8);
    f32x4 v0 = __builtin_nontemporal_load(src);
    f32x4 v1 = __builtin_nontemporal_load(src + 1);
    bf16x8 o;
    o[0] = f2bf(v0.x); o[1] = f2bf(v0.y); o[2] = f2bf(v0.z); o[3] = f2bf(v0.w);
    o[4] = f2bf(v1.x); o[5] = f2bf(v1.y); o[6] = f2bf(v1.z); o[7] = f2bf(v1.w);
    *reinterpret_cast<bf16x8*>(hb + i * 8) = o;
  } else if (b < nbCvt + nbHist) {
    int e = (b - nbCvt) * 256 + threadIdx.x;
    if (e < E) atomicAdd(counts + parent[e], 1);
  } else {
    int i = (b - nbCvt - nbHist) * 256 + threadIdx.x;
    if (i < H * H) {
      short v1 = f2bf(W1[i]);
      short v2 = f2bf(W2[i]);
      w1b[i] = v1;
      w2b[i] = v2;
      int col = i >> 8, k = i & 255;
      int ks = k >> 5, lhi = (k >> 3) & 3, e = k & 7;
      int cb = col >> 4, lrr = col & 15;
      int pos = ((ks * 16 + cb) * 64 + lhi * 16 + lrr) * 8 + e;
      w1p[pos] = v1;
      w2p[pos] = v2;
    }
  }
}

__global__ __launch_bounds__(256) void scan1_kernel(
    const int* __restrict__ counts, int* __restrict__ excl,
    int* __restrict__ blockSums, int n) {
  __shared__ int lds[256];
  int tid = threadIdx.x;
  int base = blockIdx.x * 1024 + tid * 4;
  int4 v = {0, 0, 0, 0};
  if (base + 3 < n) v = *reinterpret_cast<const int4*>(counts + base);
  int s = v.x + v.y + v.z + v.w;
  lds[tid] = s;
  __syncthreads();
  for (int off = 1; off < 256; off <<= 1) {
    int t = (tid >= off) ? lds[tid - off] : 0;
    __syncthreads();
    lds[tid] += t;
    __syncthreads();
  }
  int toff = lds[tid] - s;
  if (base + 3 < n) {
    int4 o;
    o.x = toff;
    o.y = toff + v.x;
    o.z = o.y + v.y;
    o.w = o.z + v.z;
    *reinterpret_cast<int4*>(excl + base) = o;
  }
  if (tid == 255) blockSums[blockIdx.x] = lds[255];
}

// Merged scan2+scan3: each block re-scans blockSums (nb<=256) in LDS, then
// applies chunk base to its 256 elements. Saves a launch.
__global__ __launch_bounds__(256) void scan23_kernel(
    const int* __restrict__ excl, const int* __restrict__ blockSums, int nb,
    int* __restrict__ offsets, int* __restrict__ cursor, int n) {
  __shared__ int lds[256];
  int tid = threadIdx.x;
  int s = (tid < nb) ? blockSums[tid] : 0;
  lds[tid] = s;
  __syncthreads();
  for (int off = 1; off < 256; off <<= 1) {
    int t = (tid >= off) ? lds[tid - off] : 0;
    __syncthreads();
    lds[tid] += t;
    __syncthreads();
  }
  int i = blockIdx.x * 256 + tid;
  if (i < n) {
    int c = i >> 10;
    int exclBase = lds[c] - blockSums[c];  // exclusive prefix of chunk c
    int v = excl[i] + exclBase;
    offsets[i] = v;
    cursor[i] = v;
  }
}

__global__ __launch_bounds__(256) void scan2_kernel(int* __restrict__ blockSums,
                                                    int nb) {
  __shared__ int lds[256];
  int tid = threadIdx.x;
  int s = (tid < nb) ? blockSums[tid] : 0;
  lds[tid] = s;
  __syncthreads();
  for (int off = 1; off < 256; off <<= 1) {
    int t = (tid >= off) ? lds[tid - off] : 0;
    __syncthreads();
    lds[tid] += t;
    __syncthreads();
  }
  if (tid < nb) blockSums[tid] = lds[tid] - s;
}

__global__ __launch_bounds__(256) void scan3_kernel(
    const int* __restrict__ excl, const int* __restrict__ blockSums,
    int* __restrict__ offsets, int* __restrict__ cursor, int n) {
  int i = blockIdx.x * blockDim.x + threadIdx.x;
  if (i < n) {
    int v = excl[i] + blockSums[i >> 10];
    offsets[i] = v;
    cursor[i] = v;
  }
}

__global__ __launch_bounds__(256) void scatter_kernel(
    const int* __restrict__ parent, const int* __restrict__ child,
    int* __restrict__ cursor, int* __restrict__ childlist, int E) {
  int e = blockIdx.x * blockDim.x + threadIdx.x;
  if (e < E) {
    int pos = atomicAdd(cursor + parent[e], 1);
    childlist[pos] = child[e];
  }
}

// Standalone weight conversion (fallback paths).
__global__ __launch_bounds__(256) void cvt_kernel(
    const float* __restrict__ W1, const float* __restrict__ W2,
    short* __restrict__ w1b, short* __restrict__ w2b,
    short* __restrict__ w1p, short* __restrict__ w2p) {
  int i = blockIdx.x * blockDim.x + threadIdx.x;
  if (i < H * H) {
    short v1 = f2bf(W1[i]);
    short v2 = f2bf(W2[i]);
    w1b[i] = v1;
    w2b[i] = v2;
    int col = i >> 8, k = i & 255;
    int ks = k >> 5, lhi = (k >> 3) & 3, e = k & 7;
    int cb = col >> 4, lrr = col & 15;
    int pos = ((ks * 16 + cb) * 64 + lhi * 16 + lrr) * 8 + e;
    w1p[pos] = v1;
    w2p[pos] = v2;
  }
}

// ---------------- fully fused: gather-mean -> MLP -> residual --------------
__global__ __launch_bounds__(256, 4) void gm_mlp_kernel(
    const short* __restrict__ hb, const int* __restrict__ childlist,
    const int* __restrict__ offsets, const int* __restrict__ counts,
    const short* __restrict__ w1p, const short* __restrict__ w2p,
    const float* __restrict__ b1, const float* __restrict__ b2,
    float* __restrict__ out, int n) {
  __shared__ short lds[TILE_M2 * H];  // 16 KB: means -> z -> delta
  __shared__ float cmask[TILE_M2];

  const int tid = threadIdx.x;
  const int row0 = blockIdx.x * TILE_M2;
  const int lane = tid & 63;
  const int wv = tid >> 6;
  const int lr = lane & 15;
  const int lhi = lane >> 4;

  // ---- Phase A: gather-mean rows [wv*8, wv*8+8) ----
  {
    int rid = row0 + wv * 8 + (lane & 7);
    if (rid >= n) rid = n - 1;
    int myc = counts[rid];
    int myo = offsets[rid];

    int deg_n = __shfl(myc, 0);
    int off_n = __shfl(myo, 0);
    int dcn = deg_n < 64 ? deg_n : 64;
    int cidx_n = 0;
    if (lane < dcn) cidx_n = childlist[off_n + lane];

    for (int rr = 0; rr < 8; ++rr) {
      const int deg = deg_n;
      const int off = off_n;
      const int degc = dcn;
      const int cidx = cidx_n;
      if (rr + 1 < 8) {
        deg_n = __shfl(myc, rr + 1);
        off_n = __shfl(myo, rr + 1);
        dcn = deg_n < 64 ? deg_n : 64;
        cidx_n = 0;
        if (lane < dcn) cidx_n = childlist[off_n + lane];
      }

      f32x4 acc = {0.f, 0.f, 0.f, 0.f};
      const int k8 = degc < 8 ? degc : 8;
      s16x4 v[8];
#pragma unroll
      for (int j = 0; j < 8; ++j)
        if (j < k8) {
          int c = __shfl(cidx, j);
          v[j] = ((const s16x4*)(hb + (size_t)c * H))[lane];
        }
#pragma unroll
      for (int j = 0; j < 8; ++j)
        if (j < k8) {
          acc.x += bf2f(v[j].x);
          acc.y += bf2f(v[j].y);
          acc.z += bf2f(v[j].z);
          acc.w += bf2f(v[j].w);
        }
      int i = 8;
      for (; i + 4 <= degc; i += 4) {
        int c0 = __shfl(cidx, i);
        int c1 = __shfl(cidx, i + 1);
        int c2 = __shfl(cidx, i + 2);
        int c3 = __shfl(cidx, i + 3);
        s16x4 v0 = ((const s16x4*)(hb + (size_t)c0 * H))[lane];
        s16x4 v1 = ((const s16x4*)(hb + (size_t)c1 * H))[lane];
        s16x4 v2 = ((const s16x4*)(hb + (size_t)c2 * H))[lane];
        s16x4 v3 = ((const s16x4*)(hb + (size_t)c3 * H))[lane];
        acc.x += bf2f(v0.x) + bf2f(v1.x) + bf2f(v2.x) + bf2f(v3.x);
        acc.y += bf2f(v0.y) + bf2f(v1.y) + bf2f(v2.y) + bf2f(v3.y);
        acc.z += bf2f(v0.z) + bf2f(v1.z) + bf2f(v2.z) + bf2f(v3.z);
        acc.w += bf2f(v0.w) + bf2f(v1.w) + bf2f(v2.w) + bf2f(v3.w);
      }
      for (; i < degc; ++i) {
        int c = __shfl(cidx, i);
        s16x4 vv = ((const s16x4*)(hb + (size_t)c * H))[lane];
        acc.x += bf2f(vv.x);
        acc.y += bf2f(vv.y);
        acc.z += bf2f(vv.z);
        acc.w += bf2f(vv.w);
      }
      for (; i < deg; ++i) {
        int c = childlist[off + i];
        s16x4 vv = ((const s16x4*)(hb + (size_t)c * H))[lane];
        acc.x += bf2f(vv.x);
        acc.y += bf2f(vv.y);
        acc.z += bf2f(vv.z);
        acc.w += bf2f(vv.w);
      }
      float inv = 1.0f / (float)(deg > 0 ? deg : 1);
      acc *= inv;
      int r = wv * 8 + rr;
      if (lane == 0) cmask[r] = deg > 0 ? 1.0f : 0.0f;
      s16x4 bv;
      bv.x = f2bf(acc.x);
      bv.y = f2bf(acc.y);
      bv.z = f2bf(acc.z);
      bv.w = f2bf(acc.w);
      int byte = (r * 512 + lane * 8) ^ ((r & 7) << 4);
      *reinterpret_cast<s16x4*>(reinterpret_cast<char*>(lds) + byte) = bv;
    }
  }
  __syncthreads();

  const f32x4 zero4 = {0.f, 0.f, 0.f, 0.f};
  f32x4 acc[2][4];
#pragma unroll
  for (int m = 0; m < 2; ++m)
#pragma unroll
    for (int j = 0; j < 4; ++j) acc[m][j] = zero4;

  // ---- Layer 1 ----
#pragma unroll
  for (int ks = 0; ks < 8; ++ks) {
    bf16x8 a[2], b[4];
#pragma unroll
    for (int m = 0; m < 2; ++m) {
      int ar = m * 16 + lr;
      int abyte = (ar * 512 + ks * 64 + lhi * 16) ^ ((ar & 7) << 4);
      a[m] = *reinterpret_cast<const bf16x8*>(
          reinterpret_cast<const char*>(lds) + abyte);
    }
#pragma unroll
    for (int j = 0; j < 4; ++j) {
      int cb = wv * 4 + j;
      b[j] = *reinterpret_cast<const bf16x8*>(
          w1p + ((ks * 16 + cb) * 64 + lane) * 8);
    }
#pragma unroll
    for (int m = 0; m < 2; ++m)
#pragma unroll
      for (int j = 0; j < 4; ++j)
        acc[m][j] = __builtin_amdgcn_mfma_f32_16x16x32_bf16(a[m], b[j],
                                                            acc[m][j], 0, 0, 0);
  }
  __syncthreads();

  // z into LDS.
#pragma unroll
  for (int m = 0; m < 2; ++m)
#pragma unroll
    for (int j = 0; j < 4; ++j) {
      int col = wv * 64 + j * 16 + lr;
      float bias = b1[col];
#pragma unroll
      for (int r = 0; r < 4; ++r) {
        float z = acc[m][j][r] + bias;
        z = z >= 0.f ? z : NEG_SLOPE * z;
        int zr = m * 16 + lhi * 4 + r;
        int byte = (zr * 512 + col * 2) ^ ((zr & 7) << 4);
        *reinterpret_cast<short*>(reinterpret_cast<char*>(lds) + byte) = f2bf(z);
      }
    }
  __syncthreads();

  // ---- Layer 2 ----
#pragma unroll
  for (int m = 0; m < 2; ++m)
#pragma unroll
    for (int j = 0; j < 4; ++j) acc[m][j] = zero4;

#pragma unroll
  for (int ks = 0; ks < 8; ++ks) {
    bf16x8 a[2], b[4];
#pragma unroll
    for (int m = 0; m < 2; ++m) {
      int ar = m * 16 + lr;
      int abyte = (ar * 512 + ks * 64 + lhi * 16) ^ ((ar & 7) << 4);
      a[m] = *reinterpret_cast<const bf16x8*>(
          reinterpret_cast<const char*>(lds) + abyte);
    }
#pragma unroll
    for (int j = 0; j < 4; ++j) {
      int cb = wv * 4 + j;
      b[j] = *reinterpret_cast<const bf16x8*>(
          w2p + ((ks * 16 + cb) * 64 + lane) * 8);
    }
#pragma unroll
    for (int m = 0; m < 2; ++m)
#pragma unroll
      for (int j = 0; j < 4; ++j)
        acc[m][j] = __builtin_amdgcn_mfma_f32_16x16x32_bf16(a[m], b[j],
                                                            acc[m][j], 0, 0, 0);
  }
  __syncthreads();

  // delta into LDS.
#pragma unroll
  for (int m = 0; m < 2; ++m)
#pragma unroll
    for (int j = 0; j < 4; ++j) {
      int col = wv * 64 + j * 16 + lr;
      float bias = b2[col];
#pragma unroll
      for (int r = 0; r < 4; ++r) {
        float d = acc[m][j][r] + bias;
        int zr = m * 16 + lhi * 4 + r;
        int byte = (zr * 512 + col * 2) ^ ((zr & 7) << 4);
        *reinterpret_cast<short*>(reinterpret_cast<char*>(lds) + byte) = f2bf(d);
      }
    }
  __syncthreads();

  // Epilogue.
  {
    int row = tid >> 3;
    int sub = tid & 7;
    int grow = row0 + row;
    if (grow < n) {
      float mask = cmask[row];
      float* orow = out + (size_t)grow * H;
      const short* hrow = hb + (size_t)grow * H;
#pragma unroll
      for (int u = 0; u < 4; ++u) {
        int col = sub * 8 + u * 64;
        int byte = (row * 512 + col * 2) ^ ((row & 7) << 4);
        bf16x8 dv = *reinterpret_cast<const bf16x8*>(
            reinterpret_cast<const char*>(lds) + byte);
        bf16x8 hv = *reinterpret_cast<const bf16x8*>(hrow + col);
        f32x4 o0, o1;
        o0.x = bf2f(hv[0]) + bf2f(dv[0]) * mask;
        o0.y = bf2f(hv[1]) + bf2f(dv[1]) * mask;
        o0.z = bf2f(hv[2]) + bf2f(dv[2]) * mask;
        o0.w = bf2f(hv[3]) + bf2f(dv[3]) * mask;
        o1.x = bf2f(hv[4]) + bf2f(dv[4]) * mask;
        o1.y = bf2f(hv[5]) + bf2f(dv[5]) * mask;
        o1.z = bf2f(hv[6]) + bf2f(dv[6]) * mask;
        o1.w = bf2f(hv[7]) + bf2f(dv[7]) * mask;
        __builtin_nontemporal_store(o0, reinterpret_cast<f32x4*>(orow + col));
        __builtin_nontemporal_store(o1,
                                    reinterpret_cast<f32x4*>(orow + col + 4));
      }
    }
  }
}

// ---------------- non-fused MLP (atomic-fallback path) ----------------
__global__ __launch_bounds__(256, 4) void mlp2_kernel(
    const float* __restrict__ h, const short* __restrict__ hres,
    const short* __restrict__ meansb, const int* __restrict__ counts,
    const short* __restrict__ w1p, const short* __restrict__ w2p,
    const float* __restrict__ b1, const float* __restrict__ b2,
    float* __restrict__ out, int n) {
  __shared__ short lds[TILE_M2 * H];

  const int tid = threadIdx.x;
  const int row0 = blockIdx.x * TILE_M2;
  const int lane = tid & 63;
  const int wn = tid >> 6;
  const int lr = lane & 15;
  const int lhi = lane >> 4;

#pragma unroll
  for (int v = 0; v < 4; ++v) {
    int lin = v * 4096 + tid * 16;
    int row = lin >> 9;
    int grow = row0 + row;
    if (grow >= n) grow = n - 1;
    bf16x8 mv = *reinterpret_cast<const bf16x8*>(
        meansb + (size_t)grow * H + ((lin & 511) >> 1));
    int byte = lin ^ ((row & 7) << 4);
    *reinterpret_cast<bf16x8*>(reinterpret_cast<char*>(lds) + byte) = mv;
  }
  __syncthreads();

  const f32x4 zero4 = {0.f, 0.f, 0.f, 0.f};
  f32x4 acc[2][4];
#pragma unroll
  for (int m = 0; m < 2; ++m)
#pragma unroll
    for (int j = 0; j < 4; ++j) acc[m][j] = zero4;

#pragma unroll
  for (int ks = 0; ks < 8; ++ks) {
    bf16x8 a[2], b[4];
#pragma unroll
    for (int m = 0; m < 2; ++m) {
      int ar = m * 16 + lr;
      int abyte = (ar * 512 + ks * 64 + lhi * 16) ^ ((ar & 7) << 4);
      a[m] = *reinterpret_cast<const bf16x8*>(
          reinterpret_cast<const char*>(lds) + abyte);
    }
#pragma unroll
    for (int j = 0; j < 4; ++j) {
      int cb = wn * 4 + j;
      b[j] = *reinterpret_cast<const bf16x8*>(
          w1p + ((ks * 16 + cb) * 64 + lane) * 8);
    }
#pragma unroll
    for (int m = 0; m < 2; ++m)
#pragma unroll
      for (int j = 0; j < 4; ++j)
        acc[m][j] = __builtin_amdgcn_mfma_f32_16x16x32_bf16(a[m], b[j],
                                                            acc[m][j], 0, 0, 0);
  }
  __syncthreads();

#pragma unroll
  for (int m = 0; m < 2; ++m)
#pragma unroll
    for (int j = 0; j < 4; ++j) {
      int col = wn * 64 + j * 16 + lr;
      float bias = b1[col];
#pragma unroll
      for (int r = 0; r < 4; ++r) {
        float z = acc[m][j][r] + bias;
        z = z >= 0.f ? z : NEG_SLOPE * z;
        int zr = m * 16 + lhi * 4 + r;
        int byte = (zr * 512 + col * 2) ^ ((zr & 7) << 4);
        *reinterpret_cast<short*>(reinterpret_cast<char*>(lds) + byte) = f2bf(z);
      }
    }
  __syncthreads();

#pragma unroll
  for (int m = 0; m < 2; ++m)
#pragma unroll
    for (int j = 0; j < 4; ++j) acc[m][j] = zero4;

#pragma unroll
  for (int ks = 0; ks < 8; ++ks) {
    bf16x8 a[2], b[4];
#pragma unroll
    for (int m = 0; m < 2; ++m) {
      int ar = m * 16 + lr;
      int abyte = (ar * 512 + ks * 64 + lhi * 16) ^ ((ar & 7) << 4);
      a[m] = *reinterpret_cast<const bf16x8*>(
          reinterpret_cast<const char*>(lds) + abyte);
    }
#pragma unroll
    for (int j = 0; j < 4; ++j) {
      int cb = wn * 4 + j;
      b[j] = *reinterpret_cast<const bf16x8*>(
          w2p + ((ks * 16 + cb) * 64 + lane) * 8);
    }
#pragma unroll
    for (int m = 0; m < 2; ++m)
#pragma unroll
      for (int j = 0; j < 4; ++j)
        acc[m][j] = __builtin_amdgcn_mfma_f32_16x16x32_bf16(a[m], b[j],
                                                            acc[m][j], 0, 0, 0);
  }
  __syncthreads();

#pragma unroll
  for (int m = 0; m < 2; ++m)
#pragma unroll
    for (int j = 0; j < 4; ++j) {
      int col = wn * 64 + j * 16 + lr;
      float bias = b2[col];
#pragma unroll
      for (int r = 0; r < 4; ++r) {
        float d = acc[m][j][r] + bias;
        int zr = m * 16 + lhi * 4 + r;
        int byte = (zr * 512 + col * 2) ^ ((zr & 7) << 4);
        *reinterpret_cast<short*>(reinterpret_cast<char*>(lds) + byte) = f2bf(d);
      }
    }
  __syncthreads();

  {
    int row = tid >> 3;
    int sub = tid & 7;
    int grow = row0 + row;
    if (grow < n) {
      float mask = counts[grow] > 0 ? 1.0f : 0.0f;
      float* orow = out + (size_t)grow * H;
      const float* hrow = h + (size_t)grow * H;
#pragma unroll
      for (int u = 0; u < 4; ++u) {
        int col = sub * 8 + u * 64;
        int byte = (row * 512 + col * 2) ^ ((row & 7) << 4);
        bf16x8 dv = *reinterpret_cast<const bf16x8*>(
            reinterpret_cast<const char*>(lds) + byte);
        f32x4 h0 = *reinterpret_cast<const f32x4*>(hrow + col);
        f32x4 h1 = *reinterpret_cast<const f32x4*>(hrow + col + 4);
        f32x4 o0, o1;
        o0.x = h0.x + bf2f(dv[0]) * mask;
        o0.y = h0.y + bf2f(dv[1]) * mask;
        o0.z = h0.z + bf2f(dv[2]) * mask;
        o0.w = h0.w + bf2f(dv[3]) * mask;
        o1.x = h1.x + bf2f(dv[4]) * mask;
        o1.y = h1.y + bf2f(dv[5]) * mask;
        o1.z = h1.z + bf2f(dv[6]) * mask;
        o1.w = h1.w + bf2f(dv[7]) * mask;
        *reinterpret_cast<f32x4*>(orow + col) = o0;
        *reinterpret_cast<f32x4*>(orow + col + 4) = o1;
      }
    }
  }
}

// ---------------- mid fallback: fused gather+MLP (linear weights, f32) -----
__global__ __launch_bounds__(256) void fused_kernel(
    const float* __restrict__ h, const int* __restrict__ childlist,
    const int* __restrict__ offsets, const int* __restrict__ counts,
    const short* __restrict__ w1b, const short* __restrict__ w2b,
    const float* __restrict__ b1, const float* __restrict__ b2,
    float* __restrict__ out, int n) {
  __shared__ short lds[TILE_M * H];

  const int tid = threadIdx.x;
  const int row0 = blockIdx.x * TILE_M;
  const int lane = tid & 63;
  const int wv = tid >> 6;
  const int wrow = wv * 16;
  const int lr = lane & 15;
  const int lhi = lane >> 4;

  int rid = row0 + wrow + lr;
  if (rid >= n) rid = n - 1;
  const int myc = counts[rid];
  const int myo = offsets[rid];

  for (int rr = 0; rr < 16; ++rr) {
    int deg = __shfl(myc, rr);
    int off = __shfl(myo, rr);
    int degc = deg < 64 ? deg : 64;
    int cidx = 0;
    if (lane < degc) cidx = childlist[off + lane];
    f32x4 acc = {0.f, 0.f, 0.f, 0.f};
    int i = 0;
    for (; i + 4 <= degc; i += 4) {
      int c0 = __shfl(cidx, i);
      int c1 = __shfl(cidx, i + 1);
      int c2 = __shfl(cidx, i + 2);
      int c3 = __shfl(cidx, i + 3);
      f32x4 v0 = ((const f32x4*)(h + (size_t)c0 * H))[lane];
      f32x4 v1 = ((const f32x4*)(h + (size_t)c1 * H))[lane];
      f32x4 v2 = ((const f32x4*)(h + (size_t)c2 * H))[lane];
      f32x4 v3 = ((const f32x4*)(h + (size_t)c3 * H))[lane];
      acc += v0 + v1 + v2 + v3;
    }
    for (; i < degc; ++i) {
      int c = __shfl(cidx, i);
      acc += ((const f32x4*)(h + (size_t)c * H))[lane];
    }
    for (; i < deg; ++i) {
      int c = childlist[off + i];
      acc += ((const f32x4*)(h + (size_t)c * H))[lane];
    }
    float inv = 1.0f / (float)(deg > 0 ? deg : 1);
    acc *= inv;
    s16x4 bv;
    bv.x = f2bf(acc.x);
    bv.y = f2bf(acc.y);
    bv.z = f2bf(acc.z);
    bv.w = f2bf(acc.w);
    int r = wrow + rr;
    int byte = (r * 512 + lane * 8) ^ ((r & 7) << 4);
    *reinterpret_cast<s16x4*>(reinterpret_cast<char*>(lds) + byte) = bv;
  }
  __syncthreads();

  const f32x4 zero4 = {0.f, 0.f, 0.f, 0.f};
  f32x4 acc[4][4];
#pragma unroll
  for (int m = 0; m < 4; ++m)
#pragma unroll
    for (int j = 0; j < 4; ++j) acc[m][j] = zero4;

#pragma unroll
  for (int ks = 0; ks < 8; ++ks) {
    bf16x8 a[4], b[4];
#pragma unroll
    for (int m = 0; m < 4; ++m) {
      int ar = m * 16 + lr;
      int abyte = (ar * 512 + ks * 64 + lhi * 16) ^ ((ar & 7) << 4);
      a[m] = *reinterpret_cast<const bf16x8*>(
          reinterpret_cast<const char*>(lds) + abyte);
    }
#pragma unroll
    for (int j = 0; j < 4; ++j) {
      int col = wv * 64 + j * 16 + lr;
      b[j] = *reinterpret_cast<const bf16x8*>(w1b + col * H + ks * 32 + lhi * 8);
    }
#pragma unroll
    for (int m = 0; m < 4; ++m)
#pragma unroll
      for (int j = 0; j < 4; ++j)
        acc[m][j] = __builtin_amdgcn_mfma_f32_16x16x32_bf16(a[m], b[j],
                                                            acc[m][j], 0, 0, 0);
  }
  __syncthreads();

#pragma unroll
  for (int m = 0; m < 4; ++m)
#pragma unroll
    for (int j = 0; j < 4; ++j) {
      int col = wv * 64 + j * 16 + lr;
      float bias = b1[col];
#pragma unroll
      for (int r = 0; r < 4; ++r) {
        float z = acc[m][j][r] + bias;
        z = z >= 0.f ? z : NEG_SLOPE * z;
        int zr = m * 16 + lhi * 4 + r;
        int byte = (zr * 512 + col * 2) ^ ((zr & 7) << 4);
        *reinterpret_cast<short*>(reinterpret_cast<char*>(lds) + byte) = f2bf(z);
      }
    }
  __syncthreads();

#pragma unroll
  for (int m = 0; m < 4; ++m)
#pragma unroll
    for (int j = 0; j < 4; ++j) acc[m][j] = zero4;

#pragma unroll
  for (int ks = 0; ks < 8; ++ks) {
    bf16x8 a[4], b[4];
#pragma unroll
    for (int m = 0; m < 4; ++m) {
      int ar = m * 16 + lr;
      int abyte = (ar * 512 + ks * 64 + lhi * 16) ^ ((ar & 7) << 4);
      a[m] = *reinterpret_cast<const bf16x8*>(
          reinterpret_cast<const char*>(lds) + abyte);
    }
#pragma unroll
    for (int j = 0; j < 4; ++j) {
      int col = wv * 64 + j * 16 + lr;
      b[j] = *reinterpret_cast<const bf16x8*>(w2b + col * H + ks * 32 + lhi * 8);
    }
#pragma unroll
    for (int m = 0; m < 4; ++m)
#pragma unroll
      for (int j = 0; j < 4; ++j)
        acc[m][j] = __builtin_amdgcn_mfma_f32_16x16x32_bf16(a[m], b[j],
                                                            acc[m][j], 0, 0, 0);
  }

#pragma unroll
  for (int m = 0; m < 4; ++m) {
#pragma unroll
    for (int r = 0; r < 4; ++r) {
      int grow = row0 + m * 16 + lhi * 4 + r;
      if (grow < n) {
        float mask = counts[grow] > 0 ? 1.0f : 0.0f;
        const float* hrow = h + (size_t)grow * H;
        float* orow = out + (size_t)grow * H;
#pragma unroll
        for (int j = 0; j < 4; ++j) {
          int col = wv * 64 + j * 16 + lr;
          orow[col] = hrow[col] + (acc[m][j][r] + b2[col]) * mask;
        }
      }
    }
  }
}

// ---------------- last-resort fallback: atomic agg ----------------
__global__ __launch_bounds__(256) void agg_kernel(
    const float* __restrict__ h, const int* __restrict__ parent,
    const int* __restrict__ child, float* __restrict__ sums,
    int* __restrict__ counts, int E) {
  int gid = blockIdx.x * blockDim.x + threadIdx.x;
  int e = gid >> 6;
  if (e >= E) return;
  int lane = threadIdx.x & 63;
  int p = parent[e];
  int c = child[e];
  f32x4 v = ((const f32x4*)(h + (size_t)c * H))[lane];
  float* dst = sums + (size_t)p * H + lane * 4;
  unsafeAtomicAdd(dst + 0, v.x);
  unsafeAtomicAdd(dst + 1, v.y);
  unsafeAtomicAdd(dst + 2, v.z);
  unsafeAtomicAdd(dst + 3, v.w);
  if (lane == 0) atomicAdd(counts + p, 1);
}

__global__ __launch_bounds__(256) void mean_div_bf16_kernel(
    const float* __restrict__ sums, const int* __restrict__ counts,
    short* __restrict__ meansb, int n) {
  int w = (blockIdx.x * blockDim.x + threadIdx.x) >> 6;
  if (w >= n) return;
  int lane = threadIdx.x & 63;
  float inv = 1.0f / fmaxf((float)counts[w], 1.0f);
  f32x4 v = ((const f32x4*)(sums + (size_t)w * H))[lane];
  v *= inv;
  s16x4 bv;
  bv.x = f2bf(v.x);
  bv.y = f2bf(v.y);
  bv.z = f2bf(v.z);
  bv.w = f2bf(v.w);
  *reinterpret_cast<s16x4*>(meansb + (size_t)w * H + lane * 4) = bv;
}

extern "C" void kernel_launch(void* const* d_in, const int* in_sizes, int n_in,
                              void* d_out, int out_size, void* d_ws, size_t ws_size,
                              hipStream_t stream) {
  const float* h  = (const float*)d_in[0];
  const int* edges = (const int*)d_in[1];
  const float* W1 = (const float*)d_in[2];
  const float* b1 = (const float*)d_in[3];
  const float* W2 = (const float*)d_in[4];
  const float* b2 = (const float*)d_in[5];
  float* out = (float*)d_out;

  const int n = in_sizes[0] / H;   // 200000
  const int E = in_sizes[1] / 2;   // 1000000
  const int* parent = edges;
  const int* child = edges + E;

  char* ws = (char*)d_ws;
  int* counts    = (int*)(ws);                // n ints (800 KB)
  short* w1b     = (short*)(ws + 0x100000);   // 128 KB linear
  short* w2b     = (short*)(ws + 0x120000);   // 128 KB linear
  short* w1p     = (short*)(ws + 0x140000);   // 128 KB packed
  short* w2p     = (short*)(ws + 0x160000);   // 128 KB packed
  int* excl      = (int*)(ws + 0x180000);     // n ints
  int* cursor    = (int*)(ws + 0x280000);     // n ints
  int* blockSums = (int*)(ws + 0x380000);     // 256 ints
  int* offsets   = (int*)(ws + 0x384000);     // n ints
  int* childlist = (int*)(ws + 0x484000);     // E ints (4 MB @ E=1M)
  short* hb      = (short*)(ws + 0x884000);   // n*H bf16 (102.4 MB)
  size_t meansz  = (size_t)n * H * 2;

  size_t need_csr   = 0x484000 + (size_t)E * 4;
  size_t need_fused = 0x884000 + meansz;      // CSR + hb
  int nblk64 = (n + TILE_M - 1) / TILE_M;
  int nblk32 = (n + TILE_M2 - 1) / TILE_M2;

  if (ws_size >= need_fused && E <= (0x400000 / 4) && n <= 256 * 1024) {
    hipMemsetAsync(counts, 0, (size_t)n * sizeof(int), stream);
    long total8 = (long)n * H / 8;
    int nbCvt = (int)((total8 + 255) / 256);
    int nbHist = (E + 255) / 256;
    int nbCvtW = (H * H + 255) / 256;
    prep_kernel<<<nbCvt + nbHist + nbCvtW, 256, 0, stream>>>(
        h, hb, total8, parent, counts, E, W1, W2, w1b, w2b, w1p, w2p, nbCvt,
        nbHist);
    int nb = (n + 1023) >> 10;
    scan1_kernel<<<nb, 256, 0, stream>>>(counts, excl, blockSums, n);
    scan23_kernel<<<(n + 255) / 256, 256, 0, stream>>>(excl, blockSums, nb,
                                                       offsets, cursor, n);
    scatter_kernel<<<(E + 255) / 256, 256, 0, stream>>>(parent, child, cursor,
                                                        childlist, E);
    gm_mlp_kernel<<<nblk32, 256, 0, stream>>>(hb, childlist, offsets, counts,
                                              w1p, w2p, b1, b2, out, n);
  } else if (ws_size >= need_csr && n <= 256 * 1024) {
    cvt_kernel<<<(H * H + 255) / 256, 256, 0, stream>>>(W1, W2, w1b, w2b, w1p,
                                                        w2p);
    hipMemsetAsync(counts, 0, (size_t)n * sizeof(int), stream);
    hist_kernel<<<(E + 255) / 256, 256, 0, stream>>>(parent, counts, E);
    int nb = (n + 1023) >> 10;
    scan1_kernel<<<nb, 256, 0, stream>>>(counts, excl, blockSums, n);
    scan2_kernel<<<1, 256, 0, stream>>>(blockSums, nb);
    scan3_kernel<<<(n + 255) / 256, 256, 0, stream>>>(excl, blockSums, offsets,
                                                      cursor, n);
    scatter_kernel<<<(E + 255) / 256, 256, 0, stream>>>(parent, child, cursor,
                                                        childlist, E);
    fused_kernel<<<nblk64, 256, 0, stream>>>(h, childlist, offsets, counts, w1b,
                                             w2b, b1, b2, out, n);
  } else {
    cvt_kernel<<<(H * H + 255) / 256, 256, 0, stream>>>(W1, W2, w1b, w2b, w1p,
                                                        w2p);
    hipMemsetAsync(out, 0, (size_t)n * H * sizeof(float), stream);
    hipMemsetAsync(counts, 0, (size_t)n * sizeof(int), stream);
    agg_kernel<<<(E + 3) / 4, 256, 0, stream>>>(h, parent, child, out, counts, E);
    mean_div_bf16_kernel<<<((size_t)n * 64 + 255) / 256, 256, 0, stream>>>(
        out, counts, (short*)(ws + 0x180000), n);
    mlp2_kernel<<<nblk32, 256, 0, stream>>>(h, nullptr,
                                            (short*)(ws + 0x180000), counts,
                                            w1p, w2p, b1, b2, out, n);
  }
}